// Round 11
// baseline (2472.832 us; speedup 1.0000x reference)
//
#include <hip/hip_runtime.h>
#include <math.h>

// Problem constants
constexpr int B_ = 4096;
constexpr int T_ = 20;
constexpr int XD = 256;   // X_DIM
constexpr int ZD = 128;   // Z_DIM
constexpr int HD = 512;   // H_DIM
constexpr int DD = 384;   // X+Z

using short8 = __attribute__((ext_vector_type(8))) short;
using bf16x8 = __attribute__((ext_vector_type(8))) __bf16;
using f32x4  = __attribute__((ext_vector_type(4))) float;

__device__ __forceinline__ float lrelu_f(float v) { return v > 0.f ? v : 0.2f * v; }
__device__ __forceinline__ float softplus_f(float v) {
    return log1pf(expf(-fabsf(v))) + fmaxf(v, 0.f);
}
__device__ __forceinline__ float sigmoid_f(float v) { return 1.f / (1.f + expf(-v)); }

// float -> bf16 (round to nearest even), finite inputs
__device__ __forceinline__ unsigned short f2b(float f) {
    unsigned u = __builtin_bit_cast(unsigned, f);
    u += 0x7fff + ((u >> 16) & 1);
    return (unsigned short)(u >> 16);
}

__device__ __forceinline__ f32x4 mfma16(short8 a, short8 b, f32x4 c) {
    return __builtin_amdgcn_mfma_f32_16x16x32_bf16(
        __builtin_bit_cast(bf16x8, a), __builtin_bit_cast(bf16x8, b), c, 0, 0, 0);
}

// async global->LDS, 16 B per lane; lds base must be wave-uniform
__device__ __forceinline__ void load_lds16(const unsigned short* g, unsigned short* l) {
    __builtin_amdgcn_global_load_lds(
        (const __attribute__((address_space(1))) unsigned int*)g,
        (__attribute__((address_space(3))) unsigned int*)l,
        16, 0, 0);
}

// wait until at most `rem` K-tiles (LPT loads each) remain outstanding
template <int LPT>
__device__ __forceinline__ void vmwait(int rem) {
    if (rem >= 2) {
        if constexpr (LPT == 6)      asm volatile("s_waitcnt vmcnt(12)" ::: "memory");
        else if constexpr (LPT == 4) asm volatile("s_waitcnt vmcnt(8)" ::: "memory");
        else if constexpr (LPT == 3) asm volatile("s_waitcnt vmcnt(6)" ::: "memory");
        else                         asm volatile("s_waitcnt vmcnt(4)" ::: "memory");
    } else if (rem == 1) {
        if constexpr (LPT == 6)      asm volatile("s_waitcnt vmcnt(6)" ::: "memory");
        else if constexpr (LPT == 4) asm volatile("s_waitcnt vmcnt(4)" ::: "memory");
        else if constexpr (LPT == 3) asm volatile("s_waitcnt vmcnt(3)" ::: "memory");
        else                         asm volatile("s_waitcnt vmcnt(2)" ::: "memory");
    } else {
        asm volatile("s_waitcnt vmcnt(0)" ::: "memory");
    }
}

// ---------------------------------------------------------------------------
// MTx128-tile bf16 MFMA GEMM core (MT in {64,128}), 3-deep counted-vmcnt
// pipeline. Per-wave output 32x64 (MT=64) / 64x64 (MT=128).
// Chunk swizzle c' = c ^ ((row>>1)&3) on global source AND ds_read (rule #21).
// ---------------------------------------------------------------------------
template <int MT>
__device__ __forceinline__ void gemm_core(
    const unsigned short* A1, int lda1, int K1,
    const unsigned short* A2, int lda2, int K2,
    const unsigned short* W1, int ldw1,
    const unsigned short* W2, int ldw2,
    int bm, int bn,
    unsigned short* As, unsigned short* Bs,   // As: 3*MT*32, Bs: 3*4096 shorts
    f32x4 (&acc)[MT / 32][4])
{
    constexpr int MI   = MT / 32;
    constexpr int WRS  = MT / 2;
    constexpr int NA   = MT / 64;
    constexpr int LPT  = NA + 2;
    constexpr int ABUF = MT * 32;

    const int tid  = threadIdx.x;
    const int lane = tid & 63;
    const int wave = tid >> 6;
    const int wr = wave >> 1, wc = wave & 1;
    const int fr = lane & 15, fg = lane >> 4;
    const int cswz = fg ^ ((fr >> 1) & 3);

    const int r0 = tid >> 2,          c0 = (tid & 3) ^ ((r0 >> 1) & 3);
    const int r1 = (256 + tid) >> 2,  c1 = ((256 + tid) & 3) ^ ((r1 >> 1) & 3);

    const int n1 = K1 / 32;
    const int nt = n1 + K2 / 32;

    auto stage = [&](int i, int buf) {
        const unsigned short* Ag;
        const unsigned short* Wg;
        int lda, ldw, kb;
        if (i < n1) { Ag = A1; Wg = W1; lda = lda1; ldw = ldw1; kb = i * 32; }
        else        { Ag = A2; Wg = W2; lda = lda2; ldw = ldw2; kb = (i - n1) * 32; }
        unsigned short* lA = As + buf * ABUF + wave * 512;
        unsigned short* lB = Bs + buf * 4096 + wave * 512;
        load_lds16(Ag + (size_t)(bm + r0) * lda + kb + c0 * 8, lA);
        if constexpr (NA == 2)
            load_lds16(Ag + (size_t)(bm + r1) * lda + kb + c1 * 8, lA + 2048);
        load_lds16(Wg + (size_t)(bn + r0) * ldw + kb + c0 * 8, lB);
        load_lds16(Wg + (size_t)(bn + r1) * ldw + kb + c1 * 8, lB + 2048);
    };

    auto compute = [&](int buf) {
        const unsigned short* Ab_ = As + buf * ABUF;
        const unsigned short* Bb_ = Bs + buf * 4096;
        short8 af[MI], bv[4];
#pragma unroll
        for (int mi = 0; mi < MI; ++mi)
            af[mi] = *reinterpret_cast<const short8*>(Ab_ + (wr * WRS + mi * 16 + fr) * 32 + cswz * 8);
#pragma unroll
        for (int ni = 0; ni < 4; ++ni)
            bv[ni] = *reinterpret_cast<const short8*>(Bb_ + (wc * 64 + ni * 16 + fr) * 32 + cswz * 8);
#pragma unroll
        for (int mi = 0; mi < MI; ++mi)
#pragma unroll
            for (int ni = 0; ni < 4; ++ni)
                acc[mi][ni] = mfma16(af[mi], bv[ni], acc[mi][ni]);
    };

    stage(0, 0);
    if (1 < nt) stage(1, 1);
    if (2 < nt) stage(2, 2);
    {
        int rem = (nt - 1 < 2) ? (nt - 1) : 2;
        vmwait<LPT>(rem);
    }
    __builtin_amdgcn_s_barrier();

    int buf = 0;
    for (int i = 0; i < nt; ++i) {
        compute(buf);
        if (i + 1 < nt) {
            asm volatile("" ::: "memory");
            __builtin_amdgcn_s_barrier();
            if (i + 3 < nt) stage(i + 3, buf);
            int rem = nt - (i + 2);
            if (rem > 2) rem = 2;
            vmwait<LPT>(rem);
            __builtin_amdgcn_s_barrier();
            buf = (buf == 2) ? 0 : buf + 1;
        }
    }
}

// ---------------------------------------------------------------------------
// 256x128-tile core, per-wave output 128x64 (acc 8x4) -> LDS:MFMA 0.74:1.
// 4 waves (2M x 2N), LPT=6 (4 A + 2 B loads/wave/K-tile), 3-deep pipeline.
// Same K-tile order/fragment data as gemm_core -> bit-identical accumulation.
// ---------------------------------------------------------------------------
__device__ __forceinline__ void gemm_core_wide(
    const unsigned short* A1, int lda1, int K1,
    const unsigned short* A2, int lda2, int K2,
    const unsigned short* W1, int ldw1,
    const unsigned short* W2, int ldw2,
    int bm, int bn,
    unsigned short* As, unsigned short* Bs,   // As: 3*8192, Bs: 3*4096 shorts
    f32x4 (&acc)[8][4])
{
    const int tid  = threadIdx.x;
    const int lane = tid & 63;
    const int wave = tid >> 6;
    const int wr = wave >> 1, wc = wave & 1;
    const int fr = lane & 15, fg = lane >> 4;
    const int cswz = fg ^ ((fr >> 1) & 3);

    const int rr = tid >> 2;
    const int cc_ = (tid & 3) ^ ((rr >> 1) & 3);

    const int n1 = K1 / 32;
    const int nt = n1 + K2 / 32;

    auto stage = [&](int i, int buf) {
        const unsigned short* Ag;
        const unsigned short* Wg;
        int lda, ldw, kb;
        if (i < n1) { Ag = A1; Wg = W1; lda = lda1; ldw = ldw1; kb = i * 32; }
        else        { Ag = A2; Wg = W2; lda = lda2; ldw = ldw2; kb = (i - n1) * 32; }
        unsigned short* lA = As + buf * 8192 + wave * 512;
        unsigned short* lB = Bs + buf * 4096 + wave * 512;
#pragma unroll
        for (int j = 0; j < 4; ++j)   // A: 256 rows, 4 rounds
            load_lds16(Ag + (size_t)(bm + j * 64 + rr) * lda + kb + cc_ * 8, lA + j * 2048);
#pragma unroll
        for (int j = 0; j < 2; ++j)   // B: 128 rows, 2 rounds
            load_lds16(Wg + (size_t)(bn + j * 64 + rr) * ldw + kb + cc_ * 8, lB + j * 2048);
    };

    auto compute = [&](int buf) {
        const unsigned short* Ab_ = As + buf * 8192;
        const unsigned short* Bb_ = Bs + buf * 4096;
        short8 af[8], bv[4];
#pragma unroll
        for (int mi = 0; mi < 8; ++mi)
            af[mi] = *reinterpret_cast<const short8*>(Ab_ + (wr * 128 + mi * 16 + fr) * 32 + cswz * 8);
#pragma unroll
        for (int ni = 0; ni < 4; ++ni)
            bv[ni] = *reinterpret_cast<const short8*>(Bb_ + (wc * 64 + ni * 16 + fr) * 32 + cswz * 8);
#pragma unroll
        for (int mi = 0; mi < 8; ++mi)
#pragma unroll
            for (int ni = 0; ni < 4; ++ni)
                acc[mi][ni] = mfma16(af[mi], bv[ni], acc[mi][ni]);
    };

    stage(0, 0);
    stage(1, 1);
    stage(2, 2);
    vmwait<6>(2);
    __builtin_amdgcn_s_barrier();

    int buf = 0;
    for (int i = 0; i < nt; ++i) {
        compute(buf);
        if (i + 1 < nt) {
            asm volatile("" ::: "memory");
            __builtin_amdgcn_s_barrier();
            if (i + 3 < nt) stage(i + 3, buf);
            int rem = nt - (i + 2);
            if (rem > 2) rem = 2;
            vmwait<6>(rem);
            __builtin_amdgcn_s_barrier();
            buf = (buf == 2) ? 0 : buf + 1;
        }
    }
}

// GEMM + bias + activation -> bf16 output. ACT: 0 none, 1 lrelu, 2 softplus(lrelu)
// 1D grid decode: bn = (id & NMASK)*128, bm = (id >> NSHIFT)*MT
template <int ACT, int MT, int NMASK, int NSHIFT>
__global__ __launch_bounds__(256) void k_gemm_act(
    const unsigned short* __restrict__ A1, int lda1, int K1,
    const unsigned short* __restrict__ A2, int lda2, int K2,
    const unsigned short* __restrict__ W1, int ldw1,
    const unsigned short* __restrict__ W2, int ldw2,
    const float* __restrict__ bias,
    unsigned short* __restrict__ DB, int lddb)
{
    __shared__ unsigned short As[3 * MT * 32];
    __shared__ unsigned short Bs[3 * 4096];
    const int id = blockIdx.x;
    const int bm = (id >> NSHIFT) * MT, bn = (id & NMASK) * 128;
    f32x4 acc[MT / 32][4] = {};
    gemm_core<MT>(A1, lda1, K1, A2, lda2, K2, W1, ldw1, W2, ldw2, bm, bn, As, Bs, acc);

    constexpr int MI = MT / 32, WRS = MT / 2;
    const int tid = threadIdx.x, lane = tid & 63, wave = tid >> 6;
    const int wr = wave >> 1, wc = wave & 1, fr = lane & 15, rg = lane >> 4;
    float bb[4];
#pragma unroll
    for (int ni = 0; ni < 4; ++ni)
        bb[ni] = bias ? bias[bn + wc * 64 + ni * 16 + fr] : 0.f;
#pragma unroll
    for (int mi = 0; mi < MI; ++mi)
#pragma unroll
        for (int r = 0; r < 4; ++r) {
            const int row = bm + wr * WRS + mi * 16 + rg * 4 + r;
#pragma unroll
            for (int ni = 0; ni < 4; ++ni) {
                float v = acc[mi][ni][r] + bb[ni];
                if (ACT == 1) v = lrelu_f(v);
                else if (ACT == 2) v = softplus_f(lrelu_f(v));
                DB[(size_t)row * lddb + (bn + wc * 64 + ni * 16 + fr)] = f2b(v);
            }
        }
}

// ---------------------------------------------------------------------------
// Fused mean + phi kernel: grid 512: bm=(id>>3)*64 rows, bn=(id&7)*128 phi-cols.
// ---------------------------------------------------------------------------
__global__ __launch_bounds__(256) void k_meanphi(
    const unsigned short* __restrict__ uslot,  // umuvall + t*B*1024, [B][1024]
    const unsigned short* __restrict__ xb,     // [B][256]
    const unsigned short* __restrict__ Wm2b,   // [128][512]
    const unsigned short* __restrict__ Wcb,    // [1024][384]
    const float* __restrict__ bm2,             // [128]
    const float* __restrict__ bphi,            // [1024]
    float* __restrict__ oz, float* __restrict__ om,   // + t*ZD, stride T*ZD
    unsigned short* __restrict__ phib)
{
    __shared__ unsigned short As[3 * 64 * 32];
    __shared__ unsigned short Bs[3 * 4096];
    __shared__ unsigned short meanL[64 * 136];   // pad 136: conflict-light

    const int id = blockIdx.x;
    const int bm = (id >> 3) * 64, bn = (id & 7) * 128;
    const int tid = threadIdx.x, lane = tid & 63, wave = tid >> 6;
    const int wr = wave >> 1, wc = wave & 1, fr = lane & 15, fg = lane >> 4, rg = lane >> 4;
    const int cswz = fg ^ ((fr >> 1) & 3);
    const int r0 = tid >> 2,          c0 = (tid & 3) ^ ((r0 >> 1) & 3);
    const int r1 = (256 + tid) >> 2,  c1 = ((256 + tid) & 3) ^ ((r1 >> 1) & 3);

    // ---- stage 1: mean ----
    {
        f32x4 macc[2][4] = {};
        gemm_core<64>(uslot, 1024, 512, uslot, 1024, 0,
                      Wm2b, 512, Wm2b, 512, bm, 0, As, Bs, macc);
        float mb[4];
#pragma unroll
        for (int ni = 0; ni < 4; ++ni)
            mb[ni] = bm2[wc * 64 + ni * 16 + fr];
#pragma unroll
        for (int mi = 0; mi < 2; ++mi)
#pragma unroll
            for (int r = 0; r < 4; ++r) {
                const int rowl = wr * 32 + mi * 16 + rg * 4 + r;
#pragma unroll
                for (int ni = 0; ni < 4; ++ni) {
                    const int col = wc * 64 + ni * 16 + fr;
                    const float v = lrelu_f(macc[mi][ni][r] + mb[ni]);
                    meanL[rowl * 136 + col] = f2b(v);
                    if (bn == 0) {
                        const size_t o = (size_t)(bm + rowl) * (T_ * ZD) + col;
                        oz[o] = v; om[o] = v;
                    }
                }
            }
    }
    __syncthreads();

    // ---- stage 2: phi x-part (K=256) ----
    f32x4 acc[2][4] = {};
    gemm_core<64>(xb, XD, XD, xb, XD, 0,
                  Wcb, DD, Wcb, DD, bm, bn, As, Bs, acc);
    __syncthreads();

    // ---- stage 3: phi mean-part (K=128, 4 tiles), A from meanL ----
    {
        const unsigned short* WG = Wcb + XD;
        auto stageB = [&](int i, int buf) {
            unsigned short* lB = Bs + buf * 4096 + wave * 512;
            load_lds16(WG + (size_t)(bn + r0) * DD + i * 32 + c0 * 8, lB);
            load_lds16(WG + (size_t)(bn + r1) * DD + i * 32 + c1 * 8, lB + 2048);
        };
        stageB(0, 0); stageB(1, 1); stageB(2, 2);
        vmwait<2>(2);
        __builtin_amdgcn_s_barrier();
        int buf = 0;
        for (int i = 0; i < 4; ++i) {
            short8 af[2], bv[4];
#pragma unroll
            for (int mi = 0; mi < 2; ++mi)
                af[mi] = *reinterpret_cast<const short8*>(
                    meanL + (wr * 32 + mi * 16 + fr) * 136 + i * 32 + fg * 8);
#pragma unroll
            for (int ni = 0; ni < 4; ++ni)
                bv[ni] = *reinterpret_cast<const short8*>(
                    Bs + buf * 4096 + (wc * 64 + ni * 16 + fr) * 32 + cswz * 8);
#pragma unroll
            for (int mi = 0; mi < 2; ++mi)
#pragma unroll
                for (int ni = 0; ni < 4; ++ni)
                    acc[mi][ni] = mfma16(af[mi], bv[ni], acc[mi][ni]);
            if (i + 1 < 4) {
                asm volatile("" ::: "memory");
                __builtin_amdgcn_s_barrier();
                if (i + 3 < 4) stageB(i + 3, buf);
                int rem = 4 - (i + 2);
                if (rem > 2) rem = 2;
                vmwait<2>(rem);
                __builtin_amdgcn_s_barrier();
                buf = (buf == 2) ? 0 : buf + 1;
            }
        }
    }

    // ---- epilogue ----
    float pb[4];
#pragma unroll
    for (int ni = 0; ni < 4; ++ni)
        pb[ni] = bphi[bn + wc * 64 + ni * 16 + fr];
#pragma unroll
    for (int mi = 0; mi < 2; ++mi)
#pragma unroll
        for (int r = 0; r < 4; ++r) {
            const int row = bm + wr * 32 + mi * 16 + rg * 4 + r;
#pragma unroll
            for (int ni = 0; ni < 4; ++ni) {
                const float v = softplus_f(lrelu_f(acc[mi][ni][r] + pb[ni]));
                phib[(size_t)row * 1024 + (bn + wc * 64 + ni * 16 + fr)] = f2b(v);
            }
        }
}

// ---------------------------------------------------------------------------
// Batched logvar over ALL steps (off the recurrence path)
__global__ __launch_bounds__(256) void k_logvar_all(
    const unsigned short* __restrict__ umuvall,
    const unsigned short* __restrict__ Wv2b,
    const float* __restrict__ bv2,
    float* __restrict__ out_lv)               // [B][T][ZD]
{
    __shared__ unsigned short As[3 * 64 * 32];
    __shared__ unsigned short Bs[3 * 4096];
    const int bm = blockIdx.x * 64;
    f32x4 acc[2][4] = {};
    gemm_core<64>(umuvall + 512, 1024, 512, umuvall + 512, 1024, 0,
                  Wv2b, 512, Wv2b, 512, bm, 0, As, Bs, acc);

    const int tid = threadIdx.x, lane = tid & 63, wave = tid >> 6;
    const int wr = wave >> 1, wc = wave & 1, fr = lane & 15, rg = lane >> 4;
    float bb[4];
#pragma unroll
    for (int ni = 0; ni < 4; ++ni)
        bb[ni] = bv2[wc * 64 + ni * 16 + fr];
#pragma unroll
    for (int mi = 0; mi < 2; ++mi)
#pragma unroll
        for (int r = 0; r < 4; ++r) {
            const int row = bm + wr * 32 + mi * 16 + rg * 4 + r;   // t*B + b
            const int t = row >> 12, b = row & (B_ - 1);
#pragma unroll
            for (int ni = 0; ni < 4; ++ni) {
                const int col = wc * 64 + ni * 16 + fr;
                out_lv[(size_t)b * (T_ * ZD) + (size_t)t * ZD + col] =
                    lrelu_f(acc[mi][ni][r] + bb[ni]);
            }
        }
}

// gates GEMM (256x128 wide core) + gate-interleaved rows + fused LSTM.
// grid 256: sid=(id&7)*32+(id>>3); bn=(sid&15)*128, bm=(sid>>4)*256 (XCD chunks)
__global__ __launch_bounds__(256) void k_gates_lstm(
    const unsigned short* __restrict__ phib,
    const unsigned short* __restrict__ hbin,
    const unsigned short* __restrict__ Wih,   // [2048][1024] reordered rows
    const unsigned short* __restrict__ Whh,   // [2048][512] reordered rows
    const float* __restrict__ br,             // reordered b_ih+b_hh
    float* __restrict__ c,
    unsigned short* __restrict__ hbout,
    float* __restrict__ ohl,                  // out_hlo + t*HD
    float* __restrict__ oh_next)              // out_hout + (t+1)*HD, or null
{
    __shared__ unsigned short As[3 * 8192];   // 48 KB
    __shared__ unsigned short Bs[3 * 4096];   // 24 KB
    const int id = blockIdx.x;
    const int sid = (id & 7) * 32 + (id >> 3);         // bijective for 256
    const int bm = (sid >> 4) * 256, bn = (sid & 15) * 128;
    f32x4 acc[8][4] = {};
    gemm_core_wide(phib, 1024, 1024, hbin, 512, 512, Wih, 1024, Whh, 512, bm, bn, As, Bs, acc);

    const int tid = threadIdx.x, lane = tid & 63, wave = tid >> 6;
    const int wr = wave >> 1, wc = wave & 1, fr = lane & 15, rg = lane >> 4;
    const int n = ((bn + wc * 64) >> 6) * 16 + fr;     // hidden unit index
    float bb[4];
#pragma unroll
    for (int ni = 0; ni < 4; ++ni)
        bb[ni] = br[bn + wc * 64 + ni * 16 + fr];
#pragma unroll
    for (int mi = 0; mi < 8; ++mi)
#pragma unroll
        for (int r = 0; r < 4; ++r) {
            const int row = bm + wr * 128 + mi * 16 + rg * 4 + r;
            const size_t idx = (size_t)row * HD + n;
            const float gi = acc[mi][0][r] + bb[0];
            const float gf = acc[mi][1][r] + bb[1];
            const float gg = acc[mi][2][r] + bb[2];
            const float go = acc[mi][3][r] + bb[3];
            const float co = c[idx];
            const float cn = sigmoid_f(gf) * co + sigmoid_f(gi) * tanhf(gg);
            const float hn = sigmoid_f(go) * tanhf(cn);
            c[idx] = cn;
            hbout[idx] = f2b(hn);
            const size_t ob = (size_t)row * (T_ * HD) + n;
            ohl[ob] = hn;                       // h after update
            if (oh_next) oh_next[ob] = hn;      // == h BEFORE update at t+1
        }
}

// ---------------------------------------------------------------------------
// prep GEMM (MT=128 core, 2D grid) for Wc = Wphi @ A
__global__ __launch_bounds__(256) void k_gemm_plain(
    const unsigned short* __restrict__ A1, int lda1, int K1,
    const unsigned short* __restrict__ W1, int ldw1,
    unsigned short* __restrict__ DB, int lddb)
{
    __shared__ unsigned short As[3 * 128 * 32];
    __shared__ unsigned short Bs[3 * 4096];
    const int bm = blockIdx.y * 128, bn = blockIdx.x * 128;
    f32x4 acc[4][4] = {};
    gemm_core<128>(A1, lda1, K1, A1, lda1, 0, W1, ldw1, W1, ldw1, bm, bn, As, Bs, acc);

    const int tid = threadIdx.x, lane = tid & 63, wave = tid >> 6;
    const int wr = wave >> 1, wc = wave & 1, fr = lane & 15, rg = lane >> 4;
#pragma unroll
    for (int mi = 0; mi < 4; ++mi)
#pragma unroll
        for (int r = 0; r < 4; ++r) {
            const int row = bm + wr * 64 + mi * 16 + rg * 4 + r;
#pragma unroll
            for (int ni = 0; ni < 4; ++ni) {
                const int col = bn + wc * 64 + ni * 16 + fr;
                DB[(size_t)row * lddb + col] = f2b(acc[mi][ni][r]);
            }
        }
}

// ---------------------------------------------------------------------------
// One fused prep kernel: init-state + x-convert + all weight/bias reorders.
// Segment layout by blockIdx.x. Block counts (FIXED R11: conv-x was 4x short):
//   init  : B*HD/256             = 8192
//   conv-x: B*T*XD/4/256         = 20480
//   Wub   : 1024*768/256         = 3072
//   Wm2b  : ZD*HD/4/256          = 64
//   Wv2b  : 64; Wphib: 1024*DD/4/256 = 384; wg: 2048*1536/256 = 12288
//   At    : DD*DD/256            = 576;  bias: 16
// ---------------------------------------------------------------------------
constexpr int SG0 = 8192;
constexpr int SG1 = SG0 + 20480;
constexpr int SG2 = SG1 + 3072;
constexpr int SG3 = SG2 + 64;
constexpr int SG4 = SG3 + 64;
constexpr int SG5 = SG4 + 384;
constexpr int SG6 = SG5 + 12288;
constexpr int SG7 = SG6 + 576;
constexpr int SG8 = SG7 + 16;

__global__ __launch_bounds__(256) void prep_all(
    const float* __restrict__ x,
    const float* __restrict__ A,
    const float* __restrict__ Wm1, const float* __restrict__ bm1,
    const float* __restrict__ Wm2,
    const float* __restrict__ Wv1, const float* __restrict__ bv1,
    const float* __restrict__ Wv2,
    const float* __restrict__ Wphi,
    const float* __restrict__ Wih, const float* __restrict__ Whh,
    const float* __restrict__ bih, const float* __restrict__ bhh,
    float* __restrict__ c, unsigned short* __restrict__ hb0,
    float* __restrict__ oh0,
    unsigned short* __restrict__ xball,
    unsigned short* __restrict__ Wub,
    unsigned short* __restrict__ Wm2b, unsigned short* __restrict__ Wv2b,
    unsigned short* __restrict__ Wphib,
    unsigned short* __restrict__ Wrih, unsigned short* __restrict__ Wrhh,
    unsigned short* __restrict__ Atb,
    float* __restrict__ bu, float* __restrict__ br)
{
    const int blk = blockIdx.x;
    const int tid = threadIdx.x;

    if (blk < SG0) {                       // init state
        const int i = blk * 256 + tid;
        c[i] = 0.f; hb0[i] = 0;
        const int b = i >> 9, nn = i & 511;
        oh0[(size_t)b * (T_ * HD) + nn] = 0.f;
    } else if (blk < SG1) {                // x -> bf16, [T][B][XD]
        const int i = (blk - SG0) * 256 + tid;
        const int d = i & 63;
        const int bt = i >> 6;
        const int b = bt / T_, t = bt % T_;
        float4 v = reinterpret_cast<const float4*>(x)[i];
        ushort4 o;
        o.x = f2b(v.x); o.y = f2b(v.y); o.z = f2b(v.z); o.w = f2b(v.w);
        reinterpret_cast<ushort4*>(xball)[((size_t)t * B_ + b) * (XD / 4) + d] = o;
    } else if (blk < SG2) {                // Wub = [Wm1; Wv1]
        const int e = (blk - SG1) * 256 + tid;
        const float v = e < 512 * 768 ? Wm1[e] : Wv1[e - 512 * 768];
        Wub[e] = f2b(v);
    } else if (blk < SG3) {                // Wm2b
        const int i = (blk - SG2) * 256 + tid;
        float4 v = reinterpret_cast<const float4*>(Wm2)[i];
        ushort4 o;
        o.x = f2b(v.x); o.y = f2b(v.y); o.z = f2b(v.z); o.w = f2b(v.w);
        reinterpret_cast<ushort4*>(Wm2b)[i] = o;
    } else if (blk < SG4) {                // Wv2b
        const int i = (blk - SG3) * 256 + tid;
        float4 v = reinterpret_cast<const float4*>(Wv2)[i];
        ushort4 o;
        o.x = f2b(v.x); o.y = f2b(v.y); o.z = f2b(v.z); o.w = f2b(v.w);
        reinterpret_cast<ushort4*>(Wv2b)[i] = o;
    } else if (blk < SG5) {                // Wphib
        const int i = (blk - SG4) * 256 + tid;
        float4 v = reinterpret_cast<const float4*>(Wphi)[i];
        ushort4 o;
        o.x = f2b(v.x); o.y = f2b(v.y); o.z = f2b(v.z); o.w = f2b(v.w);
        reinterpret_cast<ushort4*>(Wphib)[i] = o;
    } else if (blk < SG6) {                // gate-interleaved W_ih / W_hh
        const int e = (blk - SG5) * 256 + tid;   // over 2048*1536
        const int cc = e / 1536, kk = e % 1536;
        const int gate = (cc >> 4) & 3;
        const int n = ((cc >> 6) << 4) + (cc & 15);
        const int orig = gate * 512 + n;
        if (kk < 1024) Wrih[(size_t)cc * 1024 + kk] = f2b(Wih[(size_t)orig * 1024 + kk]);
        else           Wrhh[(size_t)cc * 512 + (kk - 1024)] = f2b(Whh[(size_t)orig * 512 + (kk - 1024)]);
    } else if (blk < SG7) {                // At = A^T
        const int i = (blk - SG6) * 256 + tid;   // 384*384
        const int k = i / DD, j = i % DD;
        Atb[(size_t)k * DD + j] = f2b(A[(size_t)j * DD + k]);
    } else {                               // biases
        const int i = (blk - SG7) * 256 + tid;   // 0..4095
        if (i < 1024) {
            bu[i] = i < 512 ? bm1[i] : bv1[i - 512];
        } else if (i >= 2048) {
            const int cb = i - 2048;
            const int gate = (cb >> 4) & 3;
            const int n = ((cb >> 6) << 4) + (cb & 15);
            const int orig = gate * 512 + n;
            br[cb] = bih[orig] + bhh[orig];
        }
    }
}

extern "C" void kernel_launch(void* const* d_in, const int* in_sizes, int n_in,
                              void* d_out, int out_size, void* d_ws, size_t ws_size,
                              hipStream_t stream)
{
    const float* x    = (const float*)d_in[0];
    const float* A    = (const float*)d_in[3];
    const float* Wm1  = (const float*)d_in[4];
    const float* bm1  = (const float*)d_in[5];
    const float* Wm2  = (const float*)d_in[6];
    const float* bm2  = (const float*)d_in[7];
    const float* Wv1  = (const float*)d_in[8];
    const float* bv1  = (const float*)d_in[9];
    const float* Wv2  = (const float*)d_in[10];
    const float* bv2  = (const float*)d_in[11];
    const float* Wphi = (const float*)d_in[12];
    const float* bphi = (const float*)d_in[13];
    const float* W_ih = (const float*)d_in[14];
    const float* W_hh = (const float*)d_in[15];
    const float* b_ih = (const float*)d_in[16];
    const float* b_hh = (const float*)d_in[17];

    float* out = (float*)d_out;
    float* out_z    = out;
    float* out_mean = out_z + (size_t)B_ * T_ * ZD;
    float* out_lv   = out_mean + (size_t)B_ * T_ * ZD;
    float* out_hout = out_lv + (size_t)B_ * T_ * ZD;
    float* out_hlo  = out_hout + (size_t)B_ * T_ * HD;

    // ---- workspace layout (~255 MB) ----
    char* wp = (char*)d_ws;
    auto alloc_f = [&](size_t n) { float* p = (float*)wp; wp += n * sizeof(float); return p; };
    auto alloc_b = [&](size_t n) { unsigned short* p = (unsigned short*)wp; wp += n * sizeof(unsigned short); return p; };

    float* c = alloc_f((size_t)B_ * HD);
    unsigned short* hb0     = alloc_b((size_t)B_ * HD);
    unsigned short* hb1     = alloc_b((size_t)B_ * HD);
    unsigned short* xball   = alloc_b((size_t)T_ * B_ * XD);
    unsigned short* umuvall = alloc_b((size_t)T_ * B_ * 1024);
    unsigned short* phib    = alloc_b((size_t)B_ * 1024);

    unsigned short* Wub   = alloc_b((size_t)1024 * 768);
    unsigned short* Wm2b  = alloc_b((size_t)ZD * HD);
    unsigned short* Wv2b  = alloc_b((size_t)ZD * HD);
    unsigned short* Atb   = alloc_b((size_t)DD * DD);
    unsigned short* Wphib = alloc_b((size_t)1024 * DD);
    unsigned short* Wcb   = alloc_b((size_t)1024 * DD);
    unsigned short* Wrih  = alloc_b((size_t)2048 * 1024);
    unsigned short* Wrhh  = alloc_b((size_t)2048 * 512);

    float* bu = alloc_f(1024);
    float* br = alloc_f(2048);

    const dim3 blk(256);

    // ---- prep: one fused kernel + the Wc GEMM ----
    prep_all<<<dim3(SG8), blk, 0, stream>>>(
        x, A, Wm1, bm1, Wm2, Wv1, bv1, Wv2, Wphi, W_ih, W_hh, b_ih, b_hh,
        c, hb0, out_hout, xball, Wub, Wm2b, Wv2b, Wphib, Wrih, Wrhh, Atb, bu, br);
    // Wc = Wphi @ A  ([1024 x 384] bf16): folds the agg GEMM into phi
    k_gemm_plain<<<dim3(DD / 128, 1024 / 128), blk, 0, stream>>>(
        Wphib, DD, DD, Atb, DD, Wcb, DD);

    for (int t = 0; t < T_; ++t) {
        unsigned short* hbt = (t & 1) ? hb1 : hb0;   // h_t  (read)
        unsigned short* hbn = (t & 1) ? hb0 : hb1;   // h_{t+1} (written by epilogue)
        const unsigned short* xb = xball + (size_t)t * B_ * XD;
        unsigned short* uslot = umuvall + (size_t)t * B_ * 1024;

        // [u_m | u_v] = lrelu([x_t, h] @ Wub^T + bu)   [B, 1024]  MT=64, grid 512
        k_gemm_act<1, 64, 7, 3><<<dim3(512), blk, 0, stream>>>(
            xb, XD, XD, hbt, HD, HD,
            Wub, XD + HD, Wub + XD, XD + HD,
            bu, uslot, 1024);

        // mean (in-LDS) + phi fused; bn==0 writes out_z/out_mean
        k_meanphi<<<dim3(512), blk, 0, stream>>>(
            uslot, xb, Wm2b, Wcb, bm2, bphi,
            out_z + (size_t)t * ZD, out_mean + (size_t)t * ZD, phib);

        // gates (reordered) + fused LSTM   256x128 wide core, grid 256
        k_gates_lstm<<<dim3(256), blk, 0, stream>>>(
            phib, hbt, Wrih, Wrhh, br,
            c, hbn,
            out_hlo + (size_t)t * HD,
            (t + 1 < T_) ? out_hout + (size_t)(t + 1) * HD : nullptr);
    }

    // logvar for ALL steps in one batched GEMM (off the recurrence path)
    k_logvar_all<<<dim3(T_ * B_ / 64), blk, 0, stream>>>(
        umuvall, Wv2b, bv2, out_lv);
}

// Round 12
// 2047.468 us; speedup vs baseline: 1.2078x; 1.2078x over previous
//
#include <hip/hip_runtime.h>
#include <math.h>

// Problem constants
constexpr int B_ = 4096;
constexpr int T_ = 20;
constexpr int XD = 256;   // X_DIM
constexpr int ZD = 128;   // Z_DIM
constexpr int HD = 512;   // H_DIM
constexpr int DD = 384;   // X+Z

using short8 = __attribute__((ext_vector_type(8))) short;
using bf16x8 = __attribute__((ext_vector_type(8))) __bf16;
using f32x4  = __attribute__((ext_vector_type(4))) float;

__device__ __forceinline__ float lrelu_f(float v) { return v > 0.f ? v : 0.2f * v; }
__device__ __forceinline__ float softplus_f(float v) {
    return log1pf(expf(-fabsf(v))) + fmaxf(v, 0.f);
}
__device__ __forceinline__ float sigmoid_f(float v) { return 1.f / (1.f + expf(-v)); }

// float -> bf16 (round to nearest even), finite inputs
__device__ __forceinline__ unsigned short f2b(float f) {
    unsigned u = __builtin_bit_cast(unsigned, f);
    u += 0x7fff + ((u >> 16) & 1);
    return (unsigned short)(u >> 16);
}

__device__ __forceinline__ f32x4 mfma16(short8 a, short8 b, f32x4 c) {
    return __builtin_amdgcn_mfma_f32_16x16x32_bf16(
        __builtin_bit_cast(bf16x8, a), __builtin_bit_cast(bf16x8, b), c, 0, 0, 0);
}

// async global->LDS, 16 B per lane; lds base must be wave-uniform
__device__ __forceinline__ void load_lds16(const unsigned short* g, unsigned short* l) {
    __builtin_amdgcn_global_load_lds(
        (const __attribute__((address_space(1))) unsigned int*)g,
        (__attribute__((address_space(3))) unsigned int*)l,
        16, 0, 0);
}

// wait until at most `rem` K-tiles (LPT loads each) remain outstanding
template <int LPT>
__device__ __forceinline__ void vmwait(int rem) {
    if (rem >= 2) {
        if constexpr (LPT == 4)      asm volatile("s_waitcnt vmcnt(8)" ::: "memory");
        else if constexpr (LPT == 3) asm volatile("s_waitcnt vmcnt(6)" ::: "memory");
        else                         asm volatile("s_waitcnt vmcnt(4)" ::: "memory");
    } else if (rem == 1) {
        if constexpr (LPT == 4)      asm volatile("s_waitcnt vmcnt(4)" ::: "memory");
        else if constexpr (LPT == 3) asm volatile("s_waitcnt vmcnt(3)" ::: "memory");
        else                         asm volatile("s_waitcnt vmcnt(2)" ::: "memory");
    } else {
        asm volatile("s_waitcnt vmcnt(0)" ::: "memory");
    }
}

// ---------------------------------------------------------------------------
// MTx128-tile bf16 MFMA GEMM core (MT in {64,128}), 3-deep counted-vmcnt
// pipeline. Per-wave output 32x64 (MT=64) / 64x64 (MT=128).
// Chunk swizzle c' = c ^ ((row>>1)&3) on global source AND ds_read (rule #21).
// NOTE (R11 lesson): keep >=2 blocks/CU — the 256x128 wide core at 1 block/CU
// (1 wave/SIMD) lost cross-block TLP (m114) and cost +22 us/step despite a
// better per-wave LDS:MFMA ratio.
// ---------------------------------------------------------------------------
template <int MT>
__device__ __forceinline__ void gemm_core(
    const unsigned short* A1, int lda1, int K1,
    const unsigned short* A2, int lda2, int K2,
    const unsigned short* W1, int ldw1,
    const unsigned short* W2, int ldw2,
    int bm, int bn,
    unsigned short* As, unsigned short* Bs,   // As: 3*MT*32, Bs: 3*4096 shorts
    f32x4 (&acc)[MT / 32][4])
{
    constexpr int MI   = MT / 32;
    constexpr int WRS  = MT / 2;
    constexpr int NA   = MT / 64;
    constexpr int LPT  = NA + 2;
    constexpr int ABUF = MT * 32;

    const int tid  = threadIdx.x;
    const int lane = tid & 63;
    const int wave = tid >> 6;
    const int wr = wave >> 1, wc = wave & 1;
    const int fr = lane & 15, fg = lane >> 4;
    const int cswz = fg ^ ((fr >> 1) & 3);

    const int r0 = tid >> 2,          c0 = (tid & 3) ^ ((r0 >> 1) & 3);
    const int r1 = (256 + tid) >> 2,  c1 = ((256 + tid) & 3) ^ ((r1 >> 1) & 3);

    const int n1 = K1 / 32;
    const int nt = n1 + K2 / 32;

    auto stage = [&](int i, int buf) {
        const unsigned short* Ag;
        const unsigned short* Wg;
        int lda, ldw, kb;
        if (i < n1) { Ag = A1; Wg = W1; lda = lda1; ldw = ldw1; kb = i * 32; }
        else        { Ag = A2; Wg = W2; lda = lda2; ldw = ldw2; kb = (i - n1) * 32; }
        unsigned short* lA = As + buf * ABUF + wave * 512;
        unsigned short* lB = Bs + buf * 4096 + wave * 512;
        load_lds16(Ag + (size_t)(bm + r0) * lda + kb + c0 * 8, lA);
        if constexpr (NA == 2)
            load_lds16(Ag + (size_t)(bm + r1) * lda + kb + c1 * 8, lA + 2048);
        load_lds16(Wg + (size_t)(bn + r0) * ldw + kb + c0 * 8, lB);
        load_lds16(Wg + (size_t)(bn + r1) * ldw + kb + c1 * 8, lB + 2048);
    };

    auto compute = [&](int buf) {
        const unsigned short* Ab_ = As + buf * ABUF;
        const unsigned short* Bb_ = Bs + buf * 4096;
        short8 af[MI], bv[4];
#pragma unroll
        for (int mi = 0; mi < MI; ++mi)
            af[mi] = *reinterpret_cast<const short8*>(Ab_ + (wr * WRS + mi * 16 + fr) * 32 + cswz * 8);
#pragma unroll
        for (int ni = 0; ni < 4; ++ni)
            bv[ni] = *reinterpret_cast<const short8*>(Bb_ + (wc * 64 + ni * 16 + fr) * 32 + cswz * 8);
#pragma unroll
        for (int mi = 0; mi < MI; ++mi)
#pragma unroll
            for (int ni = 0; ni < 4; ++ni)
                acc[mi][ni] = mfma16(af[mi], bv[ni], acc[mi][ni]);
    };

    stage(0, 0);
    if (1 < nt) stage(1, 1);
    if (2 < nt) stage(2, 2);
    {
        int rem = (nt - 1 < 2) ? (nt - 1) : 2;
        vmwait<LPT>(rem);
    }
    __builtin_amdgcn_s_barrier();

    int buf = 0;
    for (int i = 0; i < nt; ++i) {
        compute(buf);
        if (i + 1 < nt) {
            asm volatile("" ::: "memory");
            __builtin_amdgcn_s_barrier();
            if (i + 3 < nt) stage(i + 3, buf);
            int rem = nt - (i + 2);
            if (rem > 2) rem = 2;
            vmwait<LPT>(rem);
            __builtin_amdgcn_s_barrier();
            buf = (buf == 2) ? 0 : buf + 1;
        }
    }
}

// GEMM + bias + activation -> bf16 output. ACT: 0 none, 1 lrelu, 2 softplus(lrelu)
// 1D grid decode: bn = (id & NMASK)*128, bm = (id >> NSHIFT)*MT
template <int ACT, int MT, int NMASK, int NSHIFT>
__global__ __launch_bounds__(256) void k_gemm_act(
    const unsigned short* __restrict__ A1, int lda1, int K1,
    const unsigned short* __restrict__ A2, int lda2, int K2,
    const unsigned short* __restrict__ W1, int ldw1,
    const unsigned short* __restrict__ W2, int ldw2,
    const float* __restrict__ bias,
    unsigned short* __restrict__ DB, int lddb)
{
    __shared__ unsigned short As[3 * MT * 32];
    __shared__ unsigned short Bs[3 * 4096];
    const int id = blockIdx.x;
    const int bm = (id >> NSHIFT) * MT, bn = (id & NMASK) * 128;
    f32x4 acc[MT / 32][4] = {};
    gemm_core<MT>(A1, lda1, K1, A2, lda2, K2, W1, ldw1, W2, ldw2, bm, bn, As, Bs, acc);

    constexpr int MI = MT / 32, WRS = MT / 2;
    const int tid = threadIdx.x, lane = tid & 63, wave = tid >> 6;
    const int wr = wave >> 1, wc = wave & 1, fr = lane & 15, rg = lane >> 4;
    float bb[4];
#pragma unroll
    for (int ni = 0; ni < 4; ++ni)
        bb[ni] = bias ? bias[bn + wc * 64 + ni * 16 + fr] : 0.f;
#pragma unroll
    for (int mi = 0; mi < MI; ++mi)
#pragma unroll
        for (int r = 0; r < 4; ++r) {
            const int row = bm + wr * WRS + mi * 16 + rg * 4 + r;
#pragma unroll
            for (int ni = 0; ni < 4; ++ni) {
                float v = acc[mi][ni][r] + bb[ni];
                if (ACT == 1) v = lrelu_f(v);
                else if (ACT == 2) v = softplus_f(lrelu_f(v));
                DB[(size_t)row * lddb + (bn + wc * 64 + ni * 16 + fr)] = f2b(v);
            }
        }
}

// ---------------------------------------------------------------------------
// Fused mean + phi kernel: grid 512: bm=(id>>3)*64 rows, bn=(id&7)*128 phi-cols.
// ---------------------------------------------------------------------------
__global__ __launch_bounds__(256) void k_meanphi(
    const unsigned short* __restrict__ uslot,  // umuvall + t*B*1024, [B][1024]
    const unsigned short* __restrict__ xb,     // [B][256]
    const unsigned short* __restrict__ Wm2b,   // [128][512]
    const unsigned short* __restrict__ Wcb,    // [1024][384]
    const float* __restrict__ bm2,             // [128]
    const float* __restrict__ bphi,            // [1024]
    float* __restrict__ oz, float* __restrict__ om,   // + t*ZD, stride T*ZD
    unsigned short* __restrict__ phib)
{
    __shared__ unsigned short As[3 * 64 * 32];
    __shared__ unsigned short Bs[3 * 4096];
    __shared__ unsigned short meanL[64 * 136];   // pad 136: conflict-light

    const int id = blockIdx.x;
    const int bm = (id >> 3) * 64, bn = (id & 7) * 128;
    const int tid = threadIdx.x, lane = tid & 63, wave = tid >> 6;
    const int wr = wave >> 1, wc = wave & 1, fr = lane & 15, fg = lane >> 4, rg = lane >> 4;
    const int cswz = fg ^ ((fr >> 1) & 3);
    const int r0 = tid >> 2,          c0 = (tid & 3) ^ ((r0 >> 1) & 3);
    const int r1 = (256 + tid) >> 2,  c1 = ((256 + tid) & 3) ^ ((r1 >> 1) & 3);

    // ---- stage 1: mean ----
    {
        f32x4 macc[2][4] = {};
        gemm_core<64>(uslot, 1024, 512, uslot, 1024, 0,
                      Wm2b, 512, Wm2b, 512, bm, 0, As, Bs, macc);
        float mb[4];
#pragma unroll
        for (int ni = 0; ni < 4; ++ni)
            mb[ni] = bm2[wc * 64 + ni * 16 + fr];
#pragma unroll
        for (int mi = 0; mi < 2; ++mi)
#pragma unroll
            for (int r = 0; r < 4; ++r) {
                const int rowl = wr * 32 + mi * 16 + rg * 4 + r;
#pragma unroll
                for (int ni = 0; ni < 4; ++ni) {
                    const int col = wc * 64 + ni * 16 + fr;
                    const float v = lrelu_f(macc[mi][ni][r] + mb[ni]);
                    meanL[rowl * 136 + col] = f2b(v);
                    if (bn == 0) {
                        const size_t o = (size_t)(bm + rowl) * (T_ * ZD) + col;
                        oz[o] = v; om[o] = v;
                    }
                }
            }
    }
    __syncthreads();

    // ---- stage 2: phi x-part (K=256) ----
    f32x4 acc[2][4] = {};
    gemm_core<64>(xb, XD, XD, xb, XD, 0,
                  Wcb, DD, Wcb, DD, bm, bn, As, Bs, acc);
    __syncthreads();

    // ---- stage 3: phi mean-part (K=128, 4 tiles), A from meanL ----
    {
        const unsigned short* WG = Wcb + XD;
        auto stageB = [&](int i, int buf) {
            unsigned short* lB = Bs + buf * 4096 + wave * 512;
            load_lds16(WG + (size_t)(bn + r0) * DD + i * 32 + c0 * 8, lB);
            load_lds16(WG + (size_t)(bn + r1) * DD + i * 32 + c1 * 8, lB + 2048);
        };
        stageB(0, 0); stageB(1, 1); stageB(2, 2);
        vmwait<2>(2);
        __builtin_amdgcn_s_barrier();
        int buf = 0;
        for (int i = 0; i < 4; ++i) {
            short8 af[2], bv[4];
#pragma unroll
            for (int mi = 0; mi < 2; ++mi)
                af[mi] = *reinterpret_cast<const short8*>(
                    meanL + (wr * 32 + mi * 16 + fr) * 136 + i * 32 + fg * 8);
#pragma unroll
            for (int ni = 0; ni < 4; ++ni)
                bv[ni] = *reinterpret_cast<const short8*>(
                    Bs + buf * 4096 + (wc * 64 + ni * 16 + fr) * 32 + cswz * 8);
#pragma unroll
            for (int mi = 0; mi < 2; ++mi)
#pragma unroll
                for (int ni = 0; ni < 4; ++ni)
                    acc[mi][ni] = mfma16(af[mi], bv[ni], acc[mi][ni]);
            if (i + 1 < 4) {
                asm volatile("" ::: "memory");
                __builtin_amdgcn_s_barrier();
                if (i + 3 < 4) stageB(i + 3, buf);
                int rem = 4 - (i + 2);
                if (rem > 2) rem = 2;
                vmwait<2>(rem);
                __builtin_amdgcn_s_barrier();
                buf = (buf == 2) ? 0 : buf + 1;
            }
        }
    }

    // ---- epilogue ----
    float pb[4];
#pragma unroll
    for (int ni = 0; ni < 4; ++ni)
        pb[ni] = bphi[bn + wc * 64 + ni * 16 + fr];
#pragma unroll
    for (int mi = 0; mi < 2; ++mi)
#pragma unroll
        for (int r = 0; r < 4; ++r) {
            const int row = bm + wr * 32 + mi * 16 + rg * 4 + r;
#pragma unroll
            for (int ni = 0; ni < 4; ++ni) {
                const float v = softplus_f(lrelu_f(acc[mi][ni][r] + pb[ni]));
                phib[(size_t)row * 1024 + (bn + wc * 64 + ni * 16 + fr)] = f2b(v);
            }
        }
}

// ---------------------------------------------------------------------------
// Batched logvar over ALL steps (off the recurrence path)
__global__ __launch_bounds__(256) void k_logvar_all(
    const unsigned short* __restrict__ umuvall,
    const unsigned short* __restrict__ Wv2b,
    const float* __restrict__ bv2,
    float* __restrict__ out_lv)               // [B][T][ZD]
{
    __shared__ unsigned short As[3 * 64 * 32];
    __shared__ unsigned short Bs[3 * 4096];
    const int bm = blockIdx.x * 64;
    f32x4 acc[2][4] = {};
    gemm_core<64>(umuvall + 512, 1024, 512, umuvall + 512, 1024, 0,
                  Wv2b, 512, Wv2b, 512, bm, 0, As, Bs, acc);

    const int tid = threadIdx.x, lane = tid & 63, wave = tid >> 6;
    const int wr = wave >> 1, wc = wave & 1, fr = lane & 15, rg = lane >> 4;
    float bb[4];
#pragma unroll
    for (int ni = 0; ni < 4; ++ni)
        bb[ni] = bv2[wc * 64 + ni * 16 + fr];
#pragma unroll
    for (int mi = 0; mi < 2; ++mi)
#pragma unroll
        for (int r = 0; r < 4; ++r) {
            const int row = bm + wr * 32 + mi * 16 + rg * 4 + r;   // t*B + b
            const int t = row >> 12, b = row & (B_ - 1);
#pragma unroll
            for (int ni = 0; ni < 4; ++ni) {
                const int col = wc * 64 + ni * 16 + fr;
                out_lv[(size_t)b * (T_ * ZD) + (size_t)t * ZD + col] =
                    lrelu_f(acc[mi][ni][r] + bb[ni]);
            }
        }
}

// gates GEMM (MT=128, grid 512 = 2 blocks/CU) + gate-interleaved rows + fused
// LSTM. XCD-chunked swizzle: sid=(id&7)*64+(id>>3); bn=(sid&15)*128,
// bm=(sid>>4)*128. [R9 config — restored after R11 wide-core regression]
__global__ __launch_bounds__(256) void k_gates_lstm(
    const unsigned short* __restrict__ phib,
    const unsigned short* __restrict__ hbin,
    const unsigned short* __restrict__ Wih,   // [2048][1024] reordered rows
    const unsigned short* __restrict__ Whh,   // [2048][512] reordered rows
    const float* __restrict__ br,             // reordered b_ih+b_hh
    float* __restrict__ c,
    unsigned short* __restrict__ hbout,
    float* __restrict__ ohl,                  // out_hlo + t*HD
    float* __restrict__ oh_next)              // out_hout + (t+1)*HD, or null
{
    __shared__ unsigned short As[3 * 128 * 32];
    __shared__ unsigned short Bs[3 * 4096];
    const int id = blockIdx.x;
    const int sid = (id & 7) * 64 + (id >> 3);         // bijective for 512
    const int bm = (sid >> 4) * 128, bn = (sid & 15) * 128;
    f32x4 acc[4][4] = {};
    gemm_core<128>(phib, 1024, 1024, hbin, 512, 512, Wih, 1024, Whh, 512, bm, bn, As, Bs, acc);

    const int tid = threadIdx.x, lane = tid & 63, wave = tid >> 6;
    const int wr = wave >> 1, wc = wave & 1, fr = lane & 15, rg = lane >> 4;
    const int n = ((bn + wc * 64) >> 6) * 16 + fr;     // hidden unit index
    float bb[4];
#pragma unroll
    for (int ni = 0; ni < 4; ++ni)
        bb[ni] = br[bn + wc * 64 + ni * 16 + fr];
#pragma unroll
    for (int mi = 0; mi < 4; ++mi)
#pragma unroll
        for (int r = 0; r < 4; ++r) {
            const int row = bm + wr * 64 + mi * 16 + rg * 4 + r;
            const size_t idx = (size_t)row * HD + n;
            const float gi = acc[mi][0][r] + bb[0];
            const float gf = acc[mi][1][r] + bb[1];
            const float gg = acc[mi][2][r] + bb[2];
            const float go = acc[mi][3][r] + bb[3];
            const float co = c[idx];
            const float cn = sigmoid_f(gf) * co + sigmoid_f(gi) * tanhf(gg);
            const float hn = sigmoid_f(go) * tanhf(cn);
            c[idx] = cn;
            hbout[idx] = f2b(hn);
            const size_t ob = (size_t)row * (T_ * HD) + n;
            ohl[ob] = hn;                       // h after update
            if (oh_next) oh_next[ob] = hn;      // == h BEFORE update at t+1
        }
}

// ---------------------------------------------------------------------------
// prep GEMM (MT=128 core, 2D grid) for Wc = Wphi @ A
__global__ __launch_bounds__(256) void k_gemm_plain(
    const unsigned short* __restrict__ A1, int lda1, int K1,
    const unsigned short* __restrict__ W1, int ldw1,
    unsigned short* __restrict__ DB, int lddb)
{
    __shared__ unsigned short As[3 * 128 * 32];
    __shared__ unsigned short Bs[3 * 4096];
    const int bm = blockIdx.y * 128, bn = blockIdx.x * 128;
    f32x4 acc[4][4] = {};
    gemm_core<128>(A1, lda1, K1, A1, lda1, 0, W1, ldw1, W1, ldw1, bm, bn, As, Bs, acc);

    const int tid = threadIdx.x, lane = tid & 63, wave = tid >> 6;
    const int wr = wave >> 1, wc = wave & 1, fr = lane & 15, rg = lane >> 4;
#pragma unroll
    for (int mi = 0; mi < 4; ++mi)
#pragma unroll
        for (int r = 0; r < 4; ++r) {
            const int row = bm + wr * 64 + mi * 16 + rg * 4 + r;
#pragma unroll
            for (int ni = 0; ni < 4; ++ni) {
                const int col = bn + wc * 64 + ni * 16 + fr;
                DB[(size_t)row * lddb + col] = f2b(acc[mi][ni][r]);
            }
        }
}

// ---------------------------------------------------------------------------
// One fused prep kernel: init-state + x-convert + all weight/bias reorders.
// Segment block counts:
//   init: 8192   conv-x: 20480   Wub: 3072   Wm2b: 64   Wv2b: 64
//   Wphib: 384   wg: 12288       At: 576     bias: 16
// ---------------------------------------------------------------------------
constexpr int SG0 = 8192;
constexpr int SG1 = SG0 + 20480;
constexpr int SG2 = SG1 + 3072;
constexpr int SG3 = SG2 + 64;
constexpr int SG4 = SG3 + 64;
constexpr int SG5 = SG4 + 384;
constexpr int SG6 = SG5 + 12288;
constexpr int SG7 = SG6 + 576;
constexpr int SG8 = SG7 + 16;

__global__ __launch_bounds__(256) void prep_all(
    const float* __restrict__ x,
    const float* __restrict__ A,
    const float* __restrict__ Wm1, const float* __restrict__ bm1,
    const float* __restrict__ Wm2,
    const float* __restrict__ Wv1, const float* __restrict__ bv1,
    const float* __restrict__ Wv2,
    const float* __restrict__ Wphi,
    const float* __restrict__ Wih, const float* __restrict__ Whh,
    const float* __restrict__ bih, const float* __restrict__ bhh,
    float* __restrict__ c, unsigned short* __restrict__ hb0,
    float* __restrict__ oh0,
    unsigned short* __restrict__ xball,
    unsigned short* __restrict__ Wub,
    unsigned short* __restrict__ Wm2b, unsigned short* __restrict__ Wv2b,
    unsigned short* __restrict__ Wphib,
    unsigned short* __restrict__ Wrih, unsigned short* __restrict__ Wrhh,
    unsigned short* __restrict__ Atb,
    float* __restrict__ bu, float* __restrict__ br)
{
    const int blk = blockIdx.x;
    const int tid = threadIdx.x;

    if (blk < SG0) {                       // init state
        const int i = blk * 256 + tid;
        c[i] = 0.f; hb0[i] = 0;
        const int b = i >> 9, nn = i & 511;
        oh0[(size_t)b * (T_ * HD) + nn] = 0.f;
    } else if (blk < SG1) {                // x -> bf16, [T][B][XD]
        const int i = (blk - SG0) * 256 + tid;
        const int d = i & 63;
        const int bt = i >> 6;
        const int b = bt / T_, t = bt % T_;
        float4 v = reinterpret_cast<const float4*>(x)[i];
        ushort4 o;
        o.x = f2b(v.x); o.y = f2b(v.y); o.z = f2b(v.z); o.w = f2b(v.w);
        reinterpret_cast<ushort4*>(xball)[((size_t)t * B_ + b) * (XD / 4) + d] = o;
    } else if (blk < SG2) {                // Wub = [Wm1; Wv1]
        const int e = (blk - SG1) * 256 + tid;
        const float v = e < 512 * 768 ? Wm1[e] : Wv1[e - 512 * 768];
        Wub[e] = f2b(v);
    } else if (blk < SG3) {                // Wm2b
        const int i = (blk - SG2) * 256 + tid;
        float4 v = reinterpret_cast<const float4*>(Wm2)[i];
        ushort4 o;
        o.x = f2b(v.x); o.y = f2b(v.y); o.z = f2b(v.z); o.w = f2b(v.w);
        reinterpret_cast<ushort4*>(Wm2b)[i] = o;
    } else if (blk < SG4) {                // Wv2b
        const int i = (blk - SG3) * 256 + tid;
        float4 v = reinterpret_cast<const float4*>(Wv2)[i];
        ushort4 o;
        o.x = f2b(v.x); o.y = f2b(v.y); o.z = f2b(v.z); o.w = f2b(v.w);
        reinterpret_cast<ushort4*>(Wv2b)[i] = o;
    } else if (blk < SG5) {                // Wphib
        const int i = (blk - SG4) * 256 + tid;
        float4 v = reinterpret_cast<const float4*>(Wphi)[i];
        ushort4 o;
        o.x = f2b(v.x); o.y = f2b(v.y); o.z = f2b(v.z); o.w = f2b(v.w);
        reinterpret_cast<ushort4*>(Wphib)[i] = o;
    } else if (blk < SG6) {                // gate-interleaved W_ih / W_hh
        const int e = (blk - SG5) * 256 + tid;   // over 2048*1536
        const int cc = e / 1536, kk = e % 1536;
        const int gate = (cc >> 4) & 3;
        const int n = ((cc >> 6) << 4) + (cc & 15);
        const int orig = gate * 512 + n;
        if (kk < 1024) Wrih[(size_t)cc * 1024 + kk] = f2b(Wih[(size_t)orig * 1024 + kk]);
        else           Wrhh[(size_t)cc * 512 + (kk - 1024)] = f2b(Whh[(size_t)orig * 512 + (kk - 1024)]);
    } else if (blk < SG7) {                // At = A^T
        const int i = (blk - SG6) * 256 + tid;   // 384*384
        const int k = i / DD, j = i % DD;
        Atb[(size_t)k * DD + j] = f2b(A[(size_t)j * DD + k]);
    } else {                               // biases
        const int i = (blk - SG7) * 256 + tid;   // 0..4095
        if (i < 1024) {
            bu[i] = i < 512 ? bm1[i] : bv1[i - 512];
        } else if (i >= 2048) {
            const int cb = i - 2048;
            const int gate = (cb >> 4) & 3;
            const int n = ((cb >> 6) << 4) + (cb & 15);
            const int orig = gate * 512 + n;
            br[cb] = bih[orig] + bhh[orig];
        }
    }
}

extern "C" void kernel_launch(void* const* d_in, const int* in_sizes, int n_in,
                              void* d_out, int out_size, void* d_ws, size_t ws_size,
                              hipStream_t stream)
{
    const float* x    = (const float*)d_in[0];
    const float* A    = (const float*)d_in[3];
    const float* Wm1  = (const float*)d_in[4];
    const float* bm1  = (const float*)d_in[5];
    const float* Wm2  = (const float*)d_in[6];
    const float* bm2  = (const float*)d_in[7];
    const float* Wv1  = (const float*)d_in[8];
    const float* bv1  = (const float*)d_in[9];
    const float* Wv2  = (const float*)d_in[10];
    const float* bv2  = (const float*)d_in[11];
    const float* Wphi = (const float*)d_in[12];
    const float* bphi = (const float*)d_in[13];
    const float* W_ih = (const float*)d_in[14];
    const float* W_hh = (const float*)d_in[15];
    const float* b_ih = (const float*)d_in[16];
    const float* b_hh = (const float*)d_in[17];

    float* out = (float*)d_out;
    float* out_z    = out;
    float* out_mean = out_z + (size_t)B_ * T_ * ZD;
    float* out_lv   = out_mean + (size_t)B_ * T_ * ZD;
    float* out_hout = out_lv + (size_t)B_ * T_ * ZD;
    float* out_hlo  = out_hout + (size_t)B_ * T_ * HD;

    // ---- workspace layout (~255 MB) ----
    char* wp = (char*)d_ws;
    auto alloc_f = [&](size_t n) { float* p = (float*)wp; wp += n * sizeof(float); return p; };
    auto alloc_b = [&](size_t n) { unsigned short* p = (unsigned short*)wp; wp += n * sizeof(unsigned short); return p; };

    float* c = alloc_f((size_t)B_ * HD);
    unsigned short* hb0     = alloc_b((size_t)B_ * HD);
    unsigned short* hb1     = alloc_b((size_t)B_ * HD);
    unsigned short* xball   = alloc_b((size_t)T_ * B_ * XD);
    unsigned short* umuvall = alloc_b((size_t)T_ * B_ * 1024);
    unsigned short* phib    = alloc_b((size_t)B_ * 1024);

    unsigned short* Wub   = alloc_b((size_t)1024 * 768);
    unsigned short* Wm2b  = alloc_b((size_t)ZD * HD);
    unsigned short* Wv2b  = alloc_b((size_t)ZD * HD);
    unsigned short* Atb   = alloc_b((size_t)DD * DD);
    unsigned short* Wphib = alloc_b((size_t)1024 * DD);
    unsigned short* Wcb   = alloc_b((size_t)1024 * DD);
    unsigned short* Wrih  = alloc_b((size_t)2048 * 1024);
    unsigned short* Wrhh  = alloc_b((size_t)2048 * 512);

    float* bu = alloc_f(1024);
    float* br = alloc_f(2048);

    const dim3 blk(256);

    // ---- prep: one fused kernel + the Wc GEMM ----
    prep_all<<<dim3(SG8), blk, 0, stream>>>(
        x, A, Wm1, bm1, Wm2, Wv1, bv1, Wv2, Wphi, W_ih, W_hh, b_ih, b_hh,
        c, hb0, out_hout, xball, Wub, Wm2b, Wv2b, Wphib, Wrih, Wrhh, Atb, bu, br);
    // Wc = Wphi @ A  ([1024 x 384] bf16): folds the agg GEMM into phi
    k_gemm_plain<<<dim3(DD / 128, 1024 / 128), blk, 0, stream>>>(
        Wphib, DD, DD, Atb, DD, Wcb, DD);

    for (int t = 0; t < T_; ++t) {
        unsigned short* hbt = (t & 1) ? hb1 : hb0;   // h_t  (read)
        unsigned short* hbn = (t & 1) ? hb0 : hb1;   // h_{t+1} (written by epilogue)
        const unsigned short* xb = xball + (size_t)t * B_ * XD;
        unsigned short* uslot = umuvall + (size_t)t * B_ * 1024;

        // [u_m | u_v] = lrelu([x_t, h] @ Wub^T + bu)   [B, 1024]  MT=64, grid 512
        k_gemm_act<1, 64, 7, 3><<<dim3(512), blk, 0, stream>>>(
            xb, XD, XD, hbt, HD, HD,
            Wub, XD + HD, Wub + XD, XD + HD,
            bu, uslot, 1024);

        // mean (in-LDS) + phi fused; bn==0 writes out_z/out_mean
        k_meanphi<<<dim3(512), blk, 0, stream>>>(
            uslot, xb, Wm2b, Wcb, bm2, bphi,
            out_z + (size_t)t * ZD, out_mean + (size_t)t * ZD, phib);

        // gates (reordered) + fused LSTM   MT=128, grid 512, XCD-swizzled
        k_gates_lstm<<<dim3(512), blk, 0, stream>>>(
            phib, hbt, Wrih, Wrhh, br,
            c, hbn,
            out_hlo + (size_t)t * HD,
            (t + 1 < T_) ? out_hout + (size_t)(t + 1) * HD : nullptr);
    }

    // logvar for ALL steps in one batched GEMM (off the recurrence path)
    k_logvar_all<<<dim3(T_ * B_ / 64), blk, 0, stream>>>(
        umuvall, Wv2b, bv2, out_lv);
}

// Round 13
// 1888.283 us; speedup vs baseline: 1.3096x; 1.0843x over previous
//
#include <hip/hip_runtime.h>
#include <math.h>

// Problem constants
constexpr int B_ = 4096;
constexpr int T_ = 20;
constexpr int XD = 256;   // X_DIM
constexpr int ZD = 128;   // Z_DIM
constexpr int HD = 512;   // H_DIM
constexpr int DD = 384;   // X+Z

using short8 = __attribute__((ext_vector_type(8))) short;
using bf16x8 = __attribute__((ext_vector_type(8))) __bf16;
using f32x4  = __attribute__((ext_vector_type(4))) float;

__device__ __forceinline__ float lrelu_f(float v) { return v > 0.f ? v : 0.2f * v; }
__device__ __forceinline__ float softplus_f(float v) {
    return log1pf(expf(-fabsf(v))) + fmaxf(v, 0.f);
}
__device__ __forceinline__ float sigmoid_f(float v) { return 1.f / (1.f + expf(-v)); }

// float -> bf16 (round to nearest even), finite inputs
__device__ __forceinline__ unsigned short f2b(float f) {
    unsigned u = __builtin_bit_cast(unsigned, f);
    u += 0x7fff + ((u >> 16) & 1);
    return (unsigned short)(u >> 16);
}

__device__ __forceinline__ f32x4 mfma16(short8 a, short8 b, f32x4 c) {
    return __builtin_amdgcn_mfma_f32_16x16x32_bf16(
        __builtin_bit_cast(bf16x8, a), __builtin_bit_cast(bf16x8, b), c, 0, 0, 0);
}

// async global->LDS, 16 B per lane; lds base must be wave-uniform
__device__ __forceinline__ void load_lds16(const unsigned short* g, unsigned short* l) {
    __builtin_amdgcn_global_load_lds(
        (const __attribute__((address_space(1))) unsigned int*)g,
        (__attribute__((address_space(3))) unsigned int*)l,
        16, 0, 0);
}

// wait until at most `rem` K-tiles (LPT loads each per wave) remain outstanding
template <int LPT>
__device__ __forceinline__ void vmwait(int rem) {
    if (rem >= 2) {
        if constexpr (LPT == 4)      asm volatile("s_waitcnt vmcnt(8)" ::: "memory");
        else if constexpr (LPT == 3) asm volatile("s_waitcnt vmcnt(6)" ::: "memory");
        else                         asm volatile("s_waitcnt vmcnt(4)" ::: "memory");
    } else if (rem == 1) {
        if constexpr (LPT == 4)      asm volatile("s_waitcnt vmcnt(4)" ::: "memory");
        else if constexpr (LPT == 3) asm volatile("s_waitcnt vmcnt(3)" ::: "memory");
        else                         asm volatile("s_waitcnt vmcnt(2)" ::: "memory");
    } else {
        asm volatile("s_waitcnt vmcnt(0)" ::: "memory");
    }
}

// ---------------------------------------------------------------------------
// MTx128-tile bf16 MFMA GEMM core (MT in {64,128}), 256 threads, 3-deep
// counted-vmcnt pipeline. Chunk swizzle c' = c ^ ((row>>1)&3) on global source
// AND ds_read (rule #21).
// ---------------------------------------------------------------------------
template <int MT>
__device__ __forceinline__ void gemm_core(
    const unsigned short* A1, int lda1, int K1,
    const unsigned short* A2, int lda2, int K2,
    const unsigned short* W1, int ldw1,
    const unsigned short* W2, int ldw2,
    int bm, int bn,
    unsigned short* As, unsigned short* Bs,   // As: 3*MT*32, Bs: 3*4096 shorts
    f32x4 (&acc)[MT / 32][4])
{
    constexpr int MI   = MT / 32;
    constexpr int WRS  = MT / 2;
    constexpr int NA   = MT / 64;
    constexpr int LPT  = NA + 2;
    constexpr int ABUF = MT * 32;

    const int tid  = threadIdx.x;
    const int lane = tid & 63;
    const int wave = tid >> 6;
    const int wr = wave >> 1, wc = wave & 1;
    const int fr = lane & 15, fg = lane >> 4;
    const int cswz = fg ^ ((fr >> 1) & 3);

    const int r0 = tid >> 2,          c0 = (tid & 3) ^ ((r0 >> 1) & 3);
    const int r1 = (256 + tid) >> 2,  c1 = ((256 + tid) & 3) ^ ((r1 >> 1) & 3);

    const int n1 = K1 / 32;
    const int nt = n1 + K2 / 32;

    auto stage = [&](int i, int buf) {
        const unsigned short* Ag;
        const unsigned short* Wg;
        int lda, ldw, kb;
        if (i < n1) { Ag = A1; Wg = W1; lda = lda1; ldw = ldw1; kb = i * 32; }
        else        { Ag = A2; Wg = W2; lda = lda2; ldw = ldw2; kb = (i - n1) * 32; }
        unsigned short* lA = As + buf * ABUF + wave * 512;
        unsigned short* lB = Bs + buf * 4096 + wave * 512;
        load_lds16(Ag + (size_t)(bm + r0) * lda + kb + c0 * 8, lA);
        if constexpr (NA == 2)
            load_lds16(Ag + (size_t)(bm + r1) * lda + kb + c1 * 8, lA + 2048);
        load_lds16(Wg + (size_t)(bn + r0) * ldw + kb + c0 * 8, lB);
        load_lds16(Wg + (size_t)(bn + r1) * ldw + kb + c1 * 8, lB + 2048);
    };

    auto compute = [&](int buf) {
        const unsigned short* Ab_ = As + buf * ABUF;
        const unsigned short* Bb_ = Bs + buf * 4096;
        short8 af[MI], bv[4];
#pragma unroll
        for (int mi = 0; mi < MI; ++mi)
            af[mi] = *reinterpret_cast<const short8*>(Ab_ + (wr * WRS + mi * 16 + fr) * 32 + cswz * 8);
#pragma unroll
        for (int ni = 0; ni < 4; ++ni)
            bv[ni] = *reinterpret_cast<const short8*>(Bb_ + (wc * 64 + ni * 16 + fr) * 32 + cswz * 8);
#pragma unroll
        for (int mi = 0; mi < MI; ++mi)
#pragma unroll
            for (int ni = 0; ni < 4; ++ni)
                acc[mi][ni] = mfma16(af[mi], bv[ni], acc[mi][ni]);
    };

    stage(0, 0);
    if (1 < nt) stage(1, 1);
    if (2 < nt) stage(2, 2);
    {
        int rem = (nt - 1 < 2) ? (nt - 1) : 2;
        vmwait<LPT>(rem);
    }
    __builtin_amdgcn_s_barrier();

    int buf = 0;
    for (int i = 0; i < nt; ++i) {
        compute(buf);
        if (i + 1 < nt) {
            asm volatile("" ::: "memory");
            __builtin_amdgcn_s_barrier();
            if (i + 3 < nt) stage(i + 3, buf);
            int rem = nt - (i + 2);
            if (rem > 2) rem = 2;
            vmwait<LPT>(rem);
            __builtin_amdgcn_s_barrier();
            buf = (buf == 2) ? 0 : buf + 1;
        }
    }
}

// ---------------------------------------------------------------------------
// 128x128-tile core, 512 threads = 8 waves (4M x 2N), each wave 32x64 output
// (acc 2x4). Same K-tile order and fragment data as gemm_core<128> ->
// bit-identical accumulation. LPT=2/wave (1 A + 1 B load per K-tile).
// More waves/SIMD (4 at 2 blocks/CU) for staging/ds_read latency hiding.
// ---------------------------------------------------------------------------
__device__ __forceinline__ void gemm_core8w(
    const unsigned short* A1, int lda1, int K1,
    const unsigned short* A2, int lda2, int K2,
    const unsigned short* W1, int ldw1,
    const unsigned short* W2, int ldw2,
    int bm, int bn,
    unsigned short* As, unsigned short* Bs,   // each 3*4096 shorts
    f32x4 (&acc)[2][4])
{
    const int tid  = threadIdx.x;          // 0..511
    const int lane = tid & 63;
    const int wave = tid >> 6;             // 0..7
    const int wr = wave >> 1, wc = wave & 1;
    const int fr = lane & 15, fg = lane >> 4;
    const int cswz = fg ^ ((fr >> 1) & 3);

    const int r0 = tid >> 2;                       // 0..127
    const int c0 = (tid & 3) ^ ((r0 >> 1) & 3);

    const int n1 = K1 / 32;
    const int nt = n1 + K2 / 32;

    auto stage = [&](int i, int buf) {
        const unsigned short* Ag;
        const unsigned short* Wg;
        int lda, ldw, kb;
        if (i < n1) { Ag = A1; Wg = W1; lda = lda1; ldw = ldw1; kb = i * 32; }
        else        { Ag = A2; Wg = W2; lda = lda2; ldw = ldw2; kb = (i - n1) * 32; }
        unsigned short* lA = As + buf * 4096 + wave * 512;   // 8 waves x 512 = 4096
        unsigned short* lB = Bs + buf * 4096 + wave * 512;
        load_lds16(Ag + (size_t)(bm + r0) * lda + kb + c0 * 8, lA);
        load_lds16(Wg + (size_t)(bn + r0) * ldw + kb + c0 * 8, lB);
    };

    auto compute = [&](int buf) {
        const unsigned short* Ab_ = As + buf * 4096;
        const unsigned short* Bb_ = Bs + buf * 4096;
        short8 af[2], bv[4];
#pragma unroll
        for (int mi = 0; mi < 2; ++mi)
            af[mi] = *reinterpret_cast<const short8*>(Ab_ + (wr * 32 + mi * 16 + fr) * 32 + cswz * 8);
#pragma unroll
        for (int ni = 0; ni < 4; ++ni)
            bv[ni] = *reinterpret_cast<const short8*>(Bb_ + (wc * 64 + ni * 16 + fr) * 32 + cswz * 8);
#pragma unroll
        for (int mi = 0; mi < 2; ++mi)
#pragma unroll
            for (int ni = 0; ni < 4; ++ni)
                acc[mi][ni] = mfma16(af[mi], bv[ni], acc[mi][ni]);
    };

    stage(0, 0);
    if (1 < nt) stage(1, 1);
    if (2 < nt) stage(2, 2);
    {
        int rem = (nt - 1 < 2) ? (nt - 1) : 2;
        vmwait<2>(rem);
    }
    __builtin_amdgcn_s_barrier();

    int buf = 0;
    for (int i = 0; i < nt; ++i) {
        compute(buf);
        if (i + 1 < nt) {
            asm volatile("" ::: "memory");
            __builtin_amdgcn_s_barrier();
            if (i + 3 < nt) stage(i + 3, buf);
            int rem = nt - (i + 2);
            if (rem > 2) rem = 2;
            vmwait<2>(rem);
            __builtin_amdgcn_s_barrier();
            buf = (buf == 2) ? 0 : buf + 1;
        }
    }
}

// GEMM + bias + activation -> bf16 output. ACT: 0 none, 1 lrelu, 2 softplus(lrelu)
// 1D grid decode: bn = (id & NMASK)*128, bm = (id >> NSHIFT)*MT
template <int ACT, int MT, int NMASK, int NSHIFT>
__global__ __launch_bounds__(256) void k_gemm_act(
    const unsigned short* __restrict__ A1, int lda1, int K1,
    const unsigned short* __restrict__ A2, int lda2, int K2,
    const unsigned short* __restrict__ W1, int ldw1,
    const unsigned short* __restrict__ W2, int ldw2,
    const float* __restrict__ bias,
    unsigned short* __restrict__ DB, int lddb)
{
    __shared__ unsigned short As[3 * MT * 32];
    __shared__ unsigned short Bs[3 * 4096];
    const int id = blockIdx.x;
    const int bm = (id >> NSHIFT) * MT, bn = (id & NMASK) * 128;
    f32x4 acc[MT / 32][4] = {};
    gemm_core<MT>(A1, lda1, K1, A2, lda2, K2, W1, ldw1, W2, ldw2, bm, bn, As, Bs, acc);

    constexpr int MI = MT / 32, WRS = MT / 2;
    const int tid = threadIdx.x, lane = tid & 63, wave = tid >> 6;
    const int wr = wave >> 1, wc = wave & 1, fr = lane & 15, rg = lane >> 4;
    float bb[4];
#pragma unroll
    for (int ni = 0; ni < 4; ++ni)
        bb[ni] = bias ? bias[bn + wc * 64 + ni * 16 + fr] : 0.f;
#pragma unroll
    for (int mi = 0; mi < MI; ++mi)
#pragma unroll
        for (int r = 0; r < 4; ++r) {
            const int row = bm + wr * WRS + mi * 16 + rg * 4 + r;
#pragma unroll
            for (int ni = 0; ni < 4; ++ni) {
                float v = acc[mi][ni][r] + bb[ni];
                if (ACT == 1) v = lrelu_f(v);
                else if (ACT == 2) v = softplus_f(lrelu_f(v));
                DB[(size_t)row * lddb + (bn + wc * 64 + ni * 16 + fr)] = f2b(v);
            }
        }
}

// ---------------------------------------------------------------------------
// Fused mean + phi kernel: grid 512: bm=(id>>3)*64 rows, bn=(id&7)*128 phi-cols.
// ---------------------------------------------------------------------------
__global__ __launch_bounds__(256) void k_meanphi(
    const unsigned short* __restrict__ uslot,  // umuvall + t*B*1024, [B][1024]
    const unsigned short* __restrict__ xb,     // [B][256]
    const unsigned short* __restrict__ Wm2b,   // [128][512]
    const unsigned short* __restrict__ Wcb,    // [1024][384]
    const float* __restrict__ bm2,             // [128]
    const float* __restrict__ bphi,            // [1024]
    float* __restrict__ oz, float* __restrict__ om,   // + t*ZD, stride T*ZD
    unsigned short* __restrict__ phib)
{
    __shared__ unsigned short As[3 * 64 * 32];
    __shared__ unsigned short Bs[3 * 4096];
    __shared__ unsigned short meanL[64 * 136];   // pad 136: conflict-light

    const int id = blockIdx.x;
    const int bm = (id >> 3) * 64, bn = (id & 7) * 128;
    const int tid = threadIdx.x, lane = tid & 63, wave = tid >> 6;
    const int wr = wave >> 1, wc = wave & 1, fr = lane & 15, fg = lane >> 4, rg = lane >> 4;
    const int cswz = fg ^ ((fr >> 1) & 3);
    const int r0 = tid >> 2,          c0 = (tid & 3) ^ ((r0 >> 1) & 3);
    const int r1 = (256 + tid) >> 2,  c1 = ((256 + tid) & 3) ^ ((r1 >> 1) & 3);

    // ---- stage 1: mean ----
    {
        f32x4 macc[2][4] = {};
        gemm_core<64>(uslot, 1024, 512, uslot, 1024, 0,
                      Wm2b, 512, Wm2b, 512, bm, 0, As, Bs, macc);
        float mb[4];
#pragma unroll
        for (int ni = 0; ni < 4; ++ni)
            mb[ni] = bm2[wc * 64 + ni * 16 + fr];
#pragma unroll
        for (int mi = 0; mi < 2; ++mi)
#pragma unroll
            for (int r = 0; r < 4; ++r) {
                const int rowl = wr * 32 + mi * 16 + rg * 4 + r;
#pragma unroll
                for (int ni = 0; ni < 4; ++ni) {
                    const int col = wc * 64 + ni * 16 + fr;
                    const float v = lrelu_f(macc[mi][ni][r] + mb[ni]);
                    meanL[rowl * 136 + col] = f2b(v);
                    if (bn == 0) {
                        const size_t o = (size_t)(bm + rowl) * (T_ * ZD) + col;
                        oz[o] = v; om[o] = v;
                    }
                }
            }
    }
    __syncthreads();

    // ---- stage 2: phi x-part (K=256) ----
    f32x4 acc[2][4] = {};
    gemm_core<64>(xb, XD, XD, xb, XD, 0,
                  Wcb, DD, Wcb, DD, bm, bn, As, Bs, acc);
    __syncthreads();

    // ---- stage 3: phi mean-part (K=128, 4 tiles), A from meanL ----
    {
        const unsigned short* WG = Wcb + XD;
        auto stageB = [&](int i, int buf) {
            unsigned short* lB = Bs + buf * 4096 + wave * 512;
            load_lds16(WG + (size_t)(bn + r0) * DD + i * 32 + c0 * 8, lB);
            load_lds16(WG + (size_t)(bn + r1) * DD + i * 32 + c1 * 8, lB + 2048);
        };
        stageB(0, 0); stageB(1, 1); stageB(2, 2);
        vmwait<2>(2);
        __builtin_amdgcn_s_barrier();
        int buf = 0;
        for (int i = 0; i < 4; ++i) {
            short8 af[2], bv[4];
#pragma unroll
            for (int mi = 0; mi < 2; ++mi)
                af[mi] = *reinterpret_cast<const short8*>(
                    meanL + (wr * 32 + mi * 16 + fr) * 136 + i * 32 + fg * 8);
#pragma unroll
            for (int ni = 0; ni < 4; ++ni)
                bv[ni] = *reinterpret_cast<const short8*>(
                    Bs + buf * 4096 + (wc * 64 + ni * 16 + fr) * 32 + cswz * 8);
#pragma unroll
            for (int mi = 0; mi < 2; ++mi)
#pragma unroll
                for (int ni = 0; ni < 4; ++ni)
                    acc[mi][ni] = mfma16(af[mi], bv[ni], acc[mi][ni]);
            if (i + 1 < 4) {
                asm volatile("" ::: "memory");
                __builtin_amdgcn_s_barrier();
                if (i + 3 < 4) stageB(i + 3, buf);
                int rem = 4 - (i + 2);
                if (rem > 2) rem = 2;
                vmwait<2>(rem);
                __builtin_amdgcn_s_barrier();
                buf = (buf == 2) ? 0 : buf + 1;
            }
        }
    }

    // ---- epilogue ----
    float pb[4];
#pragma unroll
    for (int ni = 0; ni < 4; ++ni)
        pb[ni] = bphi[bn + wc * 64 + ni * 16 + fr];
#pragma unroll
    for (int mi = 0; mi < 2; ++mi)
#pragma unroll
        for (int r = 0; r < 4; ++r) {
            const int row = bm + wr * 32 + mi * 16 + rg * 4 + r;
#pragma unroll
            for (int ni = 0; ni < 4; ++ni) {
                const float v = softplus_f(lrelu_f(acc[mi][ni][r] + pb[ni]));
                phib[(size_t)row * 1024 + (bn + wc * 64 + ni * 16 + fr)] = f2b(v);
            }
        }
}

// ---------------------------------------------------------------------------
// Batched logvar over ALL steps (off the recurrence path)
__global__ __launch_bounds__(256) void k_logvar_all(
    const unsigned short* __restrict__ umuvall,
    const unsigned short* __restrict__ Wv2b,
    const float* __restrict__ bv2,
    float* __restrict__ out_lv)               // [B][T][ZD]
{
    __shared__ unsigned short As[3 * 64 * 32];
    __shared__ unsigned short Bs[3 * 4096];
    const int bm = blockIdx.x * 64;
    f32x4 acc[2][4] = {};
    gemm_core<64>(umuvall + 512, 1024, 512, umuvall + 512, 1024, 0,
                  Wv2b, 512, Wv2b, 512, bm, 0, As, Bs, acc);

    const int tid = threadIdx.x, lane = tid & 63, wave = tid >> 6;
    const int wr = wave >> 1, wc = wave & 1, fr = lane & 15, rg = lane >> 4;
    float bb[4];
#pragma unroll
    for (int ni = 0; ni < 4; ++ni)
        bb[ni] = bv2[wc * 64 + ni * 16 + fr];
#pragma unroll
    for (int mi = 0; mi < 2; ++mi)
#pragma unroll
        for (int r = 0; r < 4; ++r) {
            const int row = bm + wr * 32 + mi * 16 + rg * 4 + r;   // t*B + b
            const int t = row >> 12, b = row & (B_ - 1);
#pragma unroll
            for (int ni = 0; ni < 4; ++ni) {
                const int col = wc * 64 + ni * 16 + fr;
                out_lv[(size_t)b * (T_ * ZD) + (size_t)t * ZD + col] =
                    lrelu_f(acc[mi][ni][r] + bb[ni]);
            }
        }
}

// gates GEMM: 512-thread 8-wave MT=128 core (R13) + gate-interleaved rows +
// fused LSTM. grid 512 = 2 blocks/CU -> 4 waves/SIMD.
// XCD-chunked swizzle: sid=(id&7)*64+(id>>3); bn=(sid&15)*128, bm=(sid>>4)*128.
__global__ __launch_bounds__(512) void k_gates_lstm(
    const unsigned short* __restrict__ phib,
    const unsigned short* __restrict__ hbin,
    const unsigned short* __restrict__ Wih,   // [2048][1024] reordered rows
    const unsigned short* __restrict__ Whh,   // [2048][512] reordered rows
    const float* __restrict__ br,             // reordered b_ih+b_hh
    float* __restrict__ c,
    unsigned short* __restrict__ hbout,
    float* __restrict__ ohl,                  // out_hlo + t*HD
    float* __restrict__ oh_next)              // out_hout + (t+1)*HD, or null
{
    __shared__ unsigned short As[3 * 4096];   // 24 KB
    __shared__ unsigned short Bs[3 * 4096];   // 24 KB
    const int id = blockIdx.x;
    const int sid = (id & 7) * 64 + (id >> 3);         // bijective for 512
    const int bm = (sid >> 4) * 128, bn = (sid & 15) * 128;
    f32x4 acc[2][4] = {};
    gemm_core8w(phib, 1024, 1024, hbin, 512, 512, Wih, 1024, Whh, 512, bm, bn, As, Bs, acc);

    const int tid = threadIdx.x, lane = tid & 63, wave = tid >> 6;
    const int wr = wave >> 1, wc = wave & 1, fr = lane & 15, rg = lane >> 4;
    const int n = ((bn + wc * 64) >> 6) * 16 + fr;     // hidden unit index
    float bb[4];
#pragma unroll
    for (int ni = 0; ni < 4; ++ni)
        bb[ni] = br[bn + wc * 64 + ni * 16 + fr];
#pragma unroll
    for (int mi = 0; mi < 2; ++mi)
#pragma unroll
        for (int r = 0; r < 4; ++r) {
            const int row = bm + wr * 32 + mi * 16 + rg * 4 + r;
            const size_t idx = (size_t)row * HD + n;
            const float gi = acc[mi][0][r] + bb[0];
            const float gf = acc[mi][1][r] + bb[1];
            const float gg = acc[mi][2][r] + bb[2];
            const float go = acc[mi][3][r] + bb[3];
            const float co = c[idx];
            const float cn = sigmoid_f(gf) * co + sigmoid_f(gi) * tanhf(gg);
            const float hn = sigmoid_f(go) * tanhf(cn);
            c[idx] = cn;
            hbout[idx] = f2b(hn);
            const size_t ob = (size_t)row * (T_ * HD) + n;
            ohl[ob] = hn;                       // h after update
            if (oh_next) oh_next[ob] = hn;      // == h BEFORE update at t+1
        }
}

// ---------------------------------------------------------------------------
// prep GEMM (MT=128 core, 2D grid) for Wc = Wphi @ A
__global__ __launch_bounds__(256) void k_gemm_plain(
    const unsigned short* __restrict__ A1, int lda1, int K1,
    const unsigned short* __restrict__ W1, int ldw1,
    unsigned short* __restrict__ DB, int lddb)
{
    __shared__ unsigned short As[3 * 128 * 32];
    __shared__ unsigned short Bs[3 * 4096];
    const int bm = blockIdx.y * 128, bn = blockIdx.x * 128;
    f32x4 acc[4][4] = {};
    gemm_core<128>(A1, lda1, K1, A1, lda1, 0, W1, ldw1, W1, ldw1, bm, bn, As, Bs, acc);

    const int tid = threadIdx.x, lane = tid & 63, wave = tid >> 6;
    const int wr = wave >> 1, wc = wave & 1, fr = lane & 15, rg = lane >> 4;
#pragma unroll
    for (int mi = 0; mi < 4; ++mi)
#pragma unroll
        for (int r = 0; r < 4; ++r) {
            const int row = bm + wr * 64 + mi * 16 + rg * 4 + r;
#pragma unroll
            for (int ni = 0; ni < 4; ++ni) {
                const int col = bn + wc * 64 + ni * 16 + fr;
                DB[(size_t)row * lddb + col] = f2b(acc[mi][ni][r]);
            }
        }
}

// ---------------------------------------------------------------------------
// One fused prep kernel: init-state + x-convert + all weight/bias reorders.
// Segment block counts:
//   init: 8192   conv-x: 20480   Wub: 3072   Wm2b: 64   Wv2b: 64
//   Wphib: 384   wg: 12288       At: 576     bias: 16
// ---------------------------------------------------------------------------
constexpr int SG0 = 8192;
constexpr int SG1 = SG0 + 20480;
constexpr int SG2 = SG1 + 3072;
constexpr int SG3 = SG2 + 64;
constexpr int SG4 = SG3 + 64;
constexpr int SG5 = SG4 + 384;
constexpr int SG6 = SG5 + 12288;
constexpr int SG7 = SG6 + 576;
constexpr int SG8 = SG7 + 16;

__global__ __launch_bounds__(256) void prep_all(
    const float* __restrict__ x,
    const float* __restrict__ A,
    const float* __restrict__ Wm1, const float* __restrict__ bm1,
    const float* __restrict__ Wm2,
    const float* __restrict__ Wv1, const float* __restrict__ bv1,
    const float* __restrict__ Wv2,
    const float* __restrict__ Wphi,
    const float* __restrict__ Wih, const float* __restrict__ Whh,
    const float* __restrict__ bih, const float* __restrict__ bhh,
    float* __restrict__ c, unsigned short* __restrict__ hb0,
    float* __restrict__ oh0,
    unsigned short* __restrict__ xball,
    unsigned short* __restrict__ Wub,
    unsigned short* __restrict__ Wm2b, unsigned short* __restrict__ Wv2b,
    unsigned short* __restrict__ Wphib,
    unsigned short* __restrict__ Wrih, unsigned short* __restrict__ Wrhh,
    unsigned short* __restrict__ Atb,
    float* __restrict__ bu, float* __restrict__ br)
{
    const int blk = blockIdx.x;
    const int tid = threadIdx.x;

    if (blk < SG0) {                       // init state
        const int i = blk * 256 + tid;
        c[i] = 0.f; hb0[i] = 0;
        const int b = i >> 9, nn = i & 511;
        oh0[(size_t)b * (T_ * HD) + nn] = 0.f;
    } else if (blk < SG1) {                // x -> bf16, [T][B][XD]
        const int i = (blk - SG0) * 256 + tid;
        const int d = i & 63;
        const int bt = i >> 6;
        const int b = bt / T_, t = bt % T_;
        float4 v = reinterpret_cast<const float4*>(x)[i];
        ushort4 o;
        o.x = f2b(v.x); o.y = f2b(v.y); o.z = f2b(v.z); o.w = f2b(v.w);
        reinterpret_cast<ushort4*>(xball)[((size_t)t * B_ + b) * (XD / 4) + d] = o;
    } else if (blk < SG2) {                // Wub = [Wm1; Wv1]
        const int e = (blk - SG1) * 256 + tid;
        const float v = e < 512 * 768 ? Wm1[e] : Wv1[e - 512 * 768];
        Wub[e] = f2b(v);
    } else if (blk < SG3) {                // Wm2b
        const int i = (blk - SG2) * 256 + tid;
        float4 v = reinterpret_cast<const float4*>(Wm2)[i];
        ushort4 o;
        o.x = f2b(v.x); o.y = f2b(v.y); o.z = f2b(v.z); o.w = f2b(v.w);
        reinterpret_cast<ushort4*>(Wm2b)[i] = o;
    } else if (blk < SG4) {                // Wv2b
        const int i = (blk - SG3) * 256 + tid;
        float4 v = reinterpret_cast<const float4*>(Wv2)[i];
        ushort4 o;
        o.x = f2b(v.x); o.y = f2b(v.y); o.z = f2b(v.z); o.w = f2b(v.w);
        reinterpret_cast<ushort4*>(Wv2b)[i] = o;
    } else if (blk < SG5) {                // Wphib
        const int i = (blk - SG4) * 256 + tid;
        float4 v = reinterpret_cast<const float4*>(Wphi)[i];
        ushort4 o;
        o.x = f2b(v.x); o.y = f2b(v.y); o.z = f2b(v.z); o.w = f2b(v.w);
        reinterpret_cast<ushort4*>(Wphib)[i] = o;
    } else if (blk < SG6) {                // gate-interleaved W_ih / W_hh
        const int e = (blk - SG5) * 256 + tid;   // over 2048*1536
        const int cc = e / 1536, kk = e % 1536;
        const int gate = (cc >> 4) & 3;
        const int n = ((cc >> 6) << 4) + (cc & 15);
        const int orig = gate * 512 + n;
        if (kk < 1024) Wrih[(size_t)cc * 1024 + kk] = f2b(Wih[(size_t)orig * 1024 + kk]);
        else           Wrhh[(size_t)cc * 512 + (kk - 1024)] = f2b(Whh[(size_t)orig * 512 + (kk - 1024)]);
    } else if (blk < SG7) {                // At = A^T
        const int i = (blk - SG6) * 256 + tid;   // 384*384
        const int k = i / DD, j = i % DD;
        Atb[(size_t)k * DD + j] = f2b(A[(size_t)j * DD + k]);
    } else {                               // biases
        const int i = (blk - SG7) * 256 + tid;   // 0..4095
        if (i < 1024) {
            bu[i] = i < 512 ? bm1[i] : bv1[i - 512];
        } else if (i >= 2048) {
            const int cb = i - 2048;
            const int gate = (cb >> 4) & 3;
            const int n = ((cb >> 6) << 4) + (cb & 15);
            const int orig = gate * 512 + n;
            br[cb] = bih[orig] + bhh[orig];
        }
    }
}

extern "C" void kernel_launch(void* const* d_in, const int* in_sizes, int n_in,
                              void* d_out, int out_size, void* d_ws, size_t ws_size,
                              hipStream_t stream)
{
    const float* x    = (const float*)d_in[0];
    const float* A    = (const float*)d_in[3];
    const float* Wm1  = (const float*)d_in[4];
    const float* bm1  = (const float*)d_in[5];
    const float* Wm2  = (const float*)d_in[6];
    const float* bm2  = (const float*)d_in[7];
    const float* Wv1  = (const float*)d_in[8];
    const float* bv1  = (const float*)d_in[9];
    const float* Wv2  = (const float*)d_in[10];
    const float* bv2  = (const float*)d_in[11];
    const float* Wphi = (const float*)d_in[12];
    const float* bphi = (const float*)d_in[13];
    const float* W_ih = (const float*)d_in[14];
    const float* W_hh = (const float*)d_in[15];
    const float* b_ih = (const float*)d_in[16];
    const float* b_hh = (const float*)d_in[17];

    float* out = (float*)d_out;
    float* out_z    = out;
    float* out_mean = out_z + (size_t)B_ * T_ * ZD;
    float* out_lv   = out_mean + (size_t)B_ * T_ * ZD;
    float* out_hout = out_lv + (size_t)B_ * T_ * ZD;
    float* out_hlo  = out_hout + (size_t)B_ * T_ * HD;

    // ---- workspace layout (~255 MB) ----
    char* wp = (char*)d_ws;
    auto alloc_f = [&](size_t n) { float* p = (float*)wp; wp += n * sizeof(float); return p; };
    auto alloc_b = [&](size_t n) { unsigned short* p = (unsigned short*)wp; wp += n * sizeof(unsigned short); return p; };

    float* c = alloc_f((size_t)B_ * HD);
    unsigned short* hb0     = alloc_b((size_t)B_ * HD);
    unsigned short* hb1     = alloc_b((size_t)B_ * HD);
    unsigned short* xball   = alloc_b((size_t)T_ * B_ * XD);
    unsigned short* umuvall = alloc_b((size_t)T_ * B_ * 1024);
    unsigned short* phib    = alloc_b((size_t)B_ * 1024);

    unsigned short* Wub   = alloc_b((size_t)1024 * 768);
    unsigned short* Wm2b  = alloc_b((size_t)ZD * HD);
    unsigned short* Wv2b  = alloc_b((size_t)ZD * HD);
    unsigned short* Atb   = alloc_b((size_t)DD * DD);
    unsigned short* Wphib = alloc_b((size_t)1024 * DD);
    unsigned short* Wcb   = alloc_b((size_t)1024 * DD);
    unsigned short* Wrih  = alloc_b((size_t)2048 * 1024);
    unsigned short* Wrhh  = alloc_b((size_t)2048 * 512);

    float* bu = alloc_f(1024);
    float* br = alloc_f(2048);

    const dim3 blk(256);

    // ---- prep: one fused kernel + the Wc GEMM ----
    prep_all<<<dim3(SG8), blk, 0, stream>>>(
        x, A, Wm1, bm1, Wm2, Wv1, bv1, Wv2, Wphi, W_ih, W_hh, b_ih, b_hh,
        c, hb0, out_hout, xball, Wub, Wm2b, Wv2b, Wphib, Wrih, Wrhh, Atb, bu, br);
    // Wc = Wphi @ A  ([1024 x 384] bf16): folds the agg GEMM into phi
    k_gemm_plain<<<dim3(DD / 128, 1024 / 128), blk, 0, stream>>>(
        Wphib, DD, DD, Atb, DD, Wcb, DD);

    for (int t = 0; t < T_; ++t) {
        unsigned short* hbt = (t & 1) ? hb1 : hb0;   // h_t  (read)
        unsigned short* hbn = (t & 1) ? hb0 : hb1;   // h_{t+1} (written by epilogue)
        const unsigned short* xb = xball + (size_t)t * B_ * XD;
        unsigned short* uslot = umuvall + (size_t)t * B_ * 1024;

        // [u_m | u_v] = lrelu([x_t, h] @ Wub^T + bu)   [B, 1024]  MT=64, grid 512
        k_gemm_act<1, 64, 7, 3><<<dim3(512), blk, 0, stream>>>(
            xb, XD, XD, hbt, HD, HD,
            Wub, XD + HD, Wub + XD, XD + HD,
            bu, uslot, 1024);

        // mean (in-LDS) + phi fused; bn==0 writes out_z/out_mean
        k_meanphi<<<dim3(512), blk, 0, stream>>>(
            uslot, xb, Wm2b, Wcb, bm2, bphi,
            out_z + (size_t)t * ZD, out_mean + (size_t)t * ZD, phib);

        // gates (reordered) + fused LSTM   8-wave MT=128 core, grid 512
        k_gates_lstm<<<dim3(512), dim3(512), 0, stream>>>(
            phib, hbt, Wrih, Wrhh, br,
            c, hbn,
            out_hlo + (size_t)t * HD,
            (t + 1 < T_) ? out_hout + (size_t)(t + 1) * HD : nullptr);
    }

    // logvar for ALL steps in one batched GEMM (off the recurrence path)
    k_logvar_all<<<dim3(T_ * B_ / 64), blk, 0, stream>>>(
        umuvall, Wv2b, bv2, out_lv);
}

// Round 15
// 1887.139 us; speedup vs baseline: 1.3104x; 1.0006x over previous
//
#include <hip/hip_runtime.h>
#include <math.h>

// Problem constants
constexpr int B_ = 4096;
constexpr int T_ = 20;
constexpr int XD = 256;   // X_DIM
constexpr int ZD = 128;   // Z_DIM
constexpr int HD = 512;   // H_DIM
constexpr int DD = 384;   // X+Z

using short8 = __attribute__((ext_vector_type(8))) short;
using bf16x8 = __attribute__((ext_vector_type(8))) __bf16;
using f32x4  = __attribute__((ext_vector_type(4))) float;

__device__ __forceinline__ float lrelu_f(float v) { return v > 0.f ? v : 0.2f * v; }
__device__ __forceinline__ float softplus_f(float v) {
    return log1pf(expf(-fabsf(v))) + fmaxf(v, 0.f);
}
__device__ __forceinline__ float sigmoid_f(float v) { return 1.f / (1.f + expf(-v)); }

// float -> bf16 (round to nearest even), finite inputs
__device__ __forceinline__ unsigned short f2b(float f) {
    unsigned u = __builtin_bit_cast(unsigned, f);
    u += 0x7fff + ((u >> 16) & 1);
    return (unsigned short)(u >> 16);
}

__device__ __forceinline__ f32x4 mfma16(short8 a, short8 b, f32x4 c) {
    return __builtin_amdgcn_mfma_f32_16x16x32_bf16(
        __builtin_bit_cast(bf16x8, a), __builtin_bit_cast(bf16x8, b), c, 0, 0, 0);
}

// async global->LDS, 16 B per lane; lds base must be wave-uniform
__device__ __forceinline__ void load_lds16(const unsigned short* g, unsigned short* l) {
    __builtin_amdgcn_global_load_lds(
        (const __attribute__((address_space(1))) unsigned int*)g,
        (__attribute__((address_space(3))) unsigned int*)l,
        16, 0, 0);
}

// wait until at most `rem` K-tiles (LPT loads each per wave) remain outstanding
template <int LPT>
__device__ __forceinline__ void vmwait(int rem) {
    if (rem >= 2) {
        if constexpr (LPT == 4)      asm volatile("s_waitcnt vmcnt(8)" ::: "memory");
        else if constexpr (LPT == 3) asm volatile("s_waitcnt vmcnt(6)" ::: "memory");
        else if constexpr (LPT == 2) asm volatile("s_waitcnt vmcnt(4)" ::: "memory");
        else                         asm volatile("s_waitcnt vmcnt(2)" ::: "memory");
    } else if (rem == 1) {
        if constexpr (LPT == 4)      asm volatile("s_waitcnt vmcnt(4)" ::: "memory");
        else if constexpr (LPT == 3) asm volatile("s_waitcnt vmcnt(3)" ::: "memory");
        else if constexpr (LPT == 2) asm volatile("s_waitcnt vmcnt(2)" ::: "memory");
        else                         asm volatile("s_waitcnt vmcnt(1)" ::: "memory");
    } else {
        asm volatile("s_waitcnt vmcnt(0)" ::: "memory");
    }
}

// ---------------------------------------------------------------------------
// MTx128-tile bf16 MFMA GEMM core (MT in {64,128}), 256 threads, 3-deep
// counted-vmcnt pipeline. Chunk swizzle c' = c ^ ((row>>1)&3) on global source
// AND ds_read (rule #21).
// ---------------------------------------------------------------------------
template <int MT>
__device__ __forceinline__ void gemm_core(
    const unsigned short* A1, int lda1, int K1,
    const unsigned short* A2, int lda2, int K2,
    const unsigned short* W1, int ldw1,
    const unsigned short* W2, int ldw2,
    int bm, int bn,
    unsigned short* As, unsigned short* Bs,   // As: 3*MT*32, Bs: 3*4096 shorts
    f32x4 (&acc)[MT / 32][4])
{
    constexpr int MI   = MT / 32;
    constexpr int WRS  = MT / 2;
    constexpr int NA   = MT / 64;
    constexpr int LPT  = NA + 2;
    constexpr int ABUF = MT * 32;

    const int tid  = threadIdx.x;
    const int lane = tid & 63;
    const int wave = tid >> 6;
    const int wr = wave >> 1, wc = wave & 1;
    const int fr = lane & 15, fg = lane >> 4;
    const int cswz = fg ^ ((fr >> 1) & 3);

    const int r0 = tid >> 2,          c0 = (tid & 3) ^ ((r0 >> 1) & 3);
    const int r1 = (256 + tid) >> 2,  c1 = ((256 + tid) & 3) ^ ((r1 >> 1) & 3);

    const int n1 = K1 / 32;
    const int nt = n1 + K2 / 32;

    auto stage = [&](int i, int buf) {
        const unsigned short* Ag;
        const unsigned short* Wg;
        int lda, ldw, kb;
        if (i < n1) { Ag = A1; Wg = W1; lda = lda1; ldw = ldw1; kb = i * 32; }
        else        { Ag = A2; Wg = W2; lda = lda2; ldw = ldw2; kb = (i - n1) * 32; }
        unsigned short* lA = As + buf * ABUF + wave * 512;
        unsigned short* lB = Bs + buf * 4096 + wave * 512;
        load_lds16(Ag + (size_t)(bm + r0) * lda + kb + c0 * 8, lA);
        if constexpr (NA == 2)
            load_lds16(Ag + (size_t)(bm + r1) * lda + kb + c1 * 8, lA + 2048);
        load_lds16(Wg + (size_t)(bn + r0) * ldw + kb + c0 * 8, lB);
        load_lds16(Wg + (size_t)(bn + r1) * ldw + kb + c1 * 8, lB + 2048);
    };

    auto compute = [&](int buf) {
        const unsigned short* Ab_ = As + buf * ABUF;
        const unsigned short* Bb_ = Bs + buf * 4096;
        short8 af[MI], bv[4];
#pragma unroll
        for (int mi = 0; mi < MI; ++mi)
            af[mi] = *reinterpret_cast<const short8*>(Ab_ + (wr * WRS + mi * 16 + fr) * 32 + cswz * 8);
#pragma unroll
        for (int ni = 0; ni < 4; ++ni)
            bv[ni] = *reinterpret_cast<const short8*>(Bb_ + (wc * 64 + ni * 16 + fr) * 32 + cswz * 8);
#pragma unroll
        for (int mi = 0; mi < MI; ++mi)
#pragma unroll
            for (int ni = 0; ni < 4; ++ni)
                acc[mi][ni] = mfma16(af[mi], bv[ni], acc[mi][ni]);
    };

    stage(0, 0);
    if (1 < nt) stage(1, 1);
    if (2 < nt) stage(2, 2);
    {
        int rem = (nt - 1 < 2) ? (nt - 1) : 2;
        vmwait<LPT>(rem);
    }
    __builtin_amdgcn_s_barrier();

    int buf = 0;
    for (int i = 0; i < nt; ++i) {
        compute(buf);
        if (i + 1 < nt) {
            asm volatile("" ::: "memory");
            __builtin_amdgcn_s_barrier();
            if (i + 3 < nt) stage(i + 3, buf);
            int rem = nt - (i + 2);
            if (rem > 2) rem = 2;
            vmwait<LPT>(rem);
            __builtin_amdgcn_s_barrier();
            buf = (buf == 2) ? 0 : buf + 1;
        }
    }
}

// ---------------------------------------------------------------------------
// 128x128-tile core, 512 threads = 8 waves (4M x 2N), each wave 32x64 output
// (acc 2x4). Same K-tile order and fragment data as gemm_core<128> ->
// bit-identical accumulation. LPT=2/wave (1 A + 1 B load per K-tile).
// ---------------------------------------------------------------------------
__device__ __forceinline__ void gemm_core8w(
    const unsigned short* A1, int lda1, int K1,
    const unsigned short* A2, int lda2, int K2,
    const unsigned short* W1, int ldw1,
    const unsigned short* W2, int ldw2,
    int bm, int bn,
    unsigned short* As, unsigned short* Bs,   // each 3*4096 shorts
    f32x4 (&acc)[2][4])
{
    const int tid  = threadIdx.x;          // 0..511
    const int lane = tid & 63;
    const int wave = tid >> 6;             // 0..7
    const int wr = wave >> 1, wc = wave & 1;
    const int fr = lane & 15, fg = lane >> 4;
    const int cswz = fg ^ ((fr >> 1) & 3);

    const int r0 = tid >> 2;                       // 0..127
    const int c0 = (tid & 3) ^ ((r0 >> 1) & 3);

    const int n1 = K1 / 32;
    const int nt = n1 + K2 / 32;

    auto stage = [&](int i, int buf) {
        const unsigned short* Ag;
        const unsigned short* Wg;
        int lda, ldw, kb;
        if (i < n1) { Ag = A1; Wg = W1; lda = lda1; ldw = ldw1; kb = i * 32; }
        else        { Ag = A2; Wg = W2; lda = lda2; ldw = ldw2; kb = (i - n1) * 32; }
        unsigned short* lA = As + buf * 4096 + wave * 512;   // 8 waves x 512 = 4096
        unsigned short* lB = Bs + buf * 4096 + wave * 512;
        load_lds16(Ag + (size_t)(bm + r0) * lda + kb + c0 * 8, lA);
        load_lds16(Wg + (size_t)(bn + r0) * ldw + kb + c0 * 8, lB);
    };

    auto compute = [&](int buf) {
        const unsigned short* Ab_ = As + buf * 4096;
        const unsigned short* Bb_ = Bs + buf * 4096;
        short8 af[2], bv[4];
#pragma unroll
        for (int mi = 0; mi < 2; ++mi)
            af[mi] = *reinterpret_cast<const short8*>(Ab_ + (wr * 32 + mi * 16 + fr) * 32 + cswz * 8);
#pragma unroll
        for (int ni = 0; ni < 4; ++ni)
            bv[ni] = *reinterpret_cast<const short8*>(Bb_ + (wc * 64 + ni * 16 + fr) * 32 + cswz * 8);
#pragma unroll
        for (int mi = 0; mi < 2; ++mi)
#pragma unroll
            for (int ni = 0; ni < 4; ++ni)
                acc[mi][ni] = mfma16(af[mi], bv[ni], acc[mi][ni]);
    };

    stage(0, 0);
    if (1 < nt) stage(1, 1);
    if (2 < nt) stage(2, 2);
    {
        int rem = (nt - 1 < 2) ? (nt - 1) : 2;
        vmwait<2>(rem);
    }
    __builtin_amdgcn_s_barrier();

    int buf = 0;
    for (int i = 0; i < nt; ++i) {
        compute(buf);
        if (i + 1 < nt) {
            asm volatile("" ::: "memory");
            __builtin_amdgcn_s_barrier();
            if (i + 3 < nt) stage(i + 3, buf);
            int rem = nt - (i + 2);
            if (rem > 2) rem = 2;
            vmwait<2>(rem);
            __builtin_amdgcn_s_barrier();
            buf = (buf == 2) ? 0 : buf + 1;
        }
    }
}

// ---------------------------------------------------------------------------
// 64x128-tile core, 512 threads = 8 waves (4M x 2N), each wave 16x64 output
// (acc 1x4). Role-split staging (R15 FIX — chunk counts now add up):
//   A tile 64x32 bf16 = 4096 B = 256 chunks -> waves 0-3, 1 load/lane
//   B tile 128x32 bf16 = 8192 B = 512 chunks -> waves 4-7, 2 loads/lane
// Per-wave LPT: A-waves 1, B-waves 2 -> wave-uniform branched vmwait.
// Same K-tile order/fragments as gemm_core<64> -> bit-identical.
// ---------------------------------------------------------------------------
__device__ __forceinline__ void gemm_core8w64(
    const unsigned short* A1, int lda1, int K1,
    const unsigned short* A2, int lda2, int K2,
    const unsigned short* W1, int ldw1,
    const unsigned short* W2, int ldw2,
    int bm, int bn,
    unsigned short* As, unsigned short* Bs,   // As: 3*2048, Bs: 3*4096 shorts
    f32x4 (&acc)[1][4])
{
    const int tid  = threadIdx.x;          // 0..511
    const int lane = tid & 63;
    const int wave = tid >> 6;             // 0..7
    const int wr = wave >> 1, wc = wave & 1;
    const int fr = lane & 15, fg = lane >> 4;
    const int cswz = fg ^ ((fr >> 1) & 3);

    // A role (waves 0-3): chunk ca = wave*64+lane (0..255)
    const int ca = wave * 64 + lane;
    const int ar = ca >> 2, ac = (ca & 3) ^ ((ar >> 1) & 3);
    // B role (waves 4-7): chunk groups g0=(wave-4)*2, g1=g0+1; chunk g*64+lane
    const int g0 = (wave - 4) * 2, g1 = g0 + 1;
    const int cb0 = g0 * 64 + lane, cb1 = g1 * 64 + lane;
    const int br0 = cb0 >> 2, bc0 = (cb0 & 3) ^ ((br0 >> 1) & 3);
    const int br1 = cb1 >> 2, bc1 = (cb1 & 3) ^ ((br1 >> 1) & 3);

    const int n1 = K1 / 32;
    const int nt = n1 + K2 / 32;

    auto stage = [&](int i, int buf) {
        const unsigned short* Ag;
        const unsigned short* Wg;
        int lda, ldw, kb;
        if (i < n1) { Ag = A1; Wg = W1; lda = lda1; ldw = ldw1; kb = i * 32; }
        else        { Ag = A2; Wg = W2; lda = lda2; ldw = ldw2; kb = (i - n1) * 32; }
        if (wave < 4) {
            unsigned short* lA = As + buf * 2048 + wave * 512;
            load_lds16(Ag + (size_t)(bm + ar) * lda + kb + ac * 8, lA);
        } else {
            unsigned short* lB = Bs + buf * 4096;
            load_lds16(Wg + (size_t)(bn + br0) * ldw + kb + bc0 * 8, lB + g0 * 512);
            load_lds16(Wg + (size_t)(bn + br1) * ldw + kb + bc1 * 8, lB + g1 * 512);
        }
    };

    auto wait = [&](int rem) {
        if (wave < 4) vmwait<1>(rem);
        else          vmwait<2>(rem);
    };

    auto compute = [&](int buf) {
        const unsigned short* Ab_ = As + buf * 2048;
        const unsigned short* Bb_ = Bs + buf * 4096;
        short8 af = *reinterpret_cast<const short8*>(Ab_ + (wr * 16 + fr) * 32 + cswz * 8);
        short8 bv[4];
#pragma unroll
        for (int ni = 0; ni < 4; ++ni)
            bv[ni] = *reinterpret_cast<const short8*>(Bb_ + (wc * 64 + ni * 16 + fr) * 32 + cswz * 8);
#pragma unroll
        for (int ni = 0; ni < 4; ++ni)
            acc[0][ni] = mfma16(af, bv[ni], acc[0][ni]);
    };

    stage(0, 0);
    if (1 < nt) stage(1, 1);
    if (2 < nt) stage(2, 2);
    {
        int rem = (nt - 1 < 2) ? (nt - 1) : 2;
        wait(rem);
    }
    __builtin_amdgcn_s_barrier();

    int buf = 0;
    for (int i = 0; i < nt; ++i) {
        compute(buf);
        if (i + 1 < nt) {
            asm volatile("" ::: "memory");
            __builtin_amdgcn_s_barrier();
            if (i + 3 < nt) stage(i + 3, buf);
            int rem = nt - (i + 2);
            if (rem > 2) rem = 2;
            wait(rem);
            __builtin_amdgcn_s_barrier();
            buf = (buf == 2) ? 0 : buf + 1;
        }
    }
}

// GEMM + bias + activation -> bf16 output. ACT: 0 none, 1 lrelu, 2 softplus(lrelu)
// 1D grid decode: bn = (id & NMASK)*128, bm = (id >> NSHIFT)*MT
template <int ACT, int MT, int NMASK, int NSHIFT>
__global__ __launch_bounds__(256) void k_gemm_act(
    const unsigned short* __restrict__ A1, int lda1, int K1,
    const unsigned short* __restrict__ A2, int lda2, int K2,
    const unsigned short* __restrict__ W1, int ldw1,
    const unsigned short* __restrict__ W2, int ldw2,
    const float* __restrict__ bias,
    unsigned short* __restrict__ DB, int lddb)
{
    __shared__ unsigned short As[3 * MT * 32];
    __shared__ unsigned short Bs[3 * 4096];
    const int id = blockIdx.x;
    const int bm = (id >> NSHIFT) * MT, bn = (id & NMASK) * 128;
    f32x4 acc[MT / 32][4] = {};
    gemm_core<MT>(A1, lda1, K1, A2, lda2, K2, W1, ldw1, W2, ldw2, bm, bn, As, Bs, acc);

    constexpr int MI = MT / 32, WRS = MT / 2;
    const int tid = threadIdx.x, lane = tid & 63, wave = tid >> 6;
    const int wr = wave >> 1, wc = wave & 1, fr = lane & 15, rg = lane >> 4;
    float bb[4];
#pragma unroll
    for (int ni = 0; ni < 4; ++ni)
        bb[ni] = bias ? bias[bn + wc * 64 + ni * 16 + fr] : 0.f;
#pragma unroll
    for (int mi = 0; mi < MI; ++mi)
#pragma unroll
        for (int r = 0; r < 4; ++r) {
            const int row = bm + wr * WRS + mi * 16 + rg * 4 + r;
#pragma unroll
            for (int ni = 0; ni < 4; ++ni) {
                float v = acc[mi][ni][r] + bb[ni];
                if (ACT == 1) v = lrelu_f(v);
                else if (ACT == 2) v = softplus_f(lrelu_f(v));
                DB[(size_t)row * lddb + (bn + wc * 64 + ni * 16 + fr)] = f2b(v);
            }
        }
}

// u GEMM via the 8-wave 64x128 core: grid 512 (bm=(id>>3)*64, bn=(id&7)*128),
// 512 threads -> 2 blocks/CU -> 4 waves/SIMD.
__global__ __launch_bounds__(512) void k_u_8w(
    const unsigned short* __restrict__ A1, int lda1, int K1,
    const unsigned short* __restrict__ A2, int lda2, int K2,
    const unsigned short* __restrict__ W1, int ldw1,
    const unsigned short* __restrict__ W2, int ldw2,
    const float* __restrict__ bias,
    unsigned short* __restrict__ DB, int lddb)
{
    __shared__ unsigned short As[3 * 2048];   // 12 KB
    __shared__ unsigned short Bs[3 * 4096];   // 24 KB
    const int id = blockIdx.x;
    const int bm = (id >> 3) * 64, bn = (id & 7) * 128;
    f32x4 acc[1][4] = {};
    gemm_core8w64(A1, lda1, K1, A2, lda2, K2, W1, ldw1, W2, ldw2, bm, bn, As, Bs, acc);

    const int tid = threadIdx.x, lane = tid & 63, wave = tid >> 6;
    const int wr = wave >> 1, wc = wave & 1, fr = lane & 15, rg = lane >> 4;
    float bb[4];
#pragma unroll
    for (int ni = 0; ni < 4; ++ni)
        bb[ni] = bias[bn + wc * 64 + ni * 16 + fr];
#pragma unroll
    for (int r = 0; r < 4; ++r) {
        const int row = bm + wr * 16 + rg * 4 + r;
#pragma unroll
        for (int ni = 0; ni < 4; ++ni) {
            float v = lrelu_f(acc[0][ni][r] + bb[ni]);
            DB[(size_t)row * lddb + (bn + wc * 64 + ni * 16 + fr)] = f2b(v);
        }
    }
}

// ---------------------------------------------------------------------------
// Fused mean + phi kernel: grid 512: bm=(id>>3)*64 rows, bn=(id&7)*128 phi-cols.
// ---------------------------------------------------------------------------
__global__ __launch_bounds__(256) void k_meanphi(
    const unsigned short* __restrict__ uslot,  // umuvall + t*B*1024, [B][1024]
    const unsigned short* __restrict__ xb,     // [B][256]
    const unsigned short* __restrict__ Wm2b,   // [128][512]
    const unsigned short* __restrict__ Wcb,    // [1024][384]
    const float* __restrict__ bm2,             // [128]
    const float* __restrict__ bphi,            // [1024]
    float* __restrict__ oz, float* __restrict__ om,   // + t*ZD, stride T*ZD
    unsigned short* __restrict__ phib)
{
    __shared__ unsigned short As[3 * 64 * 32];
    __shared__ unsigned short Bs[3 * 4096];
    __shared__ unsigned short meanL[64 * 136];   // pad 136: conflict-light

    const int id = blockIdx.x;
    const int bm = (id >> 3) * 64, bn = (id & 7) * 128;
    const int tid = threadIdx.x, lane = tid & 63, wave = tid >> 6;
    const int wr = wave >> 1, wc = wave & 1, fr = lane & 15, fg = lane >> 4, rg = lane >> 4;
    const int cswz = fg ^ ((fr >> 1) & 3);
    const int r0 = tid >> 2,          c0 = (tid & 3) ^ ((r0 >> 1) & 3);
    const int r1 = (256 + tid) >> 2,  c1 = ((256 + tid) & 3) ^ ((r1 >> 1) & 3);

    // ---- stage 1: mean ----
    {
        f32x4 macc[2][4] = {};
        gemm_core<64>(uslot, 1024, 512, uslot, 1024, 0,
                      Wm2b, 512, Wm2b, 512, bm, 0, As, Bs, macc);
        float mb[4];
#pragma unroll
        for (int ni = 0; ni < 4; ++ni)
            mb[ni] = bm2[wc * 64 + ni * 16 + fr];
#pragma unroll
        for (int mi = 0; mi < 2; ++mi)
#pragma unroll
            for (int r = 0; r < 4; ++r) {
                const int rowl = wr * 32 + mi * 16 + rg * 4 + r;
#pragma unroll
                for (int ni = 0; ni < 4; ++ni) {
                    const int col = wc * 64 + ni * 16 + fr;
                    const float v = lrelu_f(macc[mi][ni][r] + mb[ni]);
                    meanL[rowl * 136 + col] = f2b(v);
                    if (bn == 0) {
                        const size_t o = (size_t)(bm + rowl) * (T_ * ZD) + col;
                        oz[o] = v; om[o] = v;
                    }
                }
            }
    }
    __syncthreads();

    // ---- stage 2: phi x-part (K=256) ----
    f32x4 acc[2][4] = {};
    gemm_core<64>(xb, XD, XD, xb, XD, 0,
                  Wcb, DD, Wcb, DD, bm, bn, As, Bs, acc);
    __syncthreads();

    // ---- stage 3: phi mean-part (K=128, 4 tiles), A from meanL ----
    {
        const unsigned short* WG = Wcb + XD;
        auto stageB = [&](int i, int buf) {
            unsigned short* lB = Bs + buf * 4096 + wave * 512;
            load_lds16(WG + (size_t)(bn + r0) * DD + i * 32 + c0 * 8, lB);
            load_lds16(WG + (size_t)(bn + r1) * DD + i * 32 + c1 * 8, lB + 2048);
        };
        stageB(0, 0); stageB(1, 1); stageB(2, 2);
        vmwait<2>(2);
        __builtin_amdgcn_s_barrier();
        int buf = 0;
        for (int i = 0; i < 4; ++i) {
            short8 af[2], bv[4];
#pragma unroll
            for (int mi = 0; mi < 2; ++mi)
                af[mi] = *reinterpret_cast<const short8*>(
                    meanL + (wr * 32 + mi * 16 + fr) * 136 + i * 32 + fg * 8);
#pragma unroll
            for (int ni = 0; ni < 4; ++ni)
                bv[ni] = *reinterpret_cast<const short8*>(
                    Bs + buf * 4096 + (wc * 64 + ni * 16 + fr) * 32 + cswz * 8);
#pragma unroll
            for (int mi = 0; mi < 2; ++mi)
#pragma unroll
                for (int ni = 0; ni < 4; ++ni)
                    acc[mi][ni] = mfma16(af[mi], bv[ni], acc[mi][ni]);
            if (i + 1 < 4) {
                asm volatile("" ::: "memory");
                __builtin_amdgcn_s_barrier();
                if (i + 3 < 4) stageB(i + 3, buf);
                int rem = 4 - (i + 2);
                if (rem > 2) rem = 2;
                vmwait<2>(rem);
                __builtin_amdgcn_s_barrier();
                buf = (buf == 2) ? 0 : buf + 1;
            }
        }
    }

    // ---- epilogue ----
    float pb[4];
#pragma unroll
    for (int ni = 0; ni < 4; ++ni)
        pb[ni] = bphi[bn + wc * 64 + ni * 16 + fr];
#pragma unroll
    for (int mi = 0; mi < 2; ++mi)
#pragma unroll
        for (int r = 0; r < 4; ++r) {
            const int row = bm + wr * 32 + mi * 16 + rg * 4 + r;
#pragma unroll
            for (int ni = 0; ni < 4; ++ni) {
                const float v = softplus_f(lrelu_f(acc[mi][ni][r] + pb[ni]));
                phib[(size_t)row * 1024 + (bn + wc * 64 + ni * 16 + fr)] = f2b(v);
            }
        }
}

// ---------------------------------------------------------------------------
// Batched logvar over ALL steps (off the recurrence path)
__global__ __launch_bounds__(256) void k_logvar_all(
    const unsigned short* __restrict__ umuvall,
    const unsigned short* __restrict__ Wv2b,
    const float* __restrict__ bv2,
    float* __restrict__ out_lv)               // [B][T][ZD]
{
    __shared__ unsigned short As[3 * 64 * 32];
    __shared__ unsigned short Bs[3 * 4096];
    const int bm = blockIdx.x * 64;
    f32x4 acc[2][4] = {};
    gemm_core<64>(umuvall + 512, 1024, 512, umuvall + 512, 1024, 0,
                  Wv2b, 512, Wv2b, 512, bm, 0, As, Bs, acc);

    const int tid = threadIdx.x, lane = tid & 63, wave = tid >> 6;
    const int wr = wave >> 1, wc = wave & 1, fr = lane & 15, rg = lane >> 4;
    float bb[4];
#pragma unroll
    for (int ni = 0; ni < 4; ++ni)
        bb[ni] = bv2[wc * 64 + ni * 16 + fr];
#pragma unroll
    for (int mi = 0; mi < 2; ++mi)
#pragma unroll
        for (int r = 0; r < 4; ++r) {
            const int row = bm + wr * 32 + mi * 16 + rg * 4 + r;   // t*B + b
            const int t = row >> 12, b = row & (B_ - 1);
#pragma unroll
            for (int ni = 0; ni < 4; ++ni) {
                const int col = wc * 64 + ni * 16 + fr;
                out_lv[(size_t)b * (T_ * ZD) + (size_t)t * ZD + col] =
                    lrelu_f(acc[mi][ni][r] + bb[ni]);
            }
        }
}

// gates GEMM: 512-thread 8-wave MT=128 core + gate-interleaved rows + fused
// LSTM. grid 512 = 2 blocks/CU -> 4 waves/SIMD.
// XCD-chunked swizzle: sid=(id&7)*64+(id>>3); bn=(sid&15)*128, bm=(sid>>4)*128.
__global__ __launch_bounds__(512) void k_gates_lstm(
    const unsigned short* __restrict__ phib,
    const unsigned short* __restrict__ hbin,
    const unsigned short* __restrict__ Wih,   // [2048][1024] reordered rows
    const unsigned short* __restrict__ Whh,   // [2048][512] reordered rows
    const float* __restrict__ br,             // reordered b_ih+b_hh
    float* __restrict__ c,
    unsigned short* __restrict__ hbout,
    float* __restrict__ ohl,                  // out_hlo + t*HD
    float* __restrict__ oh_next)              // out_hout + (t+1)*HD, or null
{
    __shared__ unsigned short As[3 * 4096];   // 24 KB
    __shared__ unsigned short Bs[3 * 4096];   // 24 KB
    const int id = blockIdx.x;
    const int sid = (id & 7) * 64 + (id >> 3);         // bijective for 512
    const int bm = (sid >> 4) * 128, bn = (sid & 15) * 128;
    f32x4 acc[2][4] = {};
    gemm_core8w(phib, 1024, 1024, hbin, 512, 512, Wih, 1024, Whh, 512, bm, bn, As, Bs, acc);

    const int tid = threadIdx.x, lane = tid & 63, wave = tid >> 6;
    const int wr = wave >> 1, wc = wave & 1, fr = lane & 15, rg = lane >> 4;
    const int n = ((bn + wc * 64) >> 6) * 16 + fr;     // hidden unit index
    float bb[4];
#pragma unroll
    for (int ni = 0; ni < 4; ++ni)
        bb[ni] = br[bn + wc * 64 + ni * 16 + fr];
#pragma unroll
    for (int mi = 0; mi < 2; ++mi)
#pragma unroll
        for (int r = 0; r < 4; ++r) {
            const int row = bm + wr * 32 + mi * 16 + rg * 4 + r;
            const size_t idx = (size_t)row * HD + n;
            const float gi = acc[mi][0][r] + bb[0];
            const float gf = acc[mi][1][r] + bb[1];
            const float gg = acc[mi][2][r] + bb[2];
            const float go = acc[mi][3][r] + bb[3];
            const float co = c[idx];
            const float cn = sigmoid_f(gf) * co + sigmoid_f(gi) * tanhf(gg);
            const float hn = sigmoid_f(go) * tanhf(cn);
            c[idx] = cn;
            hbout[idx] = f2b(hn);
            const size_t ob = (size_t)row * (T_ * HD) + n;
            ohl[ob] = hn;                       // h after update
            if (oh_next) oh_next[ob] = hn;      // == h BEFORE update at t+1
        }
}

// ---------------------------------------------------------------------------
// prep GEMM (MT=128 core, 2D grid) for Wc = Wphi @ A
__global__ __launch_bounds__(256) void k_gemm_plain(
    const unsigned short* __restrict__ A1, int lda1, int K1,
    const unsigned short* __restrict__ W1, int ldw1,
    unsigned short* __restrict__ DB, int lddb)
{
    __shared__ unsigned short As[3 * 128 * 32];
    __shared__ unsigned short Bs[3 * 4096];
    const int bm = blockIdx.y * 128, bn = blockIdx.x * 128;
    f32x4 acc[4][4] = {};
    gemm_core<128>(A1, lda1, K1, A1, lda1, 0, W1, ldw1, W1, ldw1, bm, bn, As, Bs, acc);

    const int tid = threadIdx.x, lane = tid & 63, wave = tid >> 6;
    const int wr = wave >> 1, wc = wave & 1, fr = lane & 15, rg = lane >> 4;
#pragma unroll
    for (int mi = 0; mi < 4; ++mi)
#pragma unroll
        for (int r = 0; r < 4; ++r) {
            const int row = bm + wr * 64 + mi * 16 + rg * 4 + r;
#pragma unroll
            for (int ni = 0; ni < 4; ++ni) {
                const int col = bn + wc * 64 + ni * 16 + fr;
                DB[(size_t)row * lddb + col] = f2b(acc[mi][ni][r]);
            }
        }
}

// ---------------------------------------------------------------------------
// One fused prep kernel: init-state + x-convert + all weight/bias reorders.
// Segment block counts:
//   init: 8192   conv-x: 20480   Wub: 3072   Wm2b: 64   Wv2b: 64
//   Wphib: 384   wg: 12288       At: 576     bias: 16
// ---------------------------------------------------------------------------
constexpr int SG0 = 8192;
constexpr int SG1 = SG0 + 20480;
constexpr int SG2 = SG1 + 3072;
constexpr int SG3 = SG2 + 64;
constexpr int SG4 = SG3 + 64;
constexpr int SG5 = SG4 + 384;
constexpr int SG6 = SG5 + 12288;
constexpr int SG7 = SG6 + 576;
constexpr int SG8 = SG7 + 16;

__global__ __launch_bounds__(256) void prep_all(
    const float* __restrict__ x,
    const float* __restrict__ A,
    const float* __restrict__ Wm1, const float* __restrict__ bm1,
    const float* __restrict__ Wm2,
    const float* __restrict__ Wv1, const float* __restrict__ bv1,
    const float* __restrict__ Wv2,
    const float* __restrict__ Wphi,
    const float* __restrict__ Wih, const float* __restrict__ Whh,
    const float* __restrict__ bih, const float* __restrict__ bhh,
    float* __restrict__ c, unsigned short* __restrict__ hb0,
    float* __restrict__ oh0,
    unsigned short* __restrict__ xball,
    unsigned short* __restrict__ Wub,
    unsigned short* __restrict__ Wm2b, unsigned short* __restrict__ Wv2b,
    unsigned short* __restrict__ Wphib,
    unsigned short* __restrict__ Wrih, unsigned short* __restrict__ Wrhh,
    unsigned short* __restrict__ Atb,
    float* __restrict__ bu, float* __restrict__ br)
{
    const int blk = blockIdx.x;
    const int tid = threadIdx.x;

    if (blk < SG0) {                       // init state
        const int i = blk * 256 + tid;
        c[i] = 0.f; hb0[i] = 0;
        const int b = i >> 9, nn = i & 511;
        oh0[(size_t)b * (T_ * HD) + nn] = 0.f;
    } else if (blk < SG1) {                // x -> bf16, [T][B][XD]
        const int i = (blk - SG0) * 256 + tid;
        const int d = i & 63;
        const int bt = i >> 6;
        const int b = bt / T_, t = bt % T_;
        float4 v = reinterpret_cast<const float4*>(x)[i];
        ushort4 o;
        o.x = f2b(v.x); o.y = f2b(v.y); o.z = f2b(v.z); o.w = f2b(v.w);
        reinterpret_cast<ushort4*>(xball)[((size_t)t * B_ + b) * (XD / 4) + d] = o;
    } else if (blk < SG2) {                // Wub = [Wm1; Wv1]
        const int e = (blk - SG1) * 256 + tid;
        const float v = e < 512 * 768 ? Wm1[e] : Wv1[e - 512 * 768];
        Wub[e] = f2b(v);
    } else if (blk < SG3) {                // Wm2b
        const int i = (blk - SG2) * 256 + tid;
        float4 v = reinterpret_cast<const float4*>(Wm2)[i];
        ushort4 o;
        o.x = f2b(v.x); o.y = f2b(v.y); o.z = f2b(v.z); o.w = f2b(v.w);
        reinterpret_cast<ushort4*>(Wm2b)[i] = o;
    } else if (blk < SG4) {                // Wv2b
        const int i = (blk - SG3) * 256 + tid;
        float4 v = reinterpret_cast<const float4*>(Wv2)[i];
        ushort4 o;
        o.x = f2b(v.x); o.y = f2b(v.y); o.z = f2b(v.z); o.w = f2b(v.w);
        reinterpret_cast<ushort4*>(Wv2b)[i] = o;
    } else if (blk < SG5) {                // Wphib
        const int i = (blk - SG4) * 256 + tid;
        float4 v = reinterpret_cast<const float4*>(Wphi)[i];
        ushort4 o;
        o.x = f2b(v.x); o.y = f2b(v.y); o.z = f2b(v.z); o.w = f2b(v.w);
        reinterpret_cast<ushort4*>(Wphib)[i] = o;
    } else if (blk < SG6) {                // gate-interleaved W_ih / W_hh
        const int e = (blk - SG5) * 256 + tid;   // over 2048*1536
        const int cc = e / 1536, kk = e % 1536;
        const int gate = (cc >> 4) & 3;
        const int n = ((cc >> 6) << 4) + (cc & 15);
        const int orig = gate * 512 + n;
        if (kk < 1024) Wrih[(size_t)cc * 1024 + kk] = f2b(Wih[(size_t)orig * 1024 + kk]);
        else           Wrhh[(size_t)cc * 512 + (kk - 1024)] = f2b(Whh[(size_t)orig * 512 + (kk - 1024)]);
    } else if (blk < SG7) {                // At = A^T
        const int i = (blk - SG6) * 256 + tid;   // 384*384
        const int k = i / DD, j = i % DD;
        Atb[(size_t)k * DD + j] = f2b(A[(size_t)j * DD + k]);
    } else {                               // biases
        const int i = (blk - SG7) * 256 + tid;   // 0..4095
        if (i < 1024) {
            bu[i] = i < 512 ? bm1[i] : bv1[i - 512];
        } else if (i >= 2048) {
            const int cb = i - 2048;
            const int gate = (cb >> 4) & 3;
            const int n = ((cb >> 6) << 4) + (cb & 15);
            const int orig = gate * 512 + n;
            br[cb] = bih[orig] + bhh[orig];
        }
    }
}

extern "C" void kernel_launch(void* const* d_in, const int* in_sizes, int n_in,
                              void* d_out, int out_size, void* d_ws, size_t ws_size,
                              hipStream_t stream)
{
    const float* x    = (const float*)d_in[0];
    const float* A    = (const float*)d_in[3];
    const float* Wm1  = (const float*)d_in[4];
    const float* bm1  = (const float*)d_in[5];
    const float* Wm2  = (const float*)d_in[6];
    const float* bm2  = (const float*)d_in[7];
    const float* Wv1  = (const float*)d_in[8];
    const float* bv1  = (const float*)d_in[9];
    const float* Wv2  = (const float*)d_in[10];
    const float* bv2  = (const float*)d_in[11];
    const float* Wphi = (const float*)d_in[12];
    const float* bphi = (const float*)d_in[13];
    const float* W_ih = (const float*)d_in[14];
    const float* W_hh = (const float*)d_in[15];
    const float* b_ih = (const float*)d_in[16];
    const float* b_hh = (const float*)d_in[17];

    float* out = (float*)d_out;
    float* out_z    = out;
    float* out_mean = out_z + (size_t)B_ * T_ * ZD;
    float* out_lv   = out_mean + (size_t)B_ * T_ * ZD;
    float* out_hout = out_lv + (size_t)B_ * T_ * ZD;
    float* out_hlo  = out_hout + (size_t)B_ * T_ * HD;

    // ---- workspace layout (~255 MB) ----
    char* wp = (char*)d_ws;
    auto alloc_f = [&](size_t n) { float* p = (float*)wp; wp += n * sizeof(float); return p; };
    auto alloc_b = [&](size_t n) { unsigned short* p = (unsigned short*)wp; wp += n * sizeof(unsigned short); return p; };

    float* c = alloc_f((size_t)B_ * HD);
    unsigned short* hb0     = alloc_b((size_t)B_ * HD);
    unsigned short* hb1     = alloc_b((size_t)B_ * HD);
    unsigned short* xball   = alloc_b((size_t)T_ * B_ * XD);
    unsigned short* umuvall = alloc_b((size_t)T_ * B_ * 1024);
    unsigned short* phib    = alloc_b((size_t)B_ * 1024);

    unsigned short* Wub   = alloc_b((size_t)1024 * 768);
    unsigned short* Wm2b  = alloc_b((size_t)ZD * HD);
    unsigned short* Wv2b  = alloc_b((size_t)ZD * HD);
    unsigned short* Atb   = alloc_b((size_t)DD * DD);
    unsigned short* Wphib = alloc_b((size_t)1024 * DD);
    unsigned short* Wcb   = alloc_b((size_t)1024 * DD);
    unsigned short* Wrih  = alloc_b((size_t)2048 * 1024);
    unsigned short* Wrhh  = alloc_b((size_t)2048 * 512);

    float* bu = alloc_f(1024);
    float* br = alloc_f(2048);

    const dim3 blk(256);

    // ---- prep: one fused kernel + the Wc GEMM ----
    prep_all<<<dim3(SG8), blk, 0, stream>>>(
        x, A, Wm1, bm1, Wm2, Wv1, bv1, Wv2, Wphi, W_ih, W_hh, b_ih, b_hh,
        c, hb0, out_hout, xball, Wub, Wm2b, Wv2b, Wphib, Wrih, Wrhh, Atb, bu, br);
    // Wc = Wphi @ A  ([1024 x 384] bf16): folds the agg GEMM into phi
    k_gemm_plain<<<dim3(DD / 128, 1024 / 128), blk, 0, stream>>>(
        Wphib, DD, DD, Atb, DD, Wcb, DD);

    for (int t = 0; t < T_; ++t) {
        unsigned short* hbt = (t & 1) ? hb1 : hb0;   // h_t  (read)
        unsigned short* hbn = (t & 1) ? hb0 : hb1;   // h_{t+1} (written by epilogue)
        const unsigned short* xb = xball + (size_t)t * B_ * XD;
        unsigned short* uslot = umuvall + (size_t)t * B_ * 1024;

        // [u_m | u_v] = lrelu([x_t, h] @ Wub^T + bu)   8-wave 64x128 core, grid 512
        k_u_8w<<<dim3(512), dim3(512), 0, stream>>>(
            xb, XD, XD, hbt, HD, HD,
            Wub, XD + HD, Wub + XD, XD + HD,
            bu, uslot, 1024);

        // mean (in-LDS) + phi fused; bn==0 writes out_z/out_mean
        k_meanphi<<<dim3(512), blk, 0, stream>>>(
            uslot, xb, Wm2b, Wcb, bm2, bphi,
            out_z + (size_t)t * ZD, out_mean + (size_t)t * ZD, phib);

        // gates (reordered) + fused LSTM   8-wave MT=128 core, grid 512
        k_gates_lstm<<<dim3(512), dim3(512), 0, stream>>>(
            phib, hbt, Wrih, Wrhh, br,
            c, hbn,
            out_hlo + (size_t)t * HD,
            (t + 1 < T_) ? out_hout + (size_t)(t + 1) * HD : nullptr);
    }

    // logvar for ALL steps in one batched GEMM (off the recurrence path)
    k_logvar_all<<<dim3(T_ * B_ / 64), blk, 0, stream>>>(
        umuvall, Wv2b, bv2, out_lv);
}

// Round 16
// 1826.215 us; speedup vs baseline: 1.3541x; 1.0334x over previous
//
#include <hip/hip_runtime.h>
#include <math.h>

// Problem constants
constexpr int B_ = 4096;
constexpr int T_ = 20;
constexpr int XD = 256;   // X_DIM
constexpr int ZD = 128;   // Z_DIM
constexpr int HD = 512;   // H_DIM
constexpr int DD = 384;   // X+Z

using short8 = __attribute__((ext_vector_type(8))) short;
using bf16x8 = __attribute__((ext_vector_type(8))) __bf16;
using f32x4  = __attribute__((ext_vector_type(4))) float;

__device__ __forceinline__ float lrelu_f(float v) { return v > 0.f ? v : 0.2f * v; }
__device__ __forceinline__ float softplus_f(float v) {
    return log1pf(expf(-fabsf(v))) + fmaxf(v, 0.f);
}
__device__ __forceinline__ float sigmoid_f(float v) { return 1.f / (1.f + expf(-v)); }

// float -> bf16 (round to nearest even), finite inputs
__device__ __forceinline__ unsigned short f2b(float f) {
    unsigned u = __builtin_bit_cast(unsigned, f);
    u += 0x7fff + ((u >> 16) & 1);
    return (unsigned short)(u >> 16);
}

__device__ __forceinline__ f32x4 mfma16(short8 a, short8 b, f32x4 c) {
    return __builtin_amdgcn_mfma_f32_16x16x32_bf16(
        __builtin_bit_cast(bf16x8, a), __builtin_bit_cast(bf16x8, b), c, 0, 0, 0);
}

// async global->LDS, 16 B per lane; lds base must be wave-uniform
__device__ __forceinline__ void load_lds16(const unsigned short* g, unsigned short* l) {
    __builtin_amdgcn_global_load_lds(
        (const __attribute__((address_space(1))) unsigned int*)g,
        (__attribute__((address_space(3))) unsigned int*)l,
        16, 0, 0);
}

// wait until at most `rem` K-tiles (LPT loads each per wave) remain outstanding
template <int LPT>
__device__ __forceinline__ void vmwait(int rem) {
    if (rem >= 2) {
        if constexpr (LPT == 4)      asm volatile("s_waitcnt vmcnt(8)" ::: "memory");
        else if constexpr (LPT == 3) asm volatile("s_waitcnt vmcnt(6)" ::: "memory");
        else if constexpr (LPT == 2) asm volatile("s_waitcnt vmcnt(4)" ::: "memory");
        else                         asm volatile("s_waitcnt vmcnt(2)" ::: "memory");
    } else if (rem == 1) {
        if constexpr (LPT == 4)      asm volatile("s_waitcnt vmcnt(4)" ::: "memory");
        else if constexpr (LPT == 3) asm volatile("s_waitcnt vmcnt(3)" ::: "memory");
        else if constexpr (LPT == 2) asm volatile("s_waitcnt vmcnt(2)" ::: "memory");
        else                         asm volatile("s_waitcnt vmcnt(1)" ::: "memory");
    } else {
        asm volatile("s_waitcnt vmcnt(0)" ::: "memory");
    }
}

// ---------------------------------------------------------------------------
// MTx128-tile bf16 MFMA GEMM core (MT in {64,128}), 256 threads, 3-deep
// counted-vmcnt pipeline. Chunk swizzle c' = c ^ ((row>>1)&3) on global source
// AND ds_read (rule #21).
// ---------------------------------------------------------------------------
template <int MT>
__device__ __forceinline__ void gemm_core(
    const unsigned short* A1, int lda1, int K1,
    const unsigned short* A2, int lda2, int K2,
    const unsigned short* W1, int ldw1,
    const unsigned short* W2, int ldw2,
    int bm, int bn,
    unsigned short* As, unsigned short* Bs,   // As: 3*MT*32, Bs: 3*4096 shorts
    f32x4 (&acc)[MT / 32][4])
{
    constexpr int MI   = MT / 32;
    constexpr int WRS  = MT / 2;
    constexpr int NA   = MT / 64;
    constexpr int LPT  = NA + 2;
    constexpr int ABUF = MT * 32;

    const int tid  = threadIdx.x;
    const int lane = tid & 63;
    const int wave = tid >> 6;
    const int wr = wave >> 1, wc = wave & 1;
    const int fr = lane & 15, fg = lane >> 4;
    const int cswz = fg ^ ((fr >> 1) & 3);

    const int r0 = tid >> 2,          c0 = (tid & 3) ^ ((r0 >> 1) & 3);
    const int r1 = (256 + tid) >> 2,  c1 = ((256 + tid) & 3) ^ ((r1 >> 1) & 3);

    const int n1 = K1 / 32;
    const int nt = n1 + K2 / 32;

    auto stage = [&](int i, int buf) {
        const unsigned short* Ag;
        const unsigned short* Wg;
        int lda, ldw, kb;
        if (i < n1) { Ag = A1; Wg = W1; lda = lda1; ldw = ldw1; kb = i * 32; }
        else        { Ag = A2; Wg = W2; lda = lda2; ldw = ldw2; kb = (i - n1) * 32; }
        unsigned short* lA = As + buf * ABUF + wave * 512;
        unsigned short* lB = Bs + buf * 4096 + wave * 512;
        load_lds16(Ag + (size_t)(bm + r0) * lda + kb + c0 * 8, lA);
        if constexpr (NA == 2)
            load_lds16(Ag + (size_t)(bm + r1) * lda + kb + c1 * 8, lA + 2048);
        load_lds16(Wg + (size_t)(bn + r0) * ldw + kb + c0 * 8, lB);
        load_lds16(Wg + (size_t)(bn + r1) * ldw + kb + c1 * 8, lB + 2048);
    };

    auto compute = [&](int buf) {
        const unsigned short* Ab_ = As + buf * ABUF;
        const unsigned short* Bb_ = Bs + buf * 4096;
        short8 af[MI], bv[4];
#pragma unroll
        for (int mi = 0; mi < MI; ++mi)
            af[mi] = *reinterpret_cast<const short8*>(Ab_ + (wr * WRS + mi * 16 + fr) * 32 + cswz * 8);
#pragma unroll
        for (int ni = 0; ni < 4; ++ni)
            bv[ni] = *reinterpret_cast<const short8*>(Bb_ + (wc * 64 + ni * 16 + fr) * 32 + cswz * 8);
#pragma unroll
        for (int mi = 0; mi < MI; ++mi)
#pragma unroll
            for (int ni = 0; ni < 4; ++ni)
                acc[mi][ni] = mfma16(af[mi], bv[ni], acc[mi][ni]);
    };

    stage(0, 0);
    if (1 < nt) stage(1, 1);
    if (2 < nt) stage(2, 2);
    {
        int rem = (nt - 1 < 2) ? (nt - 1) : 2;
        vmwait<LPT>(rem);
    }
    __builtin_amdgcn_s_barrier();

    int buf = 0;
    for (int i = 0; i < nt; ++i) {
        compute(buf);
        if (i + 1 < nt) {
            asm volatile("" ::: "memory");
            __builtin_amdgcn_s_barrier();
            if (i + 3 < nt) stage(i + 3, buf);
            int rem = nt - (i + 2);
            if (rem > 2) rem = 2;
            vmwait<LPT>(rem);
            __builtin_amdgcn_s_barrier();
            buf = (buf == 2) ? 0 : buf + 1;
        }
    }
}

// ---------------------------------------------------------------------------
// 128x128-tile core, 512 threads = 8 waves (4M x 2N), each wave 32x64 output
// (acc 2x4). Same K-tile order and fragment data as gemm_core<128> ->
// bit-identical accumulation. LPT=2/wave (1 A + 1 B load per K-tile).
// ---------------------------------------------------------------------------
__device__ __forceinline__ void gemm_core8w(
    const unsigned short* A1, int lda1, int K1,
    const unsigned short* A2, int lda2, int K2,
    const unsigned short* W1, int ldw1,
    const unsigned short* W2, int ldw2,
    int bm, int bn,
    unsigned short* As, unsigned short* Bs,   // each 3*4096 shorts
    f32x4 (&acc)[2][4])
{
    const int tid  = threadIdx.x;          // 0..511
    const int lane = tid & 63;
    const int wave = tid >> 6;             // 0..7
    const int wr = wave >> 1, wc = wave & 1;
    const int fr = lane & 15, fg = lane >> 4;
    const int cswz = fg ^ ((fr >> 1) & 3);

    const int r0 = tid >> 2;                       // 0..127
    const int c0 = (tid & 3) ^ ((r0 >> 1) & 3);

    const int n1 = K1 / 32;
    const int nt = n1 + K2 / 32;

    auto stage = [&](int i, int buf) {
        const unsigned short* Ag;
        const unsigned short* Wg;
        int lda, ldw, kb;
        if (i < n1) { Ag = A1; Wg = W1; lda = lda1; ldw = ldw1; kb = i * 32; }
        else        { Ag = A2; Wg = W2; lda = lda2; ldw = ldw2; kb = (i - n1) * 32; }
        unsigned short* lA = As + buf * 4096 + wave * 512;   // 8 waves x 512 = 4096
        unsigned short* lB = Bs + buf * 4096 + wave * 512;
        load_lds16(Ag + (size_t)(bm + r0) * lda + kb + c0 * 8, lA);
        load_lds16(Wg + (size_t)(bn + r0) * ldw + kb + c0 * 8, lB);
    };

    auto compute = [&](int buf) {
        const unsigned short* Ab_ = As + buf * 4096;
        const unsigned short* Bb_ = Bs + buf * 4096;
        short8 af[2], bv[4];
#pragma unroll
        for (int mi = 0; mi < 2; ++mi)
            af[mi] = *reinterpret_cast<const short8*>(Ab_ + (wr * 32 + mi * 16 + fr) * 32 + cswz * 8);
#pragma unroll
        for (int ni = 0; ni < 4; ++ni)
            bv[ni] = *reinterpret_cast<const short8*>(Bb_ + (wc * 64 + ni * 16 + fr) * 32 + cswz * 8);
#pragma unroll
        for (int mi = 0; mi < 2; ++mi)
#pragma unroll
            for (int ni = 0; ni < 4; ++ni)
                acc[mi][ni] = mfma16(af[mi], bv[ni], acc[mi][ni]);
    };

    stage(0, 0);
    if (1 < nt) stage(1, 1);
    if (2 < nt) stage(2, 2);
    {
        int rem = (nt - 1 < 2) ? (nt - 1) : 2;
        vmwait<2>(rem);
    }
    __builtin_amdgcn_s_barrier();

    int buf = 0;
    for (int i = 0; i < nt; ++i) {
        compute(buf);
        if (i + 1 < nt) {
            asm volatile("" ::: "memory");
            __builtin_amdgcn_s_barrier();
            if (i + 3 < nt) stage(i + 3, buf);
            int rem = nt - (i + 2);
            if (rem > 2) rem = 2;
            vmwait<2>(rem);
            __builtin_amdgcn_s_barrier();
            buf = (buf == 2) ? 0 : buf + 1;
        }
    }
}

// ---------------------------------------------------------------------------
// 64x128-tile core, 512 threads = 8 waves (4M x 2N), each wave 16x64 output
// (acc 1x4). Role-split staging (chunk audit: A 64x32 = 256 chunks = waves
// 0-3 x 1 load; B 128x32 = 512 chunks = waves 4-7 x 2 loads).
// Per-wave LPT: A-waves 1, B-waves 2 -> wave-uniform branched vmwait.
// Same K-tile order/fragments as gemm_core<64> -> bit-identical.
// ---------------------------------------------------------------------------
__device__ __forceinline__ void gemm_core8w64(
    const unsigned short* A1, int lda1, int K1,
    const unsigned short* A2, int lda2, int K2,
    const unsigned short* W1, int ldw1,
    const unsigned short* W2, int ldw2,
    int bm, int bn,
    unsigned short* As, unsigned short* Bs,   // As: 3*2048, Bs: 3*4096 shorts
    f32x4 (&acc)[1][4])
{
    const int tid  = threadIdx.x;          // 0..511
    const int lane = tid & 63;
    const int wave = tid >> 6;             // 0..7
    const int wr = wave >> 1, wc = wave & 1;
    const int fr = lane & 15, fg = lane >> 4;
    const int cswz = fg ^ ((fr >> 1) & 3);

    // A role (waves 0-3): chunk ca = wave*64+lane (0..255)
    const int ca = wave * 64 + lane;
    const int ar = ca >> 2, ac = (ca & 3) ^ ((ar >> 1) & 3);
    // B role (waves 4-7): chunk groups g0=(wave-4)*2, g1=g0+1; chunk g*64+lane
    const int g0 = (wave - 4) * 2, g1 = g0 + 1;
    const int cb0 = g0 * 64 + lane, cb1 = g1 * 64 + lane;
    const int br0 = cb0 >> 2, bc0 = (cb0 & 3) ^ ((br0 >> 1) & 3);
    const int br1 = cb1 >> 2, bc1 = (cb1 & 3) ^ ((br1 >> 1) & 3);

    const int n1 = K1 / 32;
    const int nt = n1 + K2 / 32;

    auto stage = [&](int i, int buf) {
        const unsigned short* Ag;
        const unsigned short* Wg;
        int lda, ldw, kb;
        if (i < n1) { Ag = A1; Wg = W1; lda = lda1; ldw = ldw1; kb = i * 32; }
        else        { Ag = A2; Wg = W2; lda = lda2; ldw = ldw2; kb = (i - n1) * 32; }
        if (wave < 4) {
            unsigned short* lA = As + buf * 2048 + wave * 512;
            load_lds16(Ag + (size_t)(bm + ar) * lda + kb + ac * 8, lA);
        } else {
            unsigned short* lB = Bs + buf * 4096;
            load_lds16(Wg + (size_t)(bn + br0) * ldw + kb + bc0 * 8, lB + g0 * 512);
            load_lds16(Wg + (size_t)(bn + br1) * ldw + kb + bc1 * 8, lB + g1 * 512);
        }
    };

    auto wait = [&](int rem) {
        if (wave < 4) vmwait<1>(rem);
        else          vmwait<2>(rem);
    };

    auto compute = [&](int buf) {
        const unsigned short* Ab_ = As + buf * 2048;
        const unsigned short* Bb_ = Bs + buf * 4096;
        short8 af = *reinterpret_cast<const short8*>(Ab_ + (wr * 16 + fr) * 32 + cswz * 8);
        short8 bv[4];
#pragma unroll
        for (int ni = 0; ni < 4; ++ni)
            bv[ni] = *reinterpret_cast<const short8*>(Bb_ + (wc * 64 + ni * 16 + fr) * 32 + cswz * 8);
#pragma unroll
        for (int ni = 0; ni < 4; ++ni)
            acc[0][ni] = mfma16(af, bv[ni], acc[0][ni]);
    };

    stage(0, 0);
    if (1 < nt) stage(1, 1);
    if (2 < nt) stage(2, 2);
    {
        int rem = (nt - 1 < 2) ? (nt - 1) : 2;
        wait(rem);
    }
    __builtin_amdgcn_s_barrier();

    int buf = 0;
    for (int i = 0; i < nt; ++i) {
        compute(buf);
        if (i + 1 < nt) {
            asm volatile("" ::: "memory");
            __builtin_amdgcn_s_barrier();
            if (i + 3 < nt) stage(i + 3, buf);
            int rem = nt - (i + 2);
            if (rem > 2) rem = 2;
            wait(rem);
            __builtin_amdgcn_s_barrier();
            buf = (buf == 2) ? 0 : buf + 1;
        }
    }
}

// GEMM + bias + activation -> bf16 output. ACT: 0 none, 1 lrelu, 2 softplus(lrelu)
// 1D grid decode: bn = (id & NMASK)*128, bm = (id >> NSHIFT)*MT
template <int ACT, int MT, int NMASK, int NSHIFT>
__global__ __launch_bounds__(256) void k_gemm_act(
    const unsigned short* __restrict__ A1, int lda1, int K1,
    const unsigned short* __restrict__ A2, int lda2, int K2,
    const unsigned short* __restrict__ W1, int ldw1,
    const unsigned short* __restrict__ W2, int ldw2,
    const float* __restrict__ bias,
    unsigned short* __restrict__ DB, int lddb)
{
    __shared__ unsigned short As[3 * MT * 32];
    __shared__ unsigned short Bs[3 * 4096];
    const int id = blockIdx.x;
    const int bm = (id >> NSHIFT) * MT, bn = (id & NMASK) * 128;
    f32x4 acc[MT / 32][4] = {};
    gemm_core<MT>(A1, lda1, K1, A2, lda2, K2, W1, ldw1, W2, ldw2, bm, bn, As, Bs, acc);

    constexpr int MI = MT / 32, WRS = MT / 2;
    const int tid = threadIdx.x, lane = tid & 63, wave = tid >> 6;
    const int wr = wave >> 1, wc = wave & 1, fr = lane & 15, rg = lane >> 4;
    float bb[4];
#pragma unroll
    for (int ni = 0; ni < 4; ++ni)
        bb[ni] = bias ? bias[bn + wc * 64 + ni * 16 + fr] : 0.f;
#pragma unroll
    for (int mi = 0; mi < MI; ++mi)
#pragma unroll
        for (int r = 0; r < 4; ++r) {
            const int row = bm + wr * WRS + mi * 16 + rg * 4 + r;
#pragma unroll
            for (int ni = 0; ni < 4; ++ni) {
                float v = acc[mi][ni][r] + bb[ni];
                if (ACT == 1) v = lrelu_f(v);
                else if (ACT == 2) v = softplus_f(lrelu_f(v));
                DB[(size_t)row * lddb + (bn + wc * 64 + ni * 16 + fr)] = f2b(v);
            }
        }
}

// u GEMM via the 8-wave 64x128 core: grid 512 (bm=(id>>3)*64, bn=(id&7)*128),
// 512 threads -> 2 blocks/CU -> 4 waves/SIMD.
__global__ __launch_bounds__(512) void k_u_8w(
    const unsigned short* __restrict__ A1, int lda1, int K1,
    const unsigned short* __restrict__ A2, int lda2, int K2,
    const unsigned short* __restrict__ W1, int ldw1,
    const unsigned short* __restrict__ W2, int ldw2,
    const float* __restrict__ bias,
    unsigned short* __restrict__ DB, int lddb)
{
    __shared__ unsigned short As[3 * 2048];   // 12 KB
    __shared__ unsigned short Bs[3 * 4096];   // 24 KB
    const int id = blockIdx.x;
    const int bm = (id >> 3) * 64, bn = (id & 7) * 128;
    f32x4 acc[1][4] = {};
    gemm_core8w64(A1, lda1, K1, A2, lda2, K2, W1, ldw1, W2, ldw2, bm, bn, As, Bs, acc);

    const int tid = threadIdx.x, lane = tid & 63, wave = tid >> 6;
    const int wr = wave >> 1, wc = wave & 1, fr = lane & 15, rg = lane >> 4;
    float bb[4];
#pragma unroll
    for (int ni = 0; ni < 4; ++ni)
        bb[ni] = bias[bn + wc * 64 + ni * 16 + fr];
#pragma unroll
    for (int r = 0; r < 4; ++r) {
        const int row = bm + wr * 16 + rg * 4 + r;
#pragma unroll
        for (int ni = 0; ni < 4; ++ni) {
            float v = lrelu_f(acc[0][ni][r] + bb[ni]);
            DB[(size_t)row * lddb + (bn + wc * 64 + ni * 16 + fr)] = f2b(v);
        }
    }
}

// ---------------------------------------------------------------------------
// Fused mean + phi kernel, 512 threads / 8 waves (R16): grid 512:
// bm=(id>>3)*64 rows, bn=(id&7)*128 phi-cols. Stages 1-2 via gemm_core8w64;
// stage 3 B-staging: 512 chunks = 512 lanes x 1 load (LPT=1 uniform).
// Same K-tile orders as before -> bit-identical results.
// ---------------------------------------------------------------------------
__global__ __launch_bounds__(512) void k_meanphi(
    const unsigned short* __restrict__ uslot,  // umuvall + t*B*1024, [B][1024]
    const unsigned short* __restrict__ xb,     // [B][256]
    const unsigned short* __restrict__ Wm2b,   // [128][512]
    const unsigned short* __restrict__ Wcb,    // [1024][384]
    const float* __restrict__ bm2,             // [128]
    const float* __restrict__ bphi,            // [1024]
    float* __restrict__ oz, float* __restrict__ om,   // + t*ZD, stride T*ZD
    unsigned short* __restrict__ phib)
{
    __shared__ unsigned short As[3 * 2048];      // 12 KB
    __shared__ unsigned short Bs[3 * 4096];      // 24 KB
    __shared__ unsigned short meanL[64 * 136];   // 17 KB, conflict-light pad

    const int id = blockIdx.x;
    const int bm = (id >> 3) * 64, bn = (id & 7) * 128;
    const int tid = threadIdx.x, lane = tid & 63, wave = tid >> 6;
    const int wr = wave >> 1, wc = wave & 1, fr = lane & 15, fg = lane >> 4, rg = lane >> 4;
    const int cswz = fg ^ ((fr >> 1) & 3);

    // ---- stage 1: mean = lrelu(u_m @ Wm2^T + bm2) for rows [bm, bm+64) ----
    {
        f32x4 macc[1][4] = {};
        gemm_core8w64(uslot, 1024, 512, uslot, 1024, 0,
                      Wm2b, 512, Wm2b, 512, bm, 0, As, Bs, macc);
        float mb[4];
#pragma unroll
        for (int ni = 0; ni < 4; ++ni)
            mb[ni] = bm2[wc * 64 + ni * 16 + fr];
#pragma unroll
        for (int r = 0; r < 4; ++r) {
            const int rowl = wr * 16 + rg * 4 + r;
#pragma unroll
            for (int ni = 0; ni < 4; ++ni) {
                const int col = wc * 64 + ni * 16 + fr;
                const float v = lrelu_f(macc[0][ni][r] + mb[ni]);
                meanL[rowl * 136 + col] = f2b(v);
                if (bn == 0) {
                    const size_t o = (size_t)(bm + rowl) * (T_ * ZD) + col;
                    oz[o] = v; om[o] = v;
                }
            }
        }
    }
    __syncthreads();

    // ---- stage 2: phi x-part (K=256) ----
    f32x4 acc[1][4] = {};
    gemm_core8w64(xb, XD, XD, xb, XD, 0,
                  Wcb, DD, Wcb, DD, bm, bn, As, Bs, acc);
    __syncthreads();

    // ---- stage 3: phi mean-part (K=128, 4 tiles), A from meanL ----
    {
        const unsigned short* WG = Wcb + XD;     // mean-columns of Wc
        const int r0 = tid >> 2;                 // 0..127
        const int c0 = (tid & 3) ^ ((r0 >> 1) & 3);
        auto stageB = [&](int i, int buf) {
            unsigned short* lB = Bs + buf * 4096 + wave * 512;
            load_lds16(WG + (size_t)(bn + r0) * DD + i * 32 + c0 * 8, lB);
        };
        stageB(0, 0); stageB(1, 1); stageB(2, 2);
        vmwait<1>(2);
        __builtin_amdgcn_s_barrier();
        int buf = 0;
        for (int i = 0; i < 4; ++i) {
            short8 af = *reinterpret_cast<const short8*>(
                meanL + (wr * 16 + fr) * 136 + i * 32 + fg * 8);
            short8 bv[4];
#pragma unroll
            for (int ni = 0; ni < 4; ++ni)
                bv[ni] = *reinterpret_cast<const short8*>(
                    Bs + buf * 4096 + (wc * 64 + ni * 16 + fr) * 32 + cswz * 8);
#pragma unroll
            for (int ni = 0; ni < 4; ++ni)
                acc[0][ni] = mfma16(af, bv[ni], acc[0][ni]);
            if (i + 1 < 4) {
                asm volatile("" ::: "memory");
                __builtin_amdgcn_s_barrier();
                if (i + 3 < 4) stageB(i + 3, buf);
                int rem = 4 - (i + 2);
                if (rem > 2) rem = 2;
                vmwait<1>(rem);
                __builtin_amdgcn_s_barrier();
                buf = (buf == 2) ? 0 : buf + 1;
            }
        }
    }

    // ---- epilogue: softplus(lrelu(.)) -> phib ----
    float pb[4];
#pragma unroll
    for (int ni = 0; ni < 4; ++ni)
        pb[ni] = bphi[bn + wc * 64 + ni * 16 + fr];
#pragma unroll
    for (int r = 0; r < 4; ++r) {
        const int row = bm + wr * 16 + rg * 4 + r;
#pragma unroll
        for (int ni = 0; ni < 4; ++ni) {
            const float v = softplus_f(lrelu_f(acc[0][ni][r] + pb[ni]));
            phib[(size_t)row * 1024 + (bn + wc * 64 + ni * 16 + fr)] = f2b(v);
        }
    }
}

// ---------------------------------------------------------------------------
// Batched logvar over ALL steps (off the recurrence path)
__global__ __launch_bounds__(256) void k_logvar_all(
    const unsigned short* __restrict__ umuvall,
    const unsigned short* __restrict__ Wv2b,
    const float* __restrict__ bv2,
    float* __restrict__ out_lv)               // [B][T][ZD]
{
    __shared__ unsigned short As[3 * 64 * 32];
    __shared__ unsigned short Bs[3 * 4096];
    const int bm = blockIdx.x * 64;
    f32x4 acc[2][4] = {};
    gemm_core<64>(umuvall + 512, 1024, 512, umuvall + 512, 1024, 0,
                  Wv2b, 512, Wv2b, 512, bm, 0, As, Bs, acc);

    const int tid = threadIdx.x, lane = tid & 63, wave = tid >> 6;
    const int wr = wave >> 1, wc = wave & 1, fr = lane & 15, rg = lane >> 4;
    float bb[4];
#pragma unroll
    for (int ni = 0; ni < 4; ++ni)
        bb[ni] = bv2[wc * 64 + ni * 16 + fr];
#pragma unroll
    for (int mi = 0; mi < 2; ++mi)
#pragma unroll
        for (int r = 0; r < 4; ++r) {
            const int row = bm + wr * 32 + mi * 16 + rg * 4 + r;   // t*B + b
            const int t = row >> 12, b = row & (B_ - 1);
#pragma unroll
            for (int ni = 0; ni < 4; ++ni) {
                const int col = wc * 64 + ni * 16 + fr;
                out_lv[(size_t)b * (T_ * ZD) + (size_t)t * ZD + col] =
                    lrelu_f(acc[mi][ni][r] + bb[ni]);
            }
        }
}

// gates GEMM: 512-thread 8-wave MT=128 core + gate-interleaved rows + fused
// LSTM. grid 512 = 2 blocks/CU -> 4 waves/SIMD.
// XCD-chunked swizzle: sid=(id&7)*64+(id>>3); bn=(sid&15)*128, bm=(sid>>4)*128.
__global__ __launch_bounds__(512) void k_gates_lstm(
    const unsigned short* __restrict__ phib,
    const unsigned short* __restrict__ hbin,
    const unsigned short* __restrict__ Wih,   // [2048][1024] reordered rows
    const unsigned short* __restrict__ Whh,   // [2048][512] reordered rows
    const float* __restrict__ br,             // reordered b_ih+b_hh
    float* __restrict__ c,
    unsigned short* __restrict__ hbout,
    float* __restrict__ ohl,                  // out_hlo + t*HD
    float* __restrict__ oh_next)              // out_hout + (t+1)*HD, or null
{
    __shared__ unsigned short As[3 * 4096];   // 24 KB
    __shared__ unsigned short Bs[3 * 4096];   // 24 KB
    const int id = blockIdx.x;
    const int sid = (id & 7) * 64 + (id >> 3);         // bijective for 512
    const int bm = (sid >> 4) * 128, bn = (sid & 15) * 128;
    f32x4 acc[2][4] = {};
    gemm_core8w(phib, 1024, 1024, hbin, 512, 512, Wih, 1024, Whh, 512, bm, bn, As, Bs, acc);

    const int tid = threadIdx.x, lane = tid & 63, wave = tid >> 6;
    const int wr = wave >> 1, wc = wave & 1, fr = lane & 15, rg = lane >> 4;
    const int n = ((bn + wc * 64) >> 6) * 16 + fr;     // hidden unit index
    float bb[4];
#pragma unroll
    for (int ni = 0; ni < 4; ++ni)
        bb[ni] = br[bn + wc * 64 + ni * 16 + fr];
#pragma unroll
    for (int mi = 0; mi < 2; ++mi)
#pragma unroll
        for (int r = 0; r < 4; ++r) {
            const int row = bm + wr * 32 + mi * 16 + rg * 4 + r;
            const size_t idx = (size_t)row * HD + n;
            const float gi = acc[mi][0][r] + bb[0];
            const float gf = acc[mi][1][r] + bb[1];
            const float gg = acc[mi][2][r] + bb[2];
            const float go = acc[mi][3][r] + bb[3];
            const float co = c[idx];
            const float cn = sigmoid_f(gf) * co + sigmoid_f(gi) * tanhf(gg);
            const float hn = sigmoid_f(go) * tanhf(cn);
            c[idx] = cn;
            hbout[idx] = f2b(hn);
            const size_t ob = (size_t)row * (T_ * HD) + n;
            ohl[ob] = hn;                       // h after update
            if (oh_next) oh_next[ob] = hn;      // == h BEFORE update at t+1
        }
}

// ---------------------------------------------------------------------------
// prep GEMM (MT=128 core, 2D grid) for Wc = Wphi @ A
__global__ __launch_bounds__(256) void k_gemm_plain(
    const unsigned short* __restrict__ A1, int lda1, int K1,
    const unsigned short* __restrict__ W1, int ldw1,
    unsigned short* __restrict__ DB, int lddb)
{
    __shared__ unsigned short As[3 * 128 * 32];
    __shared__ unsigned short Bs[3 * 4096];
    const int bm = blockIdx.y * 128, bn = blockIdx.x * 128;
    f32x4 acc[4][4] = {};
    gemm_core<128>(A1, lda1, K1, A1, lda1, 0, W1, ldw1, W1, ldw1, bm, bn, As, Bs, acc);

    const int tid = threadIdx.x, lane = tid & 63, wave = tid >> 6;
    const int wr = wave >> 1, wc = wave & 1, fr = lane & 15, rg = lane >> 4;
#pragma unroll
    for (int mi = 0; mi < 4; ++mi)
#pragma unroll
        for (int r = 0; r < 4; ++r) {
            const int row = bm + wr * 64 + mi * 16 + rg * 4 + r;
#pragma unroll
            for (int ni = 0; ni < 4; ++ni) {
                const int col = bn + wc * 64 + ni * 16 + fr;
                DB[(size_t)row * lddb + col] = f2b(acc[mi][ni][r]);
            }
        }
}

// ---------------------------------------------------------------------------
// One fused prep kernel: init-state + x-convert + all weight/bias reorders.
// Segment block counts:
//   init: 8192   conv-x: 20480   Wub: 3072   Wm2b: 64   Wv2b: 64
//   Wphib: 384   wg: 12288       At: 576     bias: 16
// ---------------------------------------------------------------------------
constexpr int SG0 = 8192;
constexpr int SG1 = SG0 + 20480;
constexpr int SG2 = SG1 + 3072;
constexpr int SG3 = SG2 + 64;
constexpr int SG4 = SG3 + 64;
constexpr int SG5 = SG4 + 384;
constexpr int SG6 = SG5 + 12288;
constexpr int SG7 = SG6 + 576;
constexpr int SG8 = SG7 + 16;

__global__ __launch_bounds__(256) void prep_all(
    const float* __restrict__ x,
    const float* __restrict__ A,
    const float* __restrict__ Wm1, const float* __restrict__ bm1,
    const float* __restrict__ Wm2,
    const float* __restrict__ Wv1, const float* __restrict__ bv1,
    const float* __restrict__ Wv2,
    const float* __restrict__ Wphi,
    const float* __restrict__ Wih, const float* __restrict__ Whh,
    const float* __restrict__ bih, const float* __restrict__ bhh,
    float* __restrict__ c, unsigned short* __restrict__ hb0,
    float* __restrict__ oh0,
    unsigned short* __restrict__ xball,
    unsigned short* __restrict__ Wub,
    unsigned short* __restrict__ Wm2b, unsigned short* __restrict__ Wv2b,
    unsigned short* __restrict__ Wphib,
    unsigned short* __restrict__ Wrih, unsigned short* __restrict__ Wrhh,
    unsigned short* __restrict__ Atb,
    float* __restrict__ bu, float* __restrict__ br)
{
    const int blk = blockIdx.x;
    const int tid = threadIdx.x;

    if (blk < SG0) {                       // init state
        const int i = blk * 256 + tid;
        c[i] = 0.f; hb0[i] = 0;
        const int b = i >> 9, nn = i & 511;
        oh0[(size_t)b * (T_ * HD) + nn] = 0.f;
    } else if (blk < SG1) {                // x -> bf16, [T][B][XD]
        const int i = (blk - SG0) * 256 + tid;
        const int d = i & 63;
        const int bt = i >> 6;
        const int b = bt / T_, t = bt % T_;
        float4 v = reinterpret_cast<const float4*>(x)[i];
        ushort4 o;
        o.x = f2b(v.x); o.y = f2b(v.y); o.z = f2b(v.z); o.w = f2b(v.w);
        reinterpret_cast<ushort4*>(xball)[((size_t)t * B_ + b) * (XD / 4) + d] = o;
    } else if (blk < SG2) {                // Wub = [Wm1; Wv1]
        const int e = (blk - SG1) * 256 + tid;
        const float v = e < 512 * 768 ? Wm1[e] : Wv1[e - 512 * 768];
        Wub[e] = f2b(v);
    } else if (blk < SG3) {                // Wm2b
        const int i = (blk - SG2) * 256 + tid;
        float4 v = reinterpret_cast<const float4*>(Wm2)[i];
        ushort4 o;
        o.x = f2b(v.x); o.y = f2b(v.y); o.z = f2b(v.z); o.w = f2b(v.w);
        reinterpret_cast<ushort4*>(Wm2b)[i] = o;
    } else if (blk < SG4) {                // Wv2b
        const int i = (blk - SG3) * 256 + tid;
        float4 v = reinterpret_cast<const float4*>(Wv2)[i];
        ushort4 o;
        o.x = f2b(v.x); o.y = f2b(v.y); o.z = f2b(v.z); o.w = f2b(v.w);
        reinterpret_cast<ushort4*>(Wv2b)[i] = o;
    } else if (blk < SG5) {                // Wphib
        const int i = (blk - SG4) * 256 + tid;
        float4 v = reinterpret_cast<const float4*>(Wphi)[i];
        ushort4 o;
        o.x = f2b(v.x); o.y = f2b(v.y); o.z = f2b(v.z); o.w = f2b(v.w);
        reinterpret_cast<ushort4*>(Wphib)[i] = o;
    } else if (blk < SG6) {                // gate-interleaved W_ih / W_hh
        const int e = (blk - SG5) * 256 + tid;   // over 2048*1536
        const int cc = e / 1536, kk = e % 1536;
        const int gate = (cc >> 4) & 3;
        const int n = ((cc >> 6) << 4) + (cc & 15);
        const int orig = gate * 512 + n;
        if (kk < 1024) Wrih[(size_t)cc * 1024 + kk] = f2b(Wih[(size_t)orig * 1024 + kk]);
        else           Wrhh[(size_t)cc * 512 + (kk - 1024)] = f2b(Whh[(size_t)orig * 512 + (kk - 1024)]);
    } else if (blk < SG7) {                // At = A^T
        const int i = (blk - SG6) * 256 + tid;   // 384*384
        const int k = i / DD, j = i % DD;
        Atb[(size_t)k * DD + j] = f2b(A[(size_t)j * DD + k]);
    } else {                               // biases
        const int i = (blk - SG7) * 256 + tid;   // 0..4095
        if (i < 1024) {
            bu[i] = i < 512 ? bm1[i] : bv1[i - 512];
        } else if (i >= 2048) {
            const int cb = i - 2048;
            const int gate = (cb >> 4) & 3;
            const int n = ((cb >> 6) << 4) + (cb & 15);
            const int orig = gate * 512 + n;
            br[cb] = bih[orig] + bhh[orig];
        }
    }
}

extern "C" void kernel_launch(void* const* d_in, const int* in_sizes, int n_in,
                              void* d_out, int out_size, void* d_ws, size_t ws_size,
                              hipStream_t stream)
{
    const float* x    = (const float*)d_in[0];
    const float* A    = (const float*)d_in[3];
    const float* Wm1  = (const float*)d_in[4];
    const float* bm1  = (const float*)d_in[5];
    const float* Wm2  = (const float*)d_in[6];
    const float* bm2  = (const float*)d_in[7];
    const float* Wv1  = (const float*)d_in[8];
    const float* bv1  = (const float*)d_in[9];
    const float* Wv2  = (const float*)d_in[10];
    const float* bv2  = (const float*)d_in[11];
    const float* Wphi = (const float*)d_in[12];
    const float* bphi = (const float*)d_in[13];
    const float* W_ih = (const float*)d_in[14];
    const float* W_hh = (const float*)d_in[15];
    const float* b_ih = (const float*)d_in[16];
    const float* b_hh = (const float*)d_in[17];

    float* out = (float*)d_out;
    float* out_z    = out;
    float* out_mean = out_z + (size_t)B_ * T_ * ZD;
    float* out_lv   = out_mean + (size_t)B_ * T_ * ZD;
    float* out_hout = out_lv + (size_t)B_ * T_ * ZD;
    float* out_hlo  = out_hout + (size_t)B_ * T_ * HD;

    // ---- workspace layout (~255 MB) ----
    char* wp = (char*)d_ws;
    auto alloc_f = [&](size_t n) { float* p = (float*)wp; wp += n * sizeof(float); return p; };
    auto alloc_b = [&](size_t n) { unsigned short* p = (unsigned short*)wp; wp += n * sizeof(unsigned short); return p; };

    float* c = alloc_f((size_t)B_ * HD);
    unsigned short* hb0     = alloc_b((size_t)B_ * HD);
    unsigned short* hb1     = alloc_b((size_t)B_ * HD);
    unsigned short* xball   = alloc_b((size_t)T_ * B_ * XD);
    unsigned short* umuvall = alloc_b((size_t)T_ * B_ * 1024);
    unsigned short* phib    = alloc_b((size_t)B_ * 1024);

    unsigned short* Wub   = alloc_b((size_t)1024 * 768);
    unsigned short* Wm2b  = alloc_b((size_t)ZD * HD);
    unsigned short* Wv2b  = alloc_b((size_t)ZD * HD);
    unsigned short* Atb   = alloc_b((size_t)DD * DD);
    unsigned short* Wphib = alloc_b((size_t)1024 * DD);
    unsigned short* Wcb   = alloc_b((size_t)1024 * DD);
    unsigned short* Wrih  = alloc_b((size_t)2048 * 1024);
    unsigned short* Wrhh  = alloc_b((size_t)2048 * 512);

    float* bu = alloc_f(1024);
    float* br = alloc_f(2048);

    const dim3 blk(256);

    // ---- prep: one fused kernel + the Wc GEMM ----
    prep_all<<<dim3(SG8), blk, 0, stream>>>(
        x, A, Wm1, bm1, Wm2, Wv1, bv1, Wv2, Wphi, W_ih, W_hh, b_ih, b_hh,
        c, hb0, out_hout, xball, Wub, Wm2b, Wv2b, Wphib, Wrih, Wrhh, Atb, bu, br);
    // Wc = Wphi @ A  ([1024 x 384] bf16): folds the agg GEMM into phi
    k_gemm_plain<<<dim3(DD / 128, 1024 / 128), blk, 0, stream>>>(
        Wphib, DD, DD, Atb, DD, Wcb, DD);

    for (int t = 0; t < T_; ++t) {
        unsigned short* hbt = (t & 1) ? hb1 : hb0;   // h_t  (read)
        unsigned short* hbn = (t & 1) ? hb0 : hb1;   // h_{t+1} (written by epilogue)
        const unsigned short* xb = xball + (size_t)t * B_ * XD;
        unsigned short* uslot = umuvall + (size_t)t * B_ * 1024;

        // [u_m | u_v] = lrelu([x_t, h] @ Wub^T + bu)   8-wave 64x128 core, grid 512
        k_u_8w<<<dim3(512), dim3(512), 0, stream>>>(
            xb, XD, XD, hbt, HD, HD,
            Wub, XD + HD, Wub + XD, XD + HD,
            bu, uslot, 1024);

        // mean (in-LDS) + phi fused, 8-wave; bn==0 writes out_z/out_mean
        k_meanphi<<<dim3(512), dim3(512), 0, stream>>>(
            uslot, xb, Wm2b, Wcb, bm2, bphi,
            out_z + (size_t)t * ZD, out_mean + (size_t)t * ZD, phib);

        // gates (reordered) + fused LSTM   8-wave MT=128 core, grid 512
        k_gates_lstm<<<dim3(512), dim3(512), 0, stream>>>(
            phib, hbt, Wrih, Wrhh, br,
            c, hbn,
            out_hlo + (size_t)t * HD,
            (t + 1 < T_) ? out_hout + (size_t)(t + 1) * HD : nullptr);
    }

    // logvar for ALL steps in one batched GEMM (off the recurrence path)
    k_logvar_all<<<dim3(T_ * B_ / 64), blk, 0, stream>>>(
        umuvall, Wv2b, bv2, out_lv);
}

// Round 17
// 1817.566 us; speedup vs baseline: 1.3605x; 1.0048x over previous
//
#include <hip/hip_runtime.h>
#include <math.h>

// Problem constants
constexpr int B_ = 4096;
constexpr int T_ = 20;
constexpr int XD = 256;   // X_DIM
constexpr int ZD = 128;   // Z_DIM
constexpr int HD = 512;   // H_DIM
constexpr int DD = 384;   // X+Z

using short8 = __attribute__((ext_vector_type(8))) short;
using bf16x8 = __attribute__((ext_vector_type(8))) __bf16;
using f32x4  = __attribute__((ext_vector_type(4))) float;

__device__ __forceinline__ float lrelu_f(float v) { return v > 0.f ? v : 0.2f * v; }
__device__ __forceinline__ float softplus_f(float v) {
    return log1pf(expf(-fabsf(v))) + fmaxf(v, 0.f);
}
__device__ __forceinline__ float sigmoid_f(float v) { return 1.f / (1.f + expf(-v)); }

// float -> bf16 (round to nearest even), finite inputs
__device__ __forceinline__ unsigned short f2b(float f) {
    unsigned u = __builtin_bit_cast(unsigned, f);
    u += 0x7fff + ((u >> 16) & 1);
    return (unsigned short)(u >> 16);
}

__device__ __forceinline__ f32x4 mfma16(short8 a, short8 b, f32x4 c) {
    return __builtin_amdgcn_mfma_f32_16x16x32_bf16(
        __builtin_bit_cast(bf16x8, a), __builtin_bit_cast(bf16x8, b), c, 0, 0, 0);
}

// async global->LDS, 16 B per lane; lds base must be wave-uniform
__device__ __forceinline__ void load_lds16(const unsigned short* g, unsigned short* l) {
    __builtin_amdgcn_global_load_lds(
        (const __attribute__((address_space(1))) unsigned int*)g,
        (__attribute__((address_space(3))) unsigned int*)l,
        16, 0, 0);
}

// wait until at most `rem` K-tiles (LPT loads each per wave) remain outstanding
template <int LPT>
__device__ __forceinline__ void vmwait(int rem) {
    if (rem >= 2) {
        if constexpr (LPT == 4)      asm volatile("s_waitcnt vmcnt(8)" ::: "memory");
        else if constexpr (LPT == 3) asm volatile("s_waitcnt vmcnt(6)" ::: "memory");
        else if constexpr (LPT == 2) asm volatile("s_waitcnt vmcnt(4)" ::: "memory");
        else                         asm volatile("s_waitcnt vmcnt(2)" ::: "memory");
    } else if (rem == 1) {
        if constexpr (LPT == 4)      asm volatile("s_waitcnt vmcnt(4)" ::: "memory");
        else if constexpr (LPT == 3) asm volatile("s_waitcnt vmcnt(3)" ::: "memory");
        else if constexpr (LPT == 2) asm volatile("s_waitcnt vmcnt(2)" ::: "memory");
        else                         asm volatile("s_waitcnt vmcnt(1)" ::: "memory");
    } else {
        asm volatile("s_waitcnt vmcnt(0)" ::: "memory");
    }
}

// ---------------------------------------------------------------------------
// MTx128-tile bf16 MFMA GEMM core (MT in {64,128}), 256 threads, 3-deep
// counted-vmcnt pipeline. Chunk swizzle c' = c ^ ((row>>1)&3) on global source
// AND ds_read (rule #21).
// ---------------------------------------------------------------------------
template <int MT>
__device__ __forceinline__ void gemm_core(
    const unsigned short* A1, int lda1, int K1,
    const unsigned short* A2, int lda2, int K2,
    const unsigned short* W1, int ldw1,
    const unsigned short* W2, int ldw2,
    int bm, int bn,
    unsigned short* As, unsigned short* Bs,   // As: 3*MT*32, Bs: 3*4096 shorts
    f32x4 (&acc)[MT / 32][4])
{
    constexpr int MI   = MT / 32;
    constexpr int WRS  = MT / 2;
    constexpr int NA   = MT / 64;
    constexpr int LPT  = NA + 2;
    constexpr int ABUF = MT * 32;

    const int tid  = threadIdx.x;
    const int lane = tid & 63;
    const int wave = tid >> 6;
    const int wr = wave >> 1, wc = wave & 1;
    const int fr = lane & 15, fg = lane >> 4;
    const int cswz = fg ^ ((fr >> 1) & 3);

    const int r0 = tid >> 2,          c0 = (tid & 3) ^ ((r0 >> 1) & 3);
    const int r1 = (256 + tid) >> 2,  c1 = ((256 + tid) & 3) ^ ((r1 >> 1) & 3);

    const int n1 = K1 / 32;
    const int nt = n1 + K2 / 32;

    auto stage = [&](int i, int buf) {
        const unsigned short* Ag;
        const unsigned short* Wg;
        int lda, ldw, kb;
        if (i < n1) { Ag = A1; Wg = W1; lda = lda1; ldw = ldw1; kb = i * 32; }
        else        { Ag = A2; Wg = W2; lda = lda2; ldw = ldw2; kb = (i - n1) * 32; }
        unsigned short* lA = As + buf * ABUF + wave * 512;
        unsigned short* lB = Bs + buf * 4096 + wave * 512;
        load_lds16(Ag + (size_t)(bm + r0) * lda + kb + c0 * 8, lA);
        if constexpr (NA == 2)
            load_lds16(Ag + (size_t)(bm + r1) * lda + kb + c1 * 8, lA + 2048);
        load_lds16(Wg + (size_t)(bn + r0) * ldw + kb + c0 * 8, lB);
        load_lds16(Wg + (size_t)(bn + r1) * ldw + kb + c1 * 8, lB + 2048);
    };

    auto compute = [&](int buf) {
        const unsigned short* Ab_ = As + buf * ABUF;
        const unsigned short* Bb_ = Bs + buf * 4096;
        short8 af[MI], bv[4];
#pragma unroll
        for (int mi = 0; mi < MI; ++mi)
            af[mi] = *reinterpret_cast<const short8*>(Ab_ + (wr * WRS + mi * 16 + fr) * 32 + cswz * 8);
#pragma unroll
        for (int ni = 0; ni < 4; ++ni)
            bv[ni] = *reinterpret_cast<const short8*>(Bb_ + (wc * 64 + ni * 16 + fr) * 32 + cswz * 8);
#pragma unroll
        for (int mi = 0; mi < MI; ++mi)
#pragma unroll
            for (int ni = 0; ni < 4; ++ni)
                acc[mi][ni] = mfma16(af[mi], bv[ni], acc[mi][ni]);
    };

    stage(0, 0);
    if (1 < nt) stage(1, 1);
    if (2 < nt) stage(2, 2);
    {
        int rem = (nt - 1 < 2) ? (nt - 1) : 2;
        vmwait<LPT>(rem);
    }
    __builtin_amdgcn_s_barrier();

    int buf = 0;
    for (int i = 0; i < nt; ++i) {
        compute(buf);
        if (i + 1 < nt) {
            asm volatile("" ::: "memory");
            __builtin_amdgcn_s_barrier();
            if (i + 3 < nt) stage(i + 3, buf);
            int rem = nt - (i + 2);
            if (rem > 2) rem = 2;
            vmwait<LPT>(rem);
            __builtin_amdgcn_s_barrier();
            buf = (buf == 2) ? 0 : buf + 1;
        }
    }
}

// ---------------------------------------------------------------------------
// 128x128-tile core, 512 threads = 8 waves (4M x 2N), each wave 32x64 output
// (acc 2x4). Same K-tile order and fragment data as gemm_core<128> ->
// bit-identical accumulation. LPT=2/wave (1 A + 1 B load per K-tile).
// ---------------------------------------------------------------------------
__device__ __forceinline__ void gemm_core8w(
    const unsigned short* A1, int lda1, int K1,
    const unsigned short* A2, int lda2, int K2,
    const unsigned short* W1, int ldw1,
    const unsigned short* W2, int ldw2,
    int bm, int bn,
    unsigned short* As, unsigned short* Bs,   // each 3*4096 shorts
    f32x4 (&acc)[2][4])
{
    const int tid  = threadIdx.x;          // 0..511
    const int lane = tid & 63;
    const int wave = tid >> 6;             // 0..7
    const int wr = wave >> 1, wc = wave & 1;
    const int fr = lane & 15, fg = lane >> 4;
    const int cswz = fg ^ ((fr >> 1) & 3);

    const int r0 = tid >> 2;                       // 0..127
    const int c0 = (tid & 3) ^ ((r0 >> 1) & 3);

    const int n1 = K1 / 32;
    const int nt = n1 + K2 / 32;

    auto stage = [&](int i, int buf) {
        const unsigned short* Ag;
        const unsigned short* Wg;
        int lda, ldw, kb;
        if (i < n1) { Ag = A1; Wg = W1; lda = lda1; ldw = ldw1; kb = i * 32; }
        else        { Ag = A2; Wg = W2; lda = lda2; ldw = ldw2; kb = (i - n1) * 32; }
        unsigned short* lA = As + buf * 4096 + wave * 512;   // 8 waves x 512 = 4096
        unsigned short* lB = Bs + buf * 4096 + wave * 512;
        load_lds16(Ag + (size_t)(bm + r0) * lda + kb + c0 * 8, lA);
        load_lds16(Wg + (size_t)(bn + r0) * ldw + kb + c0 * 8, lB);
    };

    auto compute = [&](int buf) {
        const unsigned short* Ab_ = As + buf * 4096;
        const unsigned short* Bb_ = Bs + buf * 4096;
        short8 af[2], bv[4];
#pragma unroll
        for (int mi = 0; mi < 2; ++mi)
            af[mi] = *reinterpret_cast<const short8*>(Ab_ + (wr * 32 + mi * 16 + fr) * 32 + cswz * 8);
#pragma unroll
        for (int ni = 0; ni < 4; ++ni)
            bv[ni] = *reinterpret_cast<const short8*>(Bb_ + (wc * 64 + ni * 16 + fr) * 32 + cswz * 8);
#pragma unroll
        for (int mi = 0; mi < 2; ++mi)
#pragma unroll
            for (int ni = 0; ni < 4; ++ni)
                acc[mi][ni] = mfma16(af[mi], bv[ni], acc[mi][ni]);
    };

    stage(0, 0);
    if (1 < nt) stage(1, 1);
    if (2 < nt) stage(2, 2);
    {
        int rem = (nt - 1 < 2) ? (nt - 1) : 2;
        vmwait<2>(rem);
    }
    __builtin_amdgcn_s_barrier();

    int buf = 0;
    for (int i = 0; i < nt; ++i) {
        compute(buf);
        if (i + 1 < nt) {
            asm volatile("" ::: "memory");
            __builtin_amdgcn_s_barrier();
            if (i + 3 < nt) stage(i + 3, buf);
            int rem = nt - (i + 2);
            if (rem > 2) rem = 2;
            vmwait<2>(rem);
            __builtin_amdgcn_s_barrier();
            buf = (buf == 2) ? 0 : buf + 1;
        }
    }
}

// ---------------------------------------------------------------------------
// 64x128-tile core, 512 threads = 8 waves (4M x 2N), each wave 16x64 output
// (acc 1x4). Role-split staging (chunk audit: A 64x32 = 256 chunks = waves
// 0-3 x 1 load; B 128x32 = 512 chunks = waves 4-7 x 2 loads).
// Per-wave LPT: A-waves 1, B-waves 2 -> wave-uniform branched vmwait.
// Same K-tile order/fragments as gemm_core<64> -> bit-identical.
// ---------------------------------------------------------------------------
__device__ __forceinline__ void gemm_core8w64(
    const unsigned short* A1, int lda1, int K1,
    const unsigned short* A2, int lda2, int K2,
    const unsigned short* W1, int ldw1,
    const unsigned short* W2, int ldw2,
    int bm, int bn,
    unsigned short* As, unsigned short* Bs,   // As: 3*2048, Bs: 3*4096 shorts
    f32x4 (&acc)[1][4])
{
    const int tid  = threadIdx.x;          // 0..511
    const int lane = tid & 63;
    const int wave = tid >> 6;             // 0..7
    const int wr = wave >> 1, wc = wave & 1;
    const int fr = lane & 15, fg = lane >> 4;
    const int cswz = fg ^ ((fr >> 1) & 3);

    // A role (waves 0-3): chunk ca = wave*64+lane (0..255)
    const int ca = wave * 64 + lane;
    const int ar = ca >> 2, ac = (ca & 3) ^ ((ar >> 1) & 3);
    // B role (waves 4-7): chunk groups g0=(wave-4)*2, g1=g0+1; chunk g*64+lane
    const int g0 = (wave - 4) * 2, g1 = g0 + 1;
    const int cb0 = g0 * 64 + lane, cb1 = g1 * 64 + lane;
    const int br0 = cb0 >> 2, bc0 = (cb0 & 3) ^ ((br0 >> 1) & 3);
    const int br1 = cb1 >> 2, bc1 = (cb1 & 3) ^ ((br1 >> 1) & 3);

    const int n1 = K1 / 32;
    const int nt = n1 + K2 / 32;

    auto stage = [&](int i, int buf) {
        const unsigned short* Ag;
        const unsigned short* Wg;
        int lda, ldw, kb;
        if (i < n1) { Ag = A1; Wg = W1; lda = lda1; ldw = ldw1; kb = i * 32; }
        else        { Ag = A2; Wg = W2; lda = lda2; ldw = ldw2; kb = (i - n1) * 32; }
        if (wave < 4) {
            unsigned short* lA = As + buf * 2048 + wave * 512;
            load_lds16(Ag + (size_t)(bm + ar) * lda + kb + ac * 8, lA);
        } else {
            unsigned short* lB = Bs + buf * 4096;
            load_lds16(Wg + (size_t)(bn + br0) * ldw + kb + bc0 * 8, lB + g0 * 512);
            load_lds16(Wg + (size_t)(bn + br1) * ldw + kb + bc1 * 8, lB + g1 * 512);
        }
    };

    auto wait = [&](int rem) {
        if (wave < 4) vmwait<1>(rem);
        else          vmwait<2>(rem);
    };

    auto compute = [&](int buf) {
        const unsigned short* Ab_ = As + buf * 2048;
        const unsigned short* Bb_ = Bs + buf * 4096;
        short8 af = *reinterpret_cast<const short8*>(Ab_ + (wr * 16 + fr) * 32 + cswz * 8);
        short8 bv[4];
#pragma unroll
        for (int ni = 0; ni < 4; ++ni)
            bv[ni] = *reinterpret_cast<const short8*>(Bb_ + (wc * 64 + ni * 16 + fr) * 32 + cswz * 8);
#pragma unroll
        for (int ni = 0; ni < 4; ++ni)
            acc[0][ni] = mfma16(af, bv[ni], acc[0][ni]);
    };

    stage(0, 0);
    if (1 < nt) stage(1, 1);
    if (2 < nt) stage(2, 2);
    {
        int rem = (nt - 1 < 2) ? (nt - 1) : 2;
        wait(rem);
    }
    __builtin_amdgcn_s_barrier();

    int buf = 0;
    for (int i = 0; i < nt; ++i) {
        compute(buf);
        if (i + 1 < nt) {
            asm volatile("" ::: "memory");
            __builtin_amdgcn_s_barrier();
            if (i + 3 < nt) stage(i + 3, buf);
            int rem = nt - (i + 2);
            if (rem > 2) rem = 2;
            wait(rem);
            __builtin_amdgcn_s_barrier();
            buf = (buf == 2) ? 0 : buf + 1;
        }
    }
}

// GEMM + bias + activation -> bf16 output. ACT: 0 none, 1 lrelu, 2 softplus(lrelu)
// 1D grid decode: bn = (id & NMASK)*128, bm = (id >> NSHIFT)*MT
template <int ACT, int MT, int NMASK, int NSHIFT>
__global__ __launch_bounds__(256) void k_gemm_act(
    const unsigned short* __restrict__ A1, int lda1, int K1,
    const unsigned short* __restrict__ A2, int lda2, int K2,
    const unsigned short* __restrict__ W1, int ldw1,
    const unsigned short* __restrict__ W2, int ldw2,
    const float* __restrict__ bias,
    unsigned short* __restrict__ DB, int lddb)
{
    __shared__ unsigned short As[3 * MT * 32];
    __shared__ unsigned short Bs[3 * 4096];
    const int id = blockIdx.x;
    const int bm = (id >> NSHIFT) * MT, bn = (id & NMASK) * 128;
    f32x4 acc[MT / 32][4] = {};
    gemm_core<MT>(A1, lda1, K1, A2, lda2, K2, W1, ldw1, W2, ldw2, bm, bn, As, Bs, acc);

    constexpr int MI = MT / 32, WRS = MT / 2;
    const int tid = threadIdx.x, lane = tid & 63, wave = tid >> 6;
    const int wr = wave >> 1, wc = wave & 1, fr = lane & 15, rg = lane >> 4;
    float bb[4];
#pragma unroll
    for (int ni = 0; ni < 4; ++ni)
        bb[ni] = bias ? bias[bn + wc * 64 + ni * 16 + fr] : 0.f;
#pragma unroll
    for (int mi = 0; mi < MI; ++mi)
#pragma unroll
        for (int r = 0; r < 4; ++r) {
            const int row = bm + wr * WRS + mi * 16 + rg * 4 + r;
#pragma unroll
            for (int ni = 0; ni < 4; ++ni) {
                float v = acc[mi][ni][r] + bb[ni];
                if (ACT == 1) v = lrelu_f(v);
                else if (ACT == 2) v = softplus_f(lrelu_f(v));
                DB[(size_t)row * lddb + (bn + wc * 64 + ni * 16 + fr)] = f2b(v);
            }
        }
}

// u GEMM via the 8-wave 64x128 core: grid 512 (bm=(id>>3)*64, bn=(id&7)*128),
// 512 threads -> 2 blocks/CU -> 4 waves/SIMD.
__global__ __launch_bounds__(512) void k_u_8w(
    const unsigned short* __restrict__ A1, int lda1, int K1,
    const unsigned short* __restrict__ A2, int lda2, int K2,
    const unsigned short* __restrict__ W1, int ldw1,
    const unsigned short* __restrict__ W2, int ldw2,
    const float* __restrict__ bias,
    unsigned short* __restrict__ DB, int lddb)
{
    __shared__ unsigned short As[3 * 2048];   // 12 KB
    __shared__ unsigned short Bs[3 * 4096];   // 24 KB
    const int id = blockIdx.x;
    const int bm = (id >> 3) * 64, bn = (id & 7) * 128;
    f32x4 acc[1][4] = {};
    gemm_core8w64(A1, lda1, K1, A2, lda2, K2, W1, ldw1, W2, ldw2, bm, bn, As, Bs, acc);

    const int tid = threadIdx.x, lane = tid & 63, wave = tid >> 6;
    const int wr = wave >> 1, wc = wave & 1, fr = lane & 15, rg = lane >> 4;
    float bb[4];
#pragma unroll
    for (int ni = 0; ni < 4; ++ni)
        bb[ni] = bias[bn + wc * 64 + ni * 16 + fr];
#pragma unroll
    for (int r = 0; r < 4; ++r) {
        const int row = bm + wr * 16 + rg * 4 + r;
#pragma unroll
        for (int ni = 0; ni < 4; ++ni) {
            float v = lrelu_f(acc[0][ni][r] + bb[ni]);
            DB[(size_t)row * lddb + (bn + wc * 64 + ni * 16 + fr)] = f2b(v);
        }
    }
}

// ---------------------------------------------------------------------------
// Fused mean + phi kernel, 512 threads / 8 waves (R17): grid 512:
// bm=(id>>3)*64 rows, bn=(id&7)*128 phi-cols.
// Stage 1: mean via gemm_core8w64 -> meanL (+ out_z/out_mean if bn==0).
// Stage 2 (UNIFIED, 12 K-tiles): phi = [x|mean] @ Wc^T in one pipeline.
//   B: Wcb rows [bn..bn+128), k = i*32 (DD = 384 = 12x32 contiguous sweep);
//      waves 4-7, 2 loads/lane/tile (512 chunks).
//   A: tiles 0-7 staged from xb (waves 0-3, 1 load/lane); tiles 8-11 read
//      directly from meanL (no staging; synced before loop).
//   A-wave in-flight count at wait(i): (i<6)+(i<5)  [tiles i+2,i+3 < 8].
// Same K order as the old split stages -> bit-identical results.
// ---------------------------------------------------------------------------
__global__ __launch_bounds__(512) void k_meanphi(
    const unsigned short* __restrict__ uslot,  // umuvall + t*B*1024, [B][1024]
    const unsigned short* __restrict__ xb,     // [B][256]
    const unsigned short* __restrict__ Wm2b,   // [128][512]
    const unsigned short* __restrict__ Wcb,    // [1024][384]
    const float* __restrict__ bm2,             // [128]
    const float* __restrict__ bphi,            // [1024]
    float* __restrict__ oz, float* __restrict__ om,   // + t*ZD, stride T*ZD
    unsigned short* __restrict__ phib)
{
    __shared__ unsigned short As[3 * 2048];      // 12 KB
    __shared__ unsigned short Bs[3 * 4096];      // 24 KB
    __shared__ unsigned short meanL[64 * 136];   // 17 KB, conflict-light pad

    const int id = blockIdx.x;
    const int bm = (id >> 3) * 64, bn = (id & 7) * 128;
    const int tid = threadIdx.x, lane = tid & 63, wave = tid >> 6;
    const int wr = wave >> 1, wc = wave & 1, fr = lane & 15, fg = lane >> 4, rg = lane >> 4;
    const int cswz = fg ^ ((fr >> 1) & 3);

    // ---- stage 1: mean = lrelu(u_m @ Wm2^T + bm2) for rows [bm, bm+64) ----
    {
        f32x4 macc[1][4] = {};
        gemm_core8w64(uslot, 1024, 512, uslot, 1024, 0,
                      Wm2b, 512, Wm2b, 512, bm, 0, As, Bs, macc);
        float mb[4];
#pragma unroll
        for (int ni = 0; ni < 4; ++ni)
            mb[ni] = bm2[wc * 64 + ni * 16 + fr];
#pragma unroll
        for (int r = 0; r < 4; ++r) {
            const int rowl = wr * 16 + rg * 4 + r;
#pragma unroll
            for (int ni = 0; ni < 4; ++ni) {
                const int col = wc * 64 + ni * 16 + fr;
                const float v = lrelu_f(macc[0][ni][r] + mb[ni]);
                meanL[rowl * 136 + col] = f2b(v);
                if (bn == 0) {
                    const size_t o = (size_t)(bm + rowl) * (T_ * ZD) + col;
                    oz[o] = v; om[o] = v;
                }
            }
        }
    }
    __syncthreads();   // meanL complete; As/Bs free (stage-1 queue drained)

    // ---- stage 2 (unified): phi = [x|mean] @ Wc^T over 12 K-tiles ----
    f32x4 acc[1][4] = {};
    {
        // A role (waves 0-3): xb tiles i<8; chunk = wave*64+lane (0..255)
        const int ca_ = wave * 64 + lane;
        const int ar = ca_ >> 2, ac = (ca_ & 3) ^ ((ar >> 1) & 3);
        // B role (waves 4-7): Wcb full rows; 2 loads/lane (512 chunks)
        const int g0 = (wave - 4) * 2, g1 = g0 + 1;
        const int cb0 = g0 * 64 + lane, cb1 = g1 * 64 + lane;
        const int br0 = cb0 >> 2, bc0 = (cb0 & 3) ^ ((br0 >> 1) & 3);
        const int br1 = cb1 >> 2, bc1 = (cb1 & 3) ^ ((br1 >> 1) & 3);

        auto stageT = [&](int i, int buf) {
            if (wave < 4) {
                if (i < 8) {
                    unsigned short* lA = As + buf * 2048 + wave * 512;
                    load_lds16(xb + (size_t)(bm + ar) * XD + i * 32 + ac * 8, lA);
                }
            } else {
                unsigned short* lB = Bs + buf * 4096;
                load_lds16(Wcb + (size_t)(bn + br0) * DD + i * 32 + bc0 * 8, lB + g0 * 512);
                load_lds16(Wcb + (size_t)(bn + br1) * DD + i * 32 + bc1 * 8, lB + g1 * 512);
            }
        };

        stageT(0, 0); stageT(1, 1); stageT(2, 2);
        if (wave < 4) vmwait<1>(2); else vmwait<2>(2);
        __builtin_amdgcn_s_barrier();

        int buf = 0;
        for (int i = 0; i < 12; ++i) {
            short8 af;
            if (i < 8)
                af = *reinterpret_cast<const short8*>(
                    As + buf * 2048 + (wr * 16 + fr) * 32 + cswz * 8);
            else
                af = *reinterpret_cast<const short8*>(
                    meanL + (wr * 16 + fr) * 136 + (i - 8) * 32 + fg * 8);
            short8 bv[4];
#pragma unroll
            for (int ni = 0; ni < 4; ++ni)
                bv[ni] = *reinterpret_cast<const short8*>(
                    Bs + buf * 4096 + (wc * 64 + ni * 16 + fr) * 32 + cswz * 8);
#pragma unroll
            for (int ni = 0; ni < 4; ++ni)
                acc[0][ni] = mfma16(af, bv[ni], acc[0][ni]);

            if (i + 1 < 12) {
                asm volatile("" ::: "memory");
                __builtin_amdgcn_s_barrier();
                if (i + 3 < 12) stageT(i + 3, buf);
                if (wave < 4) {
                    // A-loads in flight allowed: tiles {i+2,i+3} ∩ [0,8)
                    const int ca2 = (i < 6 ? 1 : 0) + (i < 5 ? 1 : 0);
                    vmwait<1>(ca2);
                } else {
                    int rem = 12 - (i + 2);
                    if (rem > 2) rem = 2;
                    vmwait<2>(rem);
                }
                __builtin_amdgcn_s_barrier();
                buf = (buf == 2) ? 0 : buf + 1;
            }
        }
    }

    // ---- epilogue: softplus(lrelu(.)) -> phib ----
    float pb[4];
#pragma unroll
    for (int ni = 0; ni < 4; ++ni)
        pb[ni] = bphi[bn + wc * 64 + ni * 16 + fr];
#pragma unroll
    for (int r = 0; r < 4; ++r) {
        const int row = bm + wr * 16 + rg * 4 + r;
#pragma unroll
        for (int ni = 0; ni < 4; ++ni) {
            const float v = softplus_f(lrelu_f(acc[0][ni][r] + pb[ni]));
            phib[(size_t)row * 1024 + (bn + wc * 64 + ni * 16 + fr)] = f2b(v);
        }
    }
}

// ---------------------------------------------------------------------------
// Batched logvar over ALL steps (off the recurrence path)
__global__ __launch_bounds__(256) void k_logvar_all(
    const unsigned short* __restrict__ umuvall,
    const unsigned short* __restrict__ Wv2b,
    const float* __restrict__ bv2,
    float* __restrict__ out_lv)               // [B][T][ZD]
{
    __shared__ unsigned short As[3 * 64 * 32];
    __shared__ unsigned short Bs[3 * 4096];
    const int bm = blockIdx.x * 64;
    f32x4 acc[2][4] = {};
    gemm_core<64>(umuvall + 512, 1024, 512, umuvall + 512, 1024, 0,
                  Wv2b, 512, Wv2b, 512, bm, 0, As, Bs, acc);

    const int tid = threadIdx.x, lane = tid & 63, wave = tid >> 6;
    const int wr = wave >> 1, wc = wave & 1, fr = lane & 15, rg = lane >> 4;
    float bb[4];
#pragma unroll
    for (int ni = 0; ni < 4; ++ni)
        bb[ni] = bv2[wc * 64 + ni * 16 + fr];
#pragma unroll
    for (int mi = 0; mi < 2; ++mi)
#pragma unroll
        for (int r = 0; r < 4; ++r) {
            const int row = bm + wr * 32 + mi * 16 + rg * 4 + r;   // t*B + b
            const int t = row >> 12, b = row & (B_ - 1);
#pragma unroll
            for (int ni = 0; ni < 4; ++ni) {
                const int col = wc * 64 + ni * 16 + fr;
                out_lv[(size_t)b * (T_ * ZD) + (size_t)t * ZD + col] =
                    lrelu_f(acc[mi][ni][r] + bb[ni]);
            }
        }
}

// gates GEMM: 512-thread 8-wave MT=128 core + gate-interleaved rows + fused
// LSTM. grid 512 = 2 blocks/CU -> 4 waves/SIMD.
// XCD-chunked swizzle: sid=(id&7)*64+(id>>3); bn=(sid&15)*128, bm=(sid>>4)*128.
__global__ __launch_bounds__(512) void k_gates_lstm(
    const unsigned short* __restrict__ phib,
    const unsigned short* __restrict__ hbin,
    const unsigned short* __restrict__ Wih,   // [2048][1024] reordered rows
    const unsigned short* __restrict__ Whh,   // [2048][512] reordered rows
    const float* __restrict__ br,             // reordered b_ih+b_hh
    float* __restrict__ c,
    unsigned short* __restrict__ hbout,
    float* __restrict__ ohl,                  // out_hlo + t*HD
    float* __restrict__ oh_next)              // out_hout + (t+1)*HD, or null
{
    __shared__ unsigned short As[3 * 4096];   // 24 KB
    __shared__ unsigned short Bs[3 * 4096];   // 24 KB
    const int id = blockIdx.x;
    const int sid = (id & 7) * 64 + (id >> 3);         // bijective for 512
    const int bm = (sid >> 4) * 128, bn = (sid & 15) * 128;
    f32x4 acc[2][4] = {};
    gemm_core8w(phib, 1024, 1024, hbin, 512, 512, Wih, 1024, Whh, 512, bm, bn, As, Bs, acc);

    const int tid = threadIdx.x, lane = tid & 63, wave = tid >> 6;
    const int wr = wave >> 1, wc = wave & 1, fr = lane & 15, rg = lane >> 4;
    const int n = ((bn + wc * 64) >> 6) * 16 + fr;     // hidden unit index
    float bb[4];
#pragma unroll
    for (int ni = 0; ni < 4; ++ni)
        bb[ni] = br[bn + wc * 64 + ni * 16 + fr];
#pragma unroll
    for (int mi = 0; mi < 2; ++mi)
#pragma unroll
        for (int r = 0; r < 4; ++r) {
            const int row = bm + wr * 32 + mi * 16 + rg * 4 + r;
            const size_t idx = (size_t)row * HD + n;
            const float gi = acc[mi][0][r] + bb[0];
            const float gf = acc[mi][1][r] + bb[1];
            const float gg = acc[mi][2][r] + bb[2];
            const float go = acc[mi][3][r] + bb[3];
            const float co = c[idx];
            const float cn = sigmoid_f(gf) * co + sigmoid_f(gi) * tanhf(gg);
            const float hn = sigmoid_f(go) * tanhf(cn);
            c[idx] = cn;
            hbout[idx] = f2b(hn);
            const size_t ob = (size_t)row * (T_ * HD) + n;
            ohl[ob] = hn;                       // h after update
            if (oh_next) oh_next[ob] = hn;      // == h BEFORE update at t+1
        }
}

// ---------------------------------------------------------------------------
// prep GEMM (MT=128 core, 2D grid) for Wc = Wphi @ A
__global__ __launch_bounds__(256) void k_gemm_plain(
    const unsigned short* __restrict__ A1, int lda1, int K1,
    const unsigned short* __restrict__ W1, int ldw1,
    unsigned short* __restrict__ DB, int lddb)
{
    __shared__ unsigned short As[3 * 128 * 32];
    __shared__ unsigned short Bs[3 * 4096];
    const int bm = blockIdx.y * 128, bn = blockIdx.x * 128;
    f32x4 acc[4][4] = {};
    gemm_core<128>(A1, lda1, K1, A1, lda1, 0, W1, ldw1, W1, ldw1, bm, bn, As, Bs, acc);

    const int tid = threadIdx.x, lane = tid & 63, wave = tid >> 6;
    const int wr = wave >> 1, wc = wave & 1, fr = lane & 15, rg = lane >> 4;
#pragma unroll
    for (int mi = 0; mi < 4; ++mi)
#pragma unroll
        for (int r = 0; r < 4; ++r) {
            const int row = bm + wr * 64 + mi * 16 + rg * 4 + r;
#pragma unroll
            for (int ni = 0; ni < 4; ++ni) {
                const int col = bn + wc * 64 + ni * 16 + fr;
                DB[(size_t)row * lddb + col] = f2b(acc[mi][ni][r]);
            }
        }
}

// ---------------------------------------------------------------------------
// One fused prep kernel: init-state + x-convert + all weight/bias reorders.
// Segment block counts:
//   init: 8192   conv-x: 20480   Wub: 3072   Wm2b: 64   Wv2b: 64
//   Wphib: 384   wg: 12288       At: 576     bias: 16
// ---------------------------------------------------------------------------
constexpr int SG0 = 8192;
constexpr int SG1 = SG0 + 20480;
constexpr int SG2 = SG1 + 3072;
constexpr int SG3 = SG2 + 64;
constexpr int SG4 = SG3 + 64;
constexpr int SG5 = SG4 + 384;
constexpr int SG6 = SG5 + 12288;
constexpr int SG7 = SG6 + 576;
constexpr int SG8 = SG7 + 16;

__global__ __launch_bounds__(256) void prep_all(
    const float* __restrict__ x,
    const float* __restrict__ A,
    const float* __restrict__ Wm1, const float* __restrict__ bm1,
    const float* __restrict__ Wm2,
    const float* __restrict__ Wv1, const float* __restrict__ bv1,
    const float* __restrict__ Wv2,
    const float* __restrict__ Wphi,
    const float* __restrict__ Wih, const float* __restrict__ Whh,
    const float* __restrict__ bih, const float* __restrict__ bhh,
    float* __restrict__ c, unsigned short* __restrict__ hb0,
    float* __restrict__ oh0,
    unsigned short* __restrict__ xball,
    unsigned short* __restrict__ Wub,
    unsigned short* __restrict__ Wm2b, unsigned short* __restrict__ Wv2b,
    unsigned short* __restrict__ Wphib,
    unsigned short* __restrict__ Wrih, unsigned short* __restrict__ Wrhh,
    unsigned short* __restrict__ Atb,
    float* __restrict__ bu, float* __restrict__ br)
{
    const int blk = blockIdx.x;
    const int tid = threadIdx.x;

    if (blk < SG0) {                       // init state
        const int i = blk * 256 + tid;
        c[i] = 0.f; hb0[i] = 0;
        const int b = i >> 9, nn = i & 511;
        oh0[(size_t)b * (T_ * HD) + nn] = 0.f;
    } else if (blk < SG1) {                // x -> bf16, [T][B][XD]
        const int i = (blk - SG0) * 256 + tid;
        const int d = i & 63;
        const int bt = i >> 6;
        const int b = bt / T_, t = bt % T_;
        float4 v = reinterpret_cast<const float4*>(x)[i];
        ushort4 o;
        o.x = f2b(v.x); o.y = f2b(v.y); o.z = f2b(v.z); o.w = f2b(v.w);
        reinterpret_cast<ushort4*>(xball)[((size_t)t * B_ + b) * (XD / 4) + d] = o;
    } else if (blk < SG2) {                // Wub = [Wm1; Wv1]
        const int e = (blk - SG1) * 256 + tid;
        const float v = e < 512 * 768 ? Wm1[e] : Wv1[e - 512 * 768];
        Wub[e] = f2b(v);
    } else if (blk < SG3) {                // Wm2b
        const int i = (blk - SG2) * 256 + tid;
        float4 v = reinterpret_cast<const float4*>(Wm2)[i];
        ushort4 o;
        o.x = f2b(v.x); o.y = f2b(v.y); o.z = f2b(v.z); o.w = f2b(v.w);
        reinterpret_cast<ushort4*>(Wm2b)[i] = o;
    } else if (blk < SG4) {                // Wv2b
        const int i = (blk - SG3) * 256 + tid;
        float4 v = reinterpret_cast<const float4*>(Wv2)[i];
        ushort4 o;
        o.x = f2b(v.x); o.y = f2b(v.y); o.z = f2b(v.z); o.w = f2b(v.w);
        reinterpret_cast<ushort4*>(Wv2b)[i] = o;
    } else if (blk < SG5) {                // Wphib
        const int i = (blk - SG4) * 256 + tid;
        float4 v = reinterpret_cast<const float4*>(Wphi)[i];
        ushort4 o;
        o.x = f2b(v.x); o.y = f2b(v.y); o.z = f2b(v.z); o.w = f2b(v.w);
        reinterpret_cast<ushort4*>(Wphib)[i] = o;
    } else if (blk < SG6) {                // gate-interleaved W_ih / W_hh
        const int e = (blk - SG5) * 256 + tid;   // over 2048*1536
        const int cc = e / 1536, kk = e % 1536;
        const int gate = (cc >> 4) & 3;
        const int n = ((cc >> 6) << 4) + (cc & 15);
        const int orig = gate * 512 + n;
        if (kk < 1024) Wrih[(size_t)cc * 1024 + kk] = f2b(Wih[(size_t)orig * 1024 + kk]);
        else           Wrhh[(size_t)cc * 512 + (kk - 1024)] = f2b(Whh[(size_t)orig * 512 + (kk - 1024)]);
    } else if (blk < SG7) {                // At = A^T
        const int i = (blk - SG6) * 256 + tid;   // 384*384
        const int k = i / DD, j = i % DD;
        Atb[(size_t)k * DD + j] = f2b(A[(size_t)j * DD + k]);
    } else {                               // biases
        const int i = (blk - SG7) * 256 + tid;   // 0..4095
        if (i < 1024) {
            bu[i] = i < 512 ? bm1[i] : bv1[i - 512];
        } else if (i >= 2048) {
            const int cb = i - 2048;
            const int gate = (cb >> 4) & 3;
            const int n = ((cb >> 6) << 4) + (cb & 15);
            const int orig = gate * 512 + n;
            br[cb] = bih[orig] + bhh[orig];
        }
    }
}

extern "C" void kernel_launch(void* const* d_in, const int* in_sizes, int n_in,
                              void* d_out, int out_size, void* d_ws, size_t ws_size,
                              hipStream_t stream)
{
    const float* x    = (const float*)d_in[0];
    const float* A    = (const float*)d_in[3];
    const float* Wm1  = (const float*)d_in[4];
    const float* bm1  = (const float*)d_in[5];
    const float* Wm2  = (const float*)d_in[6];
    const float* bm2  = (const float*)d_in[7];
    const float* Wv1  = (const float*)d_in[8];
    const float* bv1  = (const float*)d_in[9];
    const float* Wv2  = (const float*)d_in[10];
    const float* bv2  = (const float*)d_in[11];
    const float* Wphi = (const float*)d_in[12];
    const float* bphi = (const float*)d_in[13];
    const float* W_ih = (const float*)d_in[14];
    const float* W_hh = (const float*)d_in[15];
    const float* b_ih = (const float*)d_in[16];
    const float* b_hh = (const float*)d_in[17];

    float* out = (float*)d_out;
    float* out_z    = out;
    float* out_mean = out_z + (size_t)B_ * T_ * ZD;
    float* out_lv   = out_mean + (size_t)B_ * T_ * ZD;
    float* out_hout = out_lv + (size_t)B_ * T_ * ZD;
    float* out_hlo  = out_hout + (size_t)B_ * T_ * HD;

    // ---- workspace layout (~255 MB) ----
    char* wp = (char*)d_ws;
    auto alloc_f = [&](size_t n) { float* p = (float*)wp; wp += n * sizeof(float); return p; };
    auto alloc_b = [&](size_t n) { unsigned short* p = (unsigned short*)wp; wp += n * sizeof(unsigned short); return p; };

    float* c = alloc_f((size_t)B_ * HD);
    unsigned short* hb0     = alloc_b((size_t)B_ * HD);
    unsigned short* hb1     = alloc_b((size_t)B_ * HD);
    unsigned short* xball   = alloc_b((size_t)T_ * B_ * XD);
    unsigned short* umuvall = alloc_b((size_t)T_ * B_ * 1024);
    unsigned short* phib    = alloc_b((size_t)B_ * 1024);

    unsigned short* Wub   = alloc_b((size_t)1024 * 768);
    unsigned short* Wm2b  = alloc_b((size_t)ZD * HD);
    unsigned short* Wv2b  = alloc_b((size_t)ZD * HD);
    unsigned short* Atb   = alloc_b((size_t)DD * DD);
    unsigned short* Wphib = alloc_b((size_t)1024 * DD);
    unsigned short* Wcb   = alloc_b((size_t)1024 * DD);
    unsigned short* Wrih  = alloc_b((size_t)2048 * 1024);
    unsigned short* Wrhh  = alloc_b((size_t)2048 * 512);

    float* bu = alloc_f(1024);
    float* br = alloc_f(2048);

    const dim3 blk(256);

    // ---- prep: one fused kernel + the Wc GEMM ----
    prep_all<<<dim3(SG8), blk, 0, stream>>>(
        x, A, Wm1, bm1, Wm2, Wv1, bv1, Wv2, Wphi, W_ih, W_hh, b_ih, b_hh,
        c, hb0, out_hout, xball, Wub, Wm2b, Wv2b, Wphib, Wrih, Wrhh, Atb, bu, br);
    // Wc = Wphi @ A  ([1024 x 384] bf16): folds the agg GEMM into phi
    k_gemm_plain<<<dim3(DD / 128, 1024 / 128), blk, 0, stream>>>(
        Wphib, DD, DD, Atb, DD, Wcb, DD);

    for (int t = 0; t < T_; ++t) {
        unsigned short* hbt = (t & 1) ? hb1 : hb0;   // h_t  (read)
        unsigned short* hbn = (t & 1) ? hb0 : hb1;   // h_{t+1} (written by epilogue)
        const unsigned short* xb = xball + (size_t)t * B_ * XD;
        unsigned short* uslot = umuvall + (size_t)t * B_ * 1024;

        // [u_m | u_v] = lrelu([x_t, h] @ Wub^T + bu)   8-wave 64x128 core, grid 512
        k_u_8w<<<dim3(512), dim3(512), 0, stream>>>(
            xb, XD, XD, hbt, HD, HD,
            Wub, XD + HD, Wub + XD, XD + HD,
            bu, uslot, 1024);

        // mean (in-LDS) + phi fused, 8-wave, unified 12-tile phi pipeline
        k_meanphi<<<dim3(512), dim3(512), 0, stream>>>(
            uslot, xb, Wm2b, Wcb, bm2, bphi,
            out_z + (size_t)t * ZD, out_mean + (size_t)t * ZD, phib);

        // gates (reordered) + fused LSTM   8-wave MT=128 core, grid 512
        k_gates_lstm<<<dim3(512), dim3(512), 0, stream>>>(
            phib, hbt, Wrih, Wrhh, br,
            c, hbn,
            out_hlo + (size_t)t * HD,
            (t + 1 < T_) ? out_hout + (size_t)(t + 1) * HD : nullptr);
    }

    // logvar for ALL steps in one batched GEMM (off the recurrence path)
    k_logvar_all<<<dim3(T_ * B_ / 64), blk, 0, stream>>>(
        umuvall, Wv2b, bv2, out_lv);
}